// Round 1
// 410.330 us; speedup vs baseline: 1.0058x; 1.0058x over previous
//
#include <hip/hip_runtime.h>
#include <hip/hip_bf16.h>
#include <math.h>

#define B_ 4
#define S_ 2048
#define D_ 768
#define H_ 12
#define DH_ 64
#define F_ 3072
#define NTOK (B_*S_)   // 8192
#define BH_ (B_*H_)    // 48

typedef __hip_bfloat16 bf16;
typedef __attribute__((ext_vector_type(8))) short bf16x8;   // 8 bf16 = 4 VGPRs (MFMA A/B frag)
typedef __attribute__((ext_vector_type(4))) float f32x4;    // MFMA C/D frag
typedef __attribute__((ext_vector_type(4))) _Float16 half4;
typedef __attribute__((ext_vector_type(8))) _Float16 half8;

// async global->LDS: 16 B/lane, lane i lands at ldsbase + i*16 (wave-uniform base)
#define GLD16(g, l) __builtin_amdgcn_global_load_lds( \
    (__attribute__((address_space(1))) void*)(uintptr_t)(g), \
    (__attribute__((address_space(3))) void*)(uintptr_t)(l), 16, 0, 0)

__device__ __forceinline__ float bs2f(short s){
  union { unsigned int u; float f; } cv; cv.u = ((unsigned int)(unsigned short)s) << 16; return cv.f;
}
__device__ __forceinline__ float b2f(bf16 v){ return __bfloat162float(v); }
__device__ __forceinline__ bf16 f2b(float v){ return __float2bfloat16(v); }
__device__ __forceinline__ short f2bb(float v){ bf16 b = f2b(v); short s; __builtin_memcpy(&s, &b, 2); return s; }

// raw workgroup barrier (no vmcnt(0) drain like __syncthreads) + compiler mem fence
__device__ __forceinline__ void wgbar(){
  __builtin_amdgcn_s_barrier();
  asm volatile("" ::: "memory");
}

// tanh-form GELU rewritten: 0.5x(1+tanh(u)) = x * rcp(1 + exp2(x*(c0 + c1*x^2)))
__device__ __forceinline__ float gelu_fast(float v){
  const float c0 = -2.302208157f;
  const float c1 = -0.102943238f;
  float w = v*v;
  float z = v * __builtin_fmaf(c1, w, c0);
  float t = __builtin_amdgcn_exp2f(z);
  return v * __builtin_amdgcn_rcpf(1.0f + t);
}

// ---------------- fp32 -> bf16 convert ----------------
__global__ void f32_to_bf16_k(const float* __restrict__ in, bf16* __restrict__ out, int n){
  int i = blockIdx.x*256 + threadIdx.x;
  if (i < n) out[i] = f2b(in[i]);
}

// ------- transpose+convert: in[K][N] f32 -> out[N][K] bf16 (LDS 32x32 tiles) -------
__global__ __launch_bounds__(256) void transpose_f32_bf16_k(const float* __restrict__ in,
    bf16* __restrict__ out, int K, int N){
  __shared__ float t[32][33];
  const int kb = blockIdx.y*32, nb = blockIdx.x*32;
  const int x = threadIdx.x & 31, y = threadIdx.x >> 5;
#pragma unroll
  for (int yy = y; yy < 32; yy += 8)
    t[yy][x] = in[(size_t)(kb+yy)*N + nb + x];
  __syncthreads();
#pragma unroll
  for (int yy = y; yy < 32; yy += 8)
    out[(size_t)(nb+yy)*K + kb + x] = f2b(t[x][yy]);
}

// ---- pack Wq/Wk/Wv [H,D,Dh] -> WcatT [3D][D] (n-major, k contiguous), biases -> bcat[3D] ----
__global__ void pack_qkv_t_k(const float* __restrict__ Wq, const float* __restrict__ bq,
                             const float* __restrict__ Wk, const float* __restrict__ bk,
                             const float* __restrict__ Wv, const float* __restrict__ bv,
                             bf16* __restrict__ Wt, float* __restrict__ bcat){
  int idx = blockIdx.x*256 + threadIdx.x;
  if (idx < 3*D_*D_){
    int n = idx / D_;
    int k = idx - n*D_;
    int which = n / D_;
    int cc = n - which*D_;
    int h = cc >> 6, e = cc & 63;
    const float* W = (which==0) ? Wq : ((which==1) ? Wk : Wv);
    Wt[idx] = f2b(W[((size_t)h*D_ + k)*DH_ + e]);
  }
  if (idx < 3*D_){
    int which = idx / D_;
    int cc = idx - which*D_;
    int h = cc >> 6, e = cc & 63;
    const float* bb = (which==0) ? bq : ((which==1) ? bk : bv);
    bcat[idx] = bb[h*DH_ + e];
  }
}

// ================= MFMA GEMM 256x256, BK=64, 8-phase counted-vmcnt schedule =================
// C[M,N] = A[M,K] @ Bt[N,K]^T.  8 waves (2M x 4N), per-wave 128x64 output.
// LDS: [2 dbuf][2 khalf][256 rows][32 cols] bf16 per operand = 64 KB each, 128 KB total.
// k-half-contiguous layout keeps global_load_lds destinations linear; staging source is
// pre-swizzled (chunk ^= (row>>1)&3) so frag ds_read_b128 are 2-way-per-quad-phase (free).
// Schedule per K-tile (4 phases): {ds-read frags | issue 1 half-tile prefetch | s_barrier |
// setprio(1) 16xMFMA setprio(0) | counted vmcnt(4) at phases 1,3 | s_barrier}.
// Steady state keeps 2-4 staging half-tiles (4-8 loads/thread) in flight; vmcnt never 0
// except the last tile's mid-drain.  EPI 0: qkv scatter; EPI 2: +bias, fast GELU.
#define STAGE_A(bufi_, kh_, kt_) do { \
    GLD16(gA  + (size_t)(kt_)*64 + (kh_)*32, asb + ((bufi_)<<15) + ((kh_)<<14)); \
    GLD16(gA2 + (size_t)(kt_)*64 + (kh_)*32, asb + ((bufi_)<<15) + ((kh_)<<14) + 8192); } while(0)
#define STAGE_B(bufi_, kh_, kt_) do { \
    GLD16(gB  + (size_t)(kt_)*64 + (kh_)*32, bsb + ((bufi_)<<15) + ((kh_)<<14)); \
    GLD16(gB2 + (size_t)(kt_)*64 + (kh_)*32, bsb + ((bufi_)<<15) + ((kh_)<<14) + 8192); } while(0)
#define AFRAG(bufi_, ks_, i_) (*(const bf16x8*)(AsB + ((bufi_)<<15) + ((ks_)<<14) + ((wm + (i_)*16 + l16)<<6) + fsw))
#define BFRAG(bufi_, ks_, j_) (*(const bf16x8*)(BsB + ((bufi_)<<15) + ((ks_)<<14) + ((wn + (j_)*16 + l16)<<6) + fsw))

template<int EPI>
__global__ __launch_bounds__(512, 2) void mgemm256_k(
    const bf16* __restrict__ A, const bf16* __restrict__ Bt,
    const float* __restrict__ bias, bf16* __restrict__ C,
    int M, int N, int K,
    bf16* __restrict__ qb, bf16* __restrict__ kbuf, _Float16* __restrict__ vt)
{
  __shared__ __align__(16) bf16 As[32768];  // [2 buf][2 kh][256 rows][32 cols]
  __shared__ __align__(16) bf16 Bs[32768];
  const int tid  = threadIdx.x;
  const int wave = tid >> 6, lane = tid & 63;
  const int quad = lane >> 4, l16 = lane & 15;
  const int wm = (wave >> 2) * 128;    // wave row block within 256-tile
  const int wn = (wave & 3) * 64;      // wave col block

  // XCD-aware remap (total blocks % 8 == 0 for all our launches)
  const int NX = gridDim.x;
  const int f  = blockIdx.y * NX + blockIdx.x;
  const int xcd = f & 7;
  const int j0  = f >> 3;
  const int bx  = j0 % NX;
  const int by  = (j0 / NX) * 8 + xcd;
  const int m0 = by * 256, n0 = bx * 256;

  // staging: thread t covers row t>>2 of a 128-row round, LDS slot t&3;
  // source chunk pre-swizzled: g = slot ^ ((row>>1)&3) = (t&3) ^ ((t>>3)&3)
  const int srow = tid >> 2;
  const int sg   = (tid & 3) ^ ((tid >> 3) & 3);
  const bf16* gA  = A  + (size_t)(m0 + srow)*K + sg*8;
  const bf16* gA2 = A  + (size_t)(m0 + 128 + srow)*K + sg*8;
  const bf16* gB  = Bt + (size_t)(n0 + srow)*K + sg*8;
  const bf16* gB2 = Bt + (size_t)(n0 + 128 + srow)*K + sg*8;
  const uintptr_t asb = (uintptr_t)(void*)As + (size_t)wave*1024;
  const uintptr_t bsb = (uintptr_t)(void*)Bs + (size_t)wave*1024;

  const char* AsB = (const char*)As;
  const char* BsB = (const char*)Bs;
  const int fsw = (quad ^ ((l16 >> 1) & 3)) * 16;  // swizzled 16B slot within 64B row

  f32x4 acc[8][4];
#pragma unroll
  for (int i=0;i<8;i++)
#pragma unroll
    for (int j2=0;j2<4;j2++) acc[i][j2] = (f32x4)0.f;

  const int KT = K >> 6;

  // prologue: stage tile 0 fully (issue order = consumption order), wait first 2 halves
  STAGE_A(0, 0, 0); STAGE_B(0, 0, 0); STAGE_A(0, 1, 0); STAGE_B(0, 1, 0);
  asm volatile("s_waitcnt vmcnt(4)" ::: "memory");
  wgbar();

  for (int kt = 0; kt < KT; ++kt){
    const int bufc = kt & 1, bufn = bufc ^ 1;
    const bool pf = (kt + 1) < KT;
    bf16x8 af[4], bfr[4];

    // -------- phase 0: khalf 0, rows i=0..3 --------
#pragma unroll
    for (int i=0;i<4;i++) af[i] = AFRAG(bufc, 0, i);
#pragma unroll
    for (int j2=0;j2<4;j2++) bfr[j2] = BFRAG(bufc, 0, j2);
    if (pf) STAGE_A(bufn, 0, kt+1);
    wgbar();
    __builtin_amdgcn_s_setprio(1);
#pragma unroll
    for (int i=0;i<4;i++)
#pragma unroll
      for (int j2=0;j2<4;j2++)
        acc[i][j2] = __builtin_amdgcn_mfma_f32_16x16x32_bf16(af[i], bfr[j2], acc[i][j2], 0, 0, 0);
    __builtin_amdgcn_s_setprio(0);
    wgbar();

    // -------- phase 1: khalf 0, rows i=4..7 --------
#pragma unroll
    for (int i=0;i<4;i++) af[i] = AFRAG(bufc, 0, 4+i);
    if (pf) STAGE_B(bufn, 0, kt+1);
    wgbar();
    __builtin_amdgcn_s_setprio(1);
#pragma unroll
    for (int i=0;i<4;i++)
#pragma unroll
      for (int j2=0;j2<4;j2++)
        acc[4+i][j2] = __builtin_amdgcn_mfma_f32_16x16x32_bf16(af[i], bfr[j2], acc[4+i][j2], 0, 0, 0);
    __builtin_amdgcn_s_setprio(0);
    // need khalf1(kt) landed for phase 2 (oldest 4 loads); last tile: full drain
    if (pf) asm volatile("s_waitcnt vmcnt(4)" ::: "memory");
    else    asm volatile("s_waitcnt vmcnt(0)" ::: "memory");
    wgbar();

    // -------- phase 2: khalf 1, rows i=0..3 --------
#pragma unroll
    for (int i=0;i<4;i++) af[i] = AFRAG(bufc, 1, i);
#pragma unroll
    for (int j2=0;j2<4;j2++) bfr[j2] = BFRAG(bufc, 1, j2);
    if (pf) STAGE_A(bufn, 1, kt+1);
    wgbar();
    __builtin_amdgcn_s_setprio(1);
#pragma unroll
    for (int i=0;i<4;i++)
#pragma unroll
      for (int j2=0;j2<4;j2++)
        acc[i][j2] = __builtin_amdgcn_mfma_f32_16x16x32_bf16(af[i], bfr[j2], acc[i][j2], 0, 0, 0);
    __builtin_amdgcn_s_setprio(0);
    wgbar();

    // -------- phase 3: khalf 1, rows i=4..7 --------
#pragma unroll
    for (int i=0;i<4;i++) af[i] = AFRAG(bufc, 1, 4+i);
    if (pf) STAGE_B(bufn, 1, kt+1);
    wgbar();
    __builtin_amdgcn_s_setprio(1);
#pragma unroll
    for (int i=0;i<4;i++)
#pragma unroll
      for (int j2=0;j2<4;j2++)
        acc[4+i][j2] = __builtin_amdgcn_mfma_f32_16x16x32_bf16(af[i], bfr[j2], acc[4+i][j2], 0, 0, 0);
    __builtin_amdgcn_s_setprio(0);
    // need khalf0(kt+1) landed for next phase 0 (oldest 4 loads)
    if (pf) asm volatile("s_waitcnt vmcnt(4)" ::: "memory");
    wgbar();
  }

  // -------- epilogue --------
#pragma unroll
  for (int i=0;i<8;i++){
#pragma unroll
    for (int j2=0;j2<4;j2++){
      const int n = n0 + wn + j2*16 + l16;
      const int m_base = m0 + wm + i*16 + quad*4;
      if (EPI == 0){
        const int which = n / D_;
        const int cc = n - which*D_;
        const int h = cc >> 6, e = cc & 63;
        if (which == 2){
          const int b = m_base >> 11, s = m_base & (S_-1);
          const int sl = s & 63;
          const int perm = ((sl>>2)&3)*16 + ((sl>>4)&3)*4;   // key-permuted V^T layout
          half4 hv;
#pragma unroll
          for (int r=0;r<4;r++) hv[r] = (_Float16)(acc[i][j2][r] + bias[n]);
          *(half4*)(vt + ((size_t)(b*H_+h)*DH_ + e)*S_ + (s & ~63) + perm) = hv;
        } else {
          bf16* dst = (which==0) ? qb : kbuf;
          const float sc2 = (which==0) ? 0.125f : 1.0f;   // fold softmax 1/sqrt(64) into q
#pragma unroll
          for (int r=0;r<4;r++){
            const int m = m_base + r;
            const int b = m >> 11, s = m & (S_-1);
            dst[((size_t)(b*H_+h)*S_ + s)*DH_ + e] = f2b((acc[i][j2][r] + bias[n]) * sc2);
          }
        }
      } else {
#pragma unroll
        for (int r=0;r<4;r++){
          const int m = m_base + r;
          float v = acc[i][j2][r] + bias[n];
          C[(size_t)m*N + n] = f2b(gelu_fast(v));
        }
      }
    }
  }
}
#undef STAGE_A
#undef STAGE_B
#undef AFRAG
#undef BFRAG

// ---------------- MFMA GEMM 64x128, BK=64 (for N=768 GEMMs: proj, FF2) ----------------
// TM=64, TN=128, BK=64: half the barrier drains of BK=32 at the same staged bytes.
// LDS rows are 128 B (64 bf16); swizzle: slot c of row r holds global chunk c ^ (r&7)
// -> per-quad-phase 2-way bank aliasing (free). Grid (N/128, M/64).
// C = A@Bt^T + bias + aux (residual), bf16 out.
__global__ __launch_bounds__(256) void mgemm64_k(
    const bf16* __restrict__ A, const bf16* __restrict__ Bt,
    const float* __restrict__ bias, const bf16* __restrict__ aux,
    bf16* __restrict__ C, int M, int N, int K)
{
  __shared__ bf16 As[4096];   // [64][64]  8 KB
  __shared__ bf16 Bs[8192];   // [128][64] 16 KB
  const int tid  = threadIdx.x;
  const int wave = tid >> 6, lane = tid & 63;
  const int quad = lane >> 4, l16 = lane & 15;
  const int wm = (wave >> 1) * 32, wn = (wave & 1) * 64;

  const int NX = gridDim.x;
  const int f  = blockIdx.y * NX + blockIdx.x;
  const int xcd = f & 7;
  const int j   = f >> 3;
  const int bx  = j % NX;
  const int by  = (j / NX) * 8 + xcd;
  const int m0 = by * 64, n0 = bx * 128;

  const int srow8 = lane >> 3;                       // 0..7
  const int g     = (lane & 7) ^ srow8;              // global 16B-chunk within the row
  const bf16* gA0 = A  + (size_t)(m0 + wave*16 +      srow8)*K + g*8;
  const bf16* gA1 = A  + (size_t)(m0 + wave*16 +  8 + srow8)*K + g*8;
  const bf16* gB0 = Bt + (size_t)(n0 + wave*32 +      srow8)*K + g*8;
  const bf16* gB1 = Bt + (size_t)(n0 + wave*32 +  8 + srow8)*K + g*8;
  const bf16* gB2 = Bt + (size_t)(n0 + wave*32 + 16 + srow8)*K + g*8;
  const bf16* gB3 = Bt + (size_t)(n0 + wave*32 + 24 + srow8)*K + g*8;
  const uintptr_t asb = (uintptr_t)(void*)As + (size_t)wave*16*128;
  const uintptr_t bsb = (uintptr_t)(void*)Bs + (size_t)wave*32*128;

  f32x4 acc[2][4];
#pragma unroll
  for (int i=0;i<2;i++)
#pragma unroll
    for (int j2=0;j2<4;j2++) acc[i][j2] = (f32x4)0.f;

  const char* AsB = (const char*)As;
  const char* BsB = (const char*)Bs;

  for (int k0 = 0; k0 < K; k0 += 64){
    __syncthreads();
    GLD16(gA0, asb);
    GLD16(gA1, asb + 1024);
    GLD16(gB0, bsb);
    GLD16(gB1, bsb + 1024);
    GLD16(gB2, bsb + 2048);
    GLD16(gB3, bsb + 3072);
    gA0 += 64; gA1 += 64; gB0 += 64; gB1 += 64; gB2 += 64; gB3 += 64;
    __syncthreads();
#pragma unroll
    for (int kq = 0; kq < 2; kq++){
      const int cbase = kq*4 + quad;
      bf16x8 af[2], bfr[4];
#pragma unroll
      for (int i=0;i<2;i++){
        const int m = wm + i*16 + l16;
        af[i] = *(const bf16x8*)(AsB + (m << 7) + ((cbase ^ (m & 7)) << 4));
      }
#pragma unroll
      for (int j2=0;j2<4;j2++){
        const int n = wn + j2*16 + l16;
        bfr[j2] = *(const bf16x8*)(BsB + (n << 7) + ((cbase ^ (n & 7)) << 4));
      }
#pragma unroll
      for (int i=0;i<2;i++)
#pragma unroll
        for (int j2=0;j2<4;j2++)
          acc[i][j2] = __builtin_amdgcn_mfma_f32_16x16x32_bf16(af[i], bfr[j2], acc[i][j2], 0, 0, 0);
    }
  }

#pragma unroll
  for (int i=0;i<2;i++){
#pragma unroll
    for (int j2=0;j2<4;j2++){
      const int n = n0 + wn + j2*16 + l16;
      const int m_base = m0 + wm + i*16 + quad*4;
#pragma unroll
      for (int r=0;r<4;r++){
        const int m = m_base + r;
        float v = acc[i][j2][r] + bias[n] + b2f(aux[(size_t)m*N + n]);
        C[(size_t)m*N + n] = f2b(v);
      }
    }
  }
}

// ---------------- MFMA flash attention ----------------
__global__ __launch_bounds__(256) void fattn_k(const bf16* __restrict__ qb,
    const bf16* __restrict__ kb, const _Float16* __restrict__ vt, bf16* __restrict__ ctx)
{
  __shared__ __align__(16) char smem[19456];
  bf16     (*Ks)[72] = (bf16(*)[72])smem;                  // [64 keys][72] bf16
  _Float16 (*Vs)[72] = (_Float16(*)[72])(smem + 9216);     // [64 d][72 keys(permuted)] f16
  float* maxb  = (float*)(smem + 18432);                   // [2 kh][64 q]
  float* libuf = (float*)(smem + 18944);                   // [2 kh][64 q]
  float* Obuf  = (float*)smem;                             // alias (end)

  const int bh = blockIdx.x;
  const int qt = 31 - blockIdx.y;       // heavy tiles first
  const int q0 = qt * 64;
  const int tid = threadIdx.x;
  const int wave = tid >> 6, lane = tid & 63;
  const int quad = lane >> 4, l16 = lane & 15;
  const int kh = wave >> 1, qh = wave & 1;
  const size_t kbase = (size_t)bh * S_ * DH_;

  bf16x8 qf[2][2];
#pragma unroll
  for (int nf=0; nf<2; nf++)
#pragma unroll
    for (int h=0; h<2; h++)
      qf[nf][h] = *(const bf16x8*)(qb + kbase + (size_t)(q0 + qh*32 + nf*16 + l16)*DH_ + h*32 + quad*8);

  f32x4 o[4][2];
#pragma unroll
  for (int df=0; df<4; df++){ o[df][0] = (f32x4)0.f; o[df][1] = (f32x4)0.f; }
  float mi[2] = {-1e30f, -1e30f}, li[2] = {0.f, 0.f};

  for (int kt = 0; kt <= qt; ++kt){
    const int k0 = kt * 64;
    __syncthreads();
    { // stage K (natural) and V^T (permuted keys)
      const int r = tid >> 2, seg = (tid & 3) * 16;
      const bf16* ksrc = kb + kbase + (size_t)(k0 + r)*DH_ + seg;
      bf16x8 ka = *(const bf16x8*)ksrc;
      bf16x8 kc2 = *(const bf16x8*)(ksrc + 8);
      *(bf16x8*)&Ks[r][seg]   = ka;
      *(bf16x8*)&Ks[r][seg+8] = kc2;
      const _Float16* vsrc = vt + ((size_t)bh*DH_ + r)*S_ + k0 + seg;
      half8 va = *(const half8*)vsrc;
      half8 vb2 = *(const half8*)(vsrc + 8);
      *(half8*)&Vs[r][seg]   = va;
      *(half8*)&Vs[r][seg+8] = vb2;
    }
    __syncthreads();

    bf16x8 af[2][2];
#pragma unroll
    for (int mf=0; mf<2; mf++)
#pragma unroll
      for (int h=0; h<2; h++)
        af[mf][h] = *(const bf16x8*)&Ks[kh*32 + mf*16 + l16][h*32 + quad*8];
    f32x4 sc[2][2];
#pragma unroll
    for (int mf=0; mf<2; mf++)
#pragma unroll
      for (int nf=0; nf<2; nf++){
        f32x4 t = __builtin_amdgcn_mfma_f32_16x16x32_bf16(af[mf][0], qf[nf][0], (f32x4)0.f, 0, 0, 0);
        sc[mf][nf] = __builtin_amdgcn_mfma_f32_16x16x32_bf16(af[mf][1], qf[nf][1], t, 0, 0, 0);
      }

    if (kt == qt){
#pragma unroll
      for (int mf=0; mf<2; mf++){
        const int keyl = kh*32 + mf*16 + quad*4;
#pragma unroll
        for (int nf=0; nf<2; nf++){
          const int ql = qh*32 + nf*16 + l16;
#pragma unroll
          for (int r=0; r<4; r++)
            if (keyl + r > ql) sc[mf][nf][r] = -1e30f;
        }
      }
    }

    float mw[2];
#pragma unroll
    for (int nf=0; nf<2; nf++){
      float mx = -1e30f;
#pragma unroll
      for (int mf=0; mf<2; mf++)
#pragma unroll
        for (int r=0; r<4; r++) mx = fmaxf(mx, sc[mf][nf][r]);
      mx = fmaxf(mx, __shfl_xor(mx, 16));
      mx = fmaxf(mx, __shfl_xor(mx, 32));
      mw[nf] = mx;
    }
    if (quad == 0){
      maxb[kh*64 + qh*32 + l16]      = mw[0];
      maxb[kh*64 + qh*32 + 16 + l16] = mw[1];
    }
    __syncthreads();

    half4 pf[2][2];
    float alpha[2];
#pragma unroll
    for (int nf=0; nf<2; nf++){
      const float mo = maxb[(1-kh)*64 + qh*32 + nf*16 + l16];
      const float mn = fmaxf(mi[nf], fmaxf(mw[nf], mo));
      alpha[nf] = __expf(mi[nf] - mn);
      mi[nf] = mn;
      float rs = 0.f;
#pragma unroll
      for (int mf=0; mf<2; mf++)
#pragma unroll
        for (int r=0; r<4; r++){
          float p = __expf(sc[mf][nf][r] - mn);
          pf[mf][nf][r] = (_Float16)p;
          rs += p;
        }
      rs += __shfl_xor(rs, 16);
      rs += __shfl_xor(rs, 32);
      li[nf] = li[nf]*alpha[nf] + rs;
    }

#pragma unroll
    for (int df=0; df<4; df++)
#pragma unroll
      for (int nf=0; nf<2; nf++)
#pragma unroll
        for (int r=0; r<4; r++) o[df][nf][r] *= alpha[nf];

#pragma unroll
    for (int df=0; df<4; df++){
      half8 vv = *(const half8*)&Vs[df*16 + l16][quad*16 + kh*8];
      half4 vlo = __builtin_shufflevector(vv, vv, 0,1,2,3);
      half4 vhi = __builtin_shufflevector(vv, vv, 4,5,6,7);
#pragma unroll
      for (int nf=0; nf<2; nf++){
        o[df][nf] = __builtin_amdgcn_mfma_f32_16x16x16f16(vlo, pf[0][nf], o[df][nf], 0, 0, 0);
        o[df][nf] = __builtin_amdgcn_mfma_f32_16x16x16f16(vhi, pf[1][nf], o[df][nf], 0, 0, 0);
      }
    }
  }

  __syncthreads();
  if (quad == 0){
    libuf[kh*64 + qh*32 + l16]      = li[0];
    libuf[kh*64 + qh*32 + 16 + l16] = li[1];
  }
  if (kh == 1){
#pragma unroll
    for (int df=0; df<4; df++)
#pragma unroll
      for (int nf=0; nf<2; nf++)
#pragma unroll
        for (int r=0; r<4; r++)
          Obuf[(qh*64 + df*16 + quad*4 + r)*33 + nf*16 + l16] = o[df][nf][r];
  }
  __syncthreads();
  if (kh == 0){
    const int b = bh / H_, h = bh - (bh / H_)*H_;
#pragma unroll
    for (int nf=0; nf<2; nf++){
      const int q64 = qh*32 + nf*16 + l16;
      const float inv = 1.0f / (libuf[q64] + libuf[64 + q64]);
      const int qtok = q0 + q64;
#pragma unroll
      for (int df=0; df<4; df++){
        short4 pk;
        float v0 = (o[df][nf][0] + Obuf[(qh*64 + df*16 + quad*4 + 0)*33 + nf*16 + l16]) * inv;
        float v1 = (o[df][nf][1] + Obuf[(qh*64 + df*16 + quad*4 + 1)*33 + nf*16 + l16]) * inv;
        float v2 = (o[df][nf][2] + Obuf[(qh*64 + df*16 + quad*4 + 2)*33 + nf*16 + l16]) * inv;
        float v3 = (o[df][nf][3] + Obuf[(qh*64 + df*16 + quad*4 + 3)*33 + nf*16 + l16]) * inv;
        pk.x = f2bb(v0); pk.y = f2bb(v1); pk.z = f2bb(v2); pk.w = f2bb(v3);
        *(short4*)((short*)ctx + ((size_t)(b*S_ + qtok))*D_ + h*DH_ + df*16 + quad*4) = pk;
      }
    }
  }
}

// ---------------- layernorm over D=768 ----------------
template<typename T> __device__ __forceinline__ void stf(T* p, float v);
template<> __device__ __forceinline__ void stf<float>(float* p, float v){ *p = v; }
template<> __device__ __forceinline__ void stf<bf16>(bf16* p, float v){ *p = f2b(v); }

template<typename OutT>
__global__ __launch_bounds__(256) void layernorm_k(const bf16* __restrict__ X,
    const float* __restrict__ g, const float* __restrict__ bta, OutT* __restrict__ Y)
{
  const int row = blockIdx.x;
  const int tid = threadIdx.x;
  const bf16* xr = X + (size_t)row * D_;
  float vals[3];
  float s = 0.f, s2 = 0.f;
#pragma unroll
  for (int i = 0; i < 3; i++){
    float v = b2f(xr[tid + i*256]);
    vals[i] = v; s += v; s2 += v*v;
  }
#pragma unroll
  for (int o = 32; o > 0; o >>= 1){ s += __shfl_down(s, o); s2 += __shfl_down(s2, o); }
  __shared__ float rs[4], rq[4];
  const int lane = tid & 63, w = tid >> 6;
  if (lane == 0){ rs[w] = s; rq[w] = s2; }
  __syncthreads();
  s  = rs[0]+rs[1]+rs[2]+rs[3];
  s2 = rq[0]+rq[1]+rq[2]+rq[3];
  const float mean = s * (1.0f/D_);
  const float var  = s2 * (1.0f/D_) - mean*mean;
  const float inv  = rsqrtf(var + 1e-5f);
#pragma unroll
  for (int i = 0; i < 3; i++){
    int c = tid + i*256;
    float o = (vals[i] - mean) * inv * g[c] + bta[c];
    stf(Y + (size_t)row*D_ + c, o);
  }
}

extern "C" void kernel_launch(void* const* d_in, const int* in_sizes, int n_in,
                              void* d_out, int out_size, void* d_ws, size_t ws_size,
                              hipStream_t stream)
{
  const float* x   = (const float*)d_in[0];
  const float* Wq  = (const float*)d_in[1];
  const float* bq  = (const float*)d_in[2];
  const float* Wk  = (const float*)d_in[3];
  const float* bk  = (const float*)d_in[4];
  const float* Wv  = (const float*)d_in[5];
  const float* bv  = (const float*)d_in[6];
  const float* Wo  = (const float*)d_in[7];
  const float* bo  = (const float*)d_in[8];
  const float* W1  = (const float*)d_in[9];
  const float* b1  = (const float*)d_in[10];
  const float* W2  = (const float*)d_in[11];
  const float* b2  = (const float*)d_in[12];
  const float* g1  = (const float*)d_in[13];
  const float* be1 = (const float*)d_in[14];
  const float* g2  = (const float*)d_in[15];
  const float* be2 = (const float*)d_in[16];
  float* out = (float*)d_out;

  char* ws = (char*)d_ws;
  size_t off = 0;
  auto alloc = [&](size_t bytes)->char*{
    char* p = ws + off; off = (off + bytes + 255) & ~(size_t)255; return p;
  };
  bf16*  xb    = (bf16*) alloc((size_t)NTOK*D_*2);
  bf16*  WcatT = (bf16*) alloc((size_t)3*D_*D_*2);
  float* bcat  = (float*)alloc((size_t)3*D_*4);
  bf16*  WoT   = (bf16*) alloc((size_t)D_*D_*2);
  bf16*  W1T   = (bf16*) alloc((size_t)F_*D_*2);
  bf16*  W2T   = (bf16*) alloc((size_t)D_*F_*2);
  bf16*  r1    = (bf16*) alloc((size_t)NTOK*F_*2);     // q,k,vt then ff1
  bf16*  qb    = r1;
  bf16*  kb    = r1 + (size_t)NTOK*D_;
  _Float16* vt = (_Float16*)(r1 + (size_t)2*NTOK*D_);  // [bh*64+d][S], f16, key-permuted
  bf16*  ff1   = r1;
  bf16*  ctxb  = (bf16*) alloc((size_t)NTOK*D_*2);     // ctx then y2
  bf16*  y1    = (bf16*) alloc((size_t)NTOK*D_*2);
  bf16*  hb    = (bf16*) alloc((size_t)NTOK*D_*2);
  bf16*  y2    = ctxb;

  f32_to_bf16_k<<<(NTOK*D_+255)/256, 256, 0, stream>>>(x, xb, NTOK*D_);
  transpose_f32_bf16_k<<<dim3(D_/32, D_/32), 256, 0, stream>>>(Wo, WoT, D_, D_);
  transpose_f32_bf16_k<<<dim3(F_/32, D_/32), 256, 0, stream>>>(W1, W1T, D_, F_);
  transpose_f32_bf16_k<<<dim3(D_/32, F_/32), 256, 0, stream>>>(W2, W2T, F_, D_);
  pack_qkv_t_k<<<(3*D_*D_+255)/256, 256, 0, stream>>>(Wq,bq,Wk,bk,Wv,bv,WcatT,bcat);

  // 1) fused QKV projection (q pre-scaled 1/8; v written transposed+permuted f16)
  //    256x256 8-phase kernel: grid 9x32 = 288 blocks (%8==0)
  mgemm256_k<0><<<dim3(3*D_/256, NTOK/256), 512, 0, stream>>>(
      xb, WcatT, bcat, nullptr, NTOK, 3*D_, D_, qb, kb, vt);

  // 2) MFMA flash attention -> ctx [8192,768]
  fattn_k<<<dim3(BH_, S_/64), 256, 0, stream>>>(qb, kb, vt, ctxb);

  // 3) out-proj + residual: y1 = ctx@Wo + bo + x   (64x128 tiles, BK=64)
  mgemm64_k<<<dim3(D_/128, NTOK/64), 256, 0, stream>>>(
      ctxb, WoT, bo, xb, y1, NTOK, D_, D_);

  // 4) LN1 -> h
  layernorm_k<bf16><<<NTOK, 256, 0, stream>>>(y1, g1, be1, hb);

  // 5) FF1 + fast GELU (256x256 8-phase: grid 12x32 = 384 blocks, %8==0)
  mgemm256_k<2><<<dim3(F_/256, NTOK/256), 512, 0, stream>>>(
      hb, W1T, b1, ff1, NTOK, F_, D_, nullptr, nullptr, nullptr);

  // 6) FF2 + residual: y2 = ff1@W2 + b2 + h   (64x128 tiles, BK=64)
  mgemm64_k<<<dim3(D_/128, NTOK/64), 256, 0, stream>>>(
      ff1, W2T, b2, hb, y2, NTOK, D_, F_);

  // 7) LN2 -> out (fp32)
  layernorm_k<float><<<NTOK, 256, 0, stream>>>(y2, g2, be2, out);
}

// Round 2
// 401.325 us; speedup vs baseline: 1.0283x; 1.0224x over previous
//
#include <hip/hip_runtime.h>
#include <hip/hip_bf16.h>
#include <math.h>

#define B_ 4
#define S_ 2048
#define D_ 768
#define H_ 12
#define DH_ 64
#define F_ 3072
#define NTOK (B_*S_)   // 8192
#define BH_ (B_*H_)    // 48

typedef __hip_bfloat16 bf16;
typedef __attribute__((ext_vector_type(8))) short bf16x8;   // 8 bf16 = 4 VGPRs (MFMA A/B frag)
typedef __attribute__((ext_vector_type(4))) float f32x4;    // MFMA C/D frag
typedef __attribute__((ext_vector_type(4))) _Float16 half4;
typedef __attribute__((ext_vector_type(8))) _Float16 half8;

// async global->LDS: 16 B/lane, lane i lands at ldsbase + i*16 (wave-uniform base)
#define GLD16(g, l) __builtin_amdgcn_global_load_lds( \
    (__attribute__((address_space(1))) void*)(uintptr_t)(g), \
    (__attribute__((address_space(3))) void*)(uintptr_t)(l), 16, 0, 0)

__device__ __forceinline__ float bs2f(short s){
  union { unsigned int u; float f; } cv; cv.u = ((unsigned int)(unsigned short)s) << 16; return cv.f;
}
__device__ __forceinline__ float b2f(bf16 v){ return __bfloat162float(v); }
__device__ __forceinline__ bf16 f2b(float v){ return __float2bfloat16(v); }
__device__ __forceinline__ short f2bb(float v){ bf16 b = f2b(v); short s; __builtin_memcpy(&s, &b, 2); return s; }

// raw workgroup barrier (no vmcnt(0) drain like __syncthreads) + compiler mem fence
__device__ __forceinline__ void wgbar(){
  __builtin_amdgcn_s_barrier();
  asm volatile("" ::: "memory");
}

// tanh-form GELU rewritten: 0.5x(1+tanh(u)) = x * rcp(1 + exp2(x*(c0 + c1*x^2)))
__device__ __forceinline__ float gelu_fast(float v){
  const float c0 = -2.302208157f;
  const float c1 = -0.102943238f;
  float w = v*v;
  float z = v * __builtin_fmaf(c1, w, c0);
  float t = __builtin_amdgcn_exp2f(z);
  return v * __builtin_amdgcn_rcpf(1.0f + t);
}

// ---------------- fp32 -> bf16 convert (vectorized: float4 -> short4) ----------------
__global__ void f32_to_bf16_k(const float4* __restrict__ in, short4* __restrict__ out, int n4){
  int i = blockIdx.x*256 + threadIdx.x;
  if (i < n4){
    float4 v = in[i];
    short4 o;
    o.x = f2bb(v.x); o.y = f2bb(v.y); o.z = f2bb(v.z); o.w = f2bb(v.w);
    out[i] = o;
  }
}

// ------- transpose+convert: in[K][N] f32 -> out[N][K] bf16 (LDS 32x32 tiles) -------
__global__ __launch_bounds__(256) void transpose_f32_bf16_k(const float* __restrict__ in,
    bf16* __restrict__ out, int K, int N){
  __shared__ float t[32][33];
  const int kb = blockIdx.y*32, nb = blockIdx.x*32;
  const int x = threadIdx.x & 31, y = threadIdx.x >> 5;
#pragma unroll
  for (int yy = y; yy < 32; yy += 8)
    t[yy][x] = in[(size_t)(kb+yy)*N + nb + x];
  __syncthreads();
#pragma unroll
  for (int yy = y; yy < 32; yy += 8)
    out[(size_t)(nb+yy)*K + kb + x] = f2b(t[x][yy]);
}

// ---- pack Wq/Wk/Wv [H,D,Dh] -> WcatT [3D][D] (n-major, k contiguous), biases -> bcat[3D] ----
__global__ void pack_qkv_t_k(const float* __restrict__ Wq, const float* __restrict__ bq,
                             const float* __restrict__ Wk, const float* __restrict__ bk,
                             const float* __restrict__ Wv, const float* __restrict__ bv,
                             bf16* __restrict__ Wt, float* __restrict__ bcat){
  int idx = blockIdx.x*256 + threadIdx.x;
  if (idx < 3*D_*D_){
    int n = idx / D_;
    int k = idx - n*D_;
    int which = n / D_;
    int cc = n - which*D_;
    int h = cc >> 6, e = cc & 63;
    const float* W = (which==0) ? Wq : ((which==1) ? Wk : Wv);
    Wt[idx] = f2b(W[((size_t)h*D_ + k)*DH_ + e]);
  }
  if (idx < 3*D_){
    int which = idx / D_;
    int cc = idx - which*D_;
    int h = cc >> 6, e = cc & 63;
    const float* bb = (which==0) ? bq : ((which==1) ? bk : bv);
    bcat[idx] = bb[h*DH_ + e];
  }
}

// ================= MFMA GEMM 256x256, BK=64, 8-phase counted-vmcnt schedule =================
// C[M,N] = A[M,K] @ Bt[N,K]^T.  8 waves (2M x 4N), per-wave 128x64 output.
// LDS: [2 dbuf][2 khalf][256 rows][32 cols] bf16 per operand = 64 KB each, 128 KB total.
#define STAGE_A(bufi_, kh_, kt_) do { \
    GLD16(gA  + (size_t)(kt_)*64 + (kh_)*32, asb + ((bufi_)<<15) + ((kh_)<<14)); \
    GLD16(gA2 + (size_t)(kt_)*64 + (kh_)*32, asb + ((bufi_)<<15) + ((kh_)<<14) + 8192); } while(0)
#define STAGE_B(bufi_, kh_, kt_) do { \
    GLD16(gB  + (size_t)(kt_)*64 + (kh_)*32, bsb + ((bufi_)<<15) + ((kh_)<<14)); \
    GLD16(gB2 + (size_t)(kt_)*64 + (kh_)*32, bsb + ((bufi_)<<15) + ((kh_)<<14) + 8192); } while(0)
#define AFRAG(bufi_, ks_, i_) (*(const bf16x8*)(AsB + ((bufi_)<<15) + ((ks_)<<14) + ((wm + (i_)*16 + l16)<<6) + fsw))
#define BFRAG(bufi_, ks_, j_) (*(const bf16x8*)(BsB + ((bufi_)<<15) + ((ks_)<<14) + ((wn + (j_)*16 + l16)<<6) + fsw))

template<int EPI>
__global__ __launch_bounds__(512, 2) void mgemm256_k(
    const bf16* __restrict__ A, const bf16* __restrict__ Bt,
    const float* __restrict__ bias, bf16* __restrict__ C,
    int M, int N, int K,
    bf16* __restrict__ qb, bf16* __restrict__ kbuf, _Float16* __restrict__ vt)
{
  __shared__ __align__(16) bf16 As[32768];  // [2 buf][2 kh][256 rows][32 cols]
  __shared__ __align__(16) bf16 Bs[32768];
  const int tid  = threadIdx.x;
  const int wave = tid >> 6, lane = tid & 63;
  const int quad = lane >> 4, l16 = lane & 15;
  const int wm = (wave >> 2) * 128;    // wave row block within 256-tile
  const int wn = (wave & 3) * 64;      // wave col block

  // XCD-aware remap (total blocks % 8 == 0 for all our launches)
  const int NX = gridDim.x;
  const int f  = blockIdx.y * NX + blockIdx.x;
  const int xcd = f & 7;
  const int j0  = f >> 3;
  const int bx  = j0 % NX;
  const int by  = (j0 / NX) * 8 + xcd;
  const int m0 = by * 256, n0 = bx * 256;

  // staging: thread t covers row t>>2 of a 128-row round, LDS slot t&3;
  // source chunk pre-swizzled: g = slot ^ ((row>>1)&3) = (t&3) ^ ((t>>3)&3)
  const int srow = tid >> 2;
  const int sg   = (tid & 3) ^ ((tid >> 3) & 3);
  const bf16* gA  = A  + (size_t)(m0 + srow)*K + sg*8;
  const bf16* gA2 = A  + (size_t)(m0 + 128 + srow)*K + sg*8;
  const bf16* gB  = Bt + (size_t)(n0 + srow)*K + sg*8;
  const bf16* gB2 = Bt + (size_t)(n0 + 128 + srow)*K + sg*8;
  const uintptr_t asb = (uintptr_t)(void*)As + (size_t)wave*1024;
  const uintptr_t bsb = (uintptr_t)(void*)Bs + (size_t)wave*1024;

  const char* AsB = (const char*)As;
  const char* BsB = (const char*)Bs;
  const int fsw = (quad ^ ((l16 >> 1) & 3)) * 16;  // swizzled 16B slot within 64B row

  f32x4 acc[8][4];
#pragma unroll
  for (int i=0;i<8;i++)
#pragma unroll
    for (int j2=0;j2<4;j2++) acc[i][j2] = (f32x4)0.f;

  const int KT = K >> 6;

  // prologue: stage tile 0 fully (issue order = consumption order), wait first 2 halves
  STAGE_A(0, 0, 0); STAGE_B(0, 0, 0); STAGE_A(0, 1, 0); STAGE_B(0, 1, 0);
  asm volatile("s_waitcnt vmcnt(4)" ::: "memory");
  wgbar();

  for (int kt = 0; kt < KT; ++kt){
    const int bufc = kt & 1, bufn = bufc ^ 1;
    const bool pf = (kt + 1) < KT;
    bf16x8 af[4], bfr[4];

    // -------- phase 0: khalf 0, rows i=0..3 --------
#pragma unroll
    for (int i=0;i<4;i++) af[i] = AFRAG(bufc, 0, i);
#pragma unroll
    for (int j2=0;j2<4;j2++) bfr[j2] = BFRAG(bufc, 0, j2);
    if (pf) STAGE_A(bufn, 0, kt+1);
    wgbar();
    __builtin_amdgcn_s_setprio(1);
#pragma unroll
    for (int i=0;i<4;i++)
#pragma unroll
      for (int j2=0;j2<4;j2++)
        acc[i][j2] = __builtin_amdgcn_mfma_f32_16x16x32_bf16(af[i], bfr[j2], acc[i][j2], 0, 0, 0);
    __builtin_amdgcn_s_setprio(0);
    wgbar();

    // -------- phase 1: khalf 0, rows i=4..7 --------
#pragma unroll
    for (int i=0;i<4;i++) af[i] = AFRAG(bufc, 0, 4+i);
    if (pf) STAGE_B(bufn, 0, kt+1);
    wgbar();
    __builtin_amdgcn_s_setprio(1);
#pragma unroll
    for (int i=0;i<4;i++)
#pragma unroll
      for (int j2=0;j2<4;j2++)
        acc[4+i][j2] = __builtin_amdgcn_mfma_f32_16x16x32_bf16(af[i], bfr[j2], acc[4+i][j2], 0, 0, 0);
    __builtin_amdgcn_s_setprio(0);
    if (pf) asm volatile("s_waitcnt vmcnt(4)" ::: "memory");
    else    asm volatile("s_waitcnt vmcnt(0)" ::: "memory");
    wgbar();

    // -------- phase 2: khalf 1, rows i=0..3 --------
#pragma unroll
    for (int i=0;i<4;i++) af[i] = AFRAG(bufc, 1, i);
#pragma unroll
    for (int j2=0;j2<4;j2++) bfr[j2] = BFRAG(bufc, 1, j2);
    if (pf) STAGE_A(bufn, 1, kt+1);
    wgbar();
    __builtin_amdgcn_s_setprio(1);
#pragma unroll
    for (int i=0;i<4;i++)
#pragma unroll
      for (int j2=0;j2<4;j2++)
        acc[i][j2] = __builtin_amdgcn_mfma_f32_16x16x32_bf16(af[i], bfr[j2], acc[i][j2], 0, 0, 0);
    __builtin_amdgcn_s_setprio(0);
    wgbar();

    // -------- phase 3: khalf 1, rows i=4..7 --------
#pragma unroll
    for (int i=0;i<4;i++) af[i] = AFRAG(bufc, 1, 4+i);
    if (pf) STAGE_B(bufn, 1, kt+1);
    wgbar();
    __builtin_amdgcn_s_setprio(1);
#pragma unroll
    for (int i=0;i<4;i++)
#pragma unroll
      for (int j2=0;j2<4;j2++)
        acc[4+i][j2] = __builtin_amdgcn_mfma_f32_16x16x32_bf16(af[i], bfr[j2], acc[4+i][j2], 0, 0, 0);
    __builtin_amdgcn_s_setprio(0);
    if (pf) asm volatile("s_waitcnt vmcnt(4)" ::: "memory");
    wgbar();
  }

  // -------- epilogue --------
#pragma unroll
  for (int i=0;i<8;i++){
#pragma unroll
    for (int j2=0;j2<4;j2++){
      const int n = n0 + wn + j2*16 + l16;
      const int m_base = m0 + wm + i*16 + quad*4;
      if (EPI == 0){
        const int which = n / D_;
        const int cc = n - which*D_;
        const int h = cc >> 6, e = cc & 63;
        if (which == 2){
          const int b = m_base >> 11, s = m_base & (S_-1);
          const int sl = s & 63;
          const int perm = ((sl>>2)&3)*16 + ((sl>>4)&3)*4;   // key-permuted V^T layout
          half4 hv;
#pragma unroll
          for (int r=0;r<4;r++) hv[r] = (_Float16)(acc[i][j2][r] + bias[n]);
          *(half4*)(vt + ((size_t)(b*H_+h)*DH_ + e)*S_ + (s & ~63) + perm) = hv;
        } else {
          bf16* dst = (which==0) ? qb : kbuf;
          // q: fold softmax 1/sqrt(64) AND log2(e) (exp2-domain softmax) into prescale
          const float sc2 = (which==0) ? 0.18033688f : 1.0f;
#pragma unroll
          for (int r=0;r<4;r++){
            const int m = m_base + r;
            const int b = m >> 11, s = m & (S_-1);
            dst[((size_t)(b*H_+h)*S_ + s)*DH_ + e] = f2b((acc[i][j2][r] + bias[n]) * sc2);
          }
        }
      } else {
#pragma unroll
        for (int r=0;r<4;r++){
          const int m = m_base + r;
          float v = acc[i][j2][r] + bias[n];
          C[(size_t)m*N + n] = f2b(gelu_fast(v));
        }
      }
    }
  }
}
#undef STAGE_A
#undef STAGE_B
#undef AFRAG
#undef BFRAG

// ---------------- MFMA GEMM 64x128, BK=64, double-buffered 2-phase counted-vmcnt ----------------
// (proj, FF2: N=768).  Per K-step: issue next tile's 6 global_load_lds BEFORE computing the
// current buffer; single vmcnt(0) + s_barrier per step (loads fly during MFMA).  LDS 48 KB.
// Swizzle: slot c of row r holds global chunk c ^ (r&7).  C = A@Bt^T + bias + aux (residual).
__global__ __launch_bounds__(256) void mgemm64_k(
    const bf16* __restrict__ A, const bf16* __restrict__ Bt,
    const float* __restrict__ bias, const bf16* __restrict__ aux,
    bf16* __restrict__ C, int M, int N, int K)
{
  __shared__ bf16 As[8192];    // [2][64][64]  16 KB
  __shared__ bf16 Bs[16384];   // [2][128][64] 32 KB
  const int tid  = threadIdx.x;
  const int wave = tid >> 6, lane = tid & 63;
  const int quad = lane >> 4, l16 = lane & 15;
  const int wm = (wave >> 1) * 32, wn = (wave & 1) * 64;

  const int NX = gridDim.x;
  const int f  = blockIdx.y * NX + blockIdx.x;
  const int xcd = f & 7;
  const int j   = f >> 3;
  const int bx  = j % NX;
  const int by  = (j / NX) * 8 + xcd;
  const int m0 = by * 64, n0 = bx * 128;

  const int srow8 = lane >> 3;                       // 0..7
  const int g     = (lane & 7) ^ srow8;              // global 16B-chunk within the row
  const bf16* gA0 = A  + (size_t)(m0 + wave*16 +      srow8)*K + g*8;
  const bf16* gA1 = A  + (size_t)(m0 + wave*16 +  8 + srow8)*K + g*8;
  const bf16* gB0 = Bt + (size_t)(n0 + wave*32 +      srow8)*K + g*8;
  const bf16* gB1 = Bt + (size_t)(n0 + wave*32 +  8 + srow8)*K + g*8;
  const bf16* gB2 = Bt + (size_t)(n0 + wave*32 + 16 + srow8)*K + g*8;
  const bf16* gB3 = Bt + (size_t)(n0 + wave*32 + 24 + srow8)*K + g*8;
  const uintptr_t asb = (uintptr_t)(void*)As + (size_t)wave*16*128;
  const uintptr_t bsb = (uintptr_t)(void*)Bs + (size_t)wave*32*128;

  f32x4 acc[2][4];
#pragma unroll
  for (int i=0;i<2;i++)
#pragma unroll
    for (int j2=0;j2<4;j2++) acc[i][j2] = (f32x4)0.f;

  const char* AsB = (const char*)As;
  const char* BsB = (const char*)Bs;
  const int KT = K >> 6;

  // prologue: stage tile 0 into buf0
  GLD16(gA0, asb);
  GLD16(gA1, asb + 1024);
  GLD16(gB0, bsb);
  GLD16(gB1, bsb + 1024);
  GLD16(gB2, bsb + 2048);
  GLD16(gB3, bsb + 3072);
  gA0 += 64; gA1 += 64; gB0 += 64; gB1 += 64; gB2 += 64; gB3 += 64;
  asm volatile("s_waitcnt vmcnt(0)" ::: "memory");
  wgbar();

  for (int kt = 0; kt < KT; ++kt){
    const int cur = kt & 1, nxt = cur ^ 1;
    const bool pf = (kt + 1) < KT;
    if (pf){
      const uintptr_t ao = asb + nxt*8192;
      const uintptr_t bo = bsb + nxt*16384;
      GLD16(gA0, ao);
      GLD16(gA1, ao + 1024);
      GLD16(gB0, bo);
      GLD16(gB1, bo + 1024);
      GLD16(gB2, bo + 2048);
      GLD16(gB3, bo + 3072);
      gA0 += 64; gA1 += 64; gB0 += 64; gB1 += 64; gB2 += 64; gB3 += 64;
    }
    const char* Ac = AsB + cur*8192;
    const char* Bc = BsB + cur*16384;
#pragma unroll
    for (int kq = 0; kq < 2; kq++){
      const int cbase = kq*4 + quad;
      bf16x8 af[2], bfr[4];
#pragma unroll
      for (int i=0;i<2;i++){
        const int m = wm + i*16 + l16;
        af[i] = *(const bf16x8*)(Ac + (m << 7) + ((cbase ^ (m & 7)) << 4));
      }
#pragma unroll
      for (int j2=0;j2<4;j2++){
        const int n = wn + j2*16 + l16;
        bfr[j2] = *(const bf16x8*)(Bc + (n << 7) + ((cbase ^ (n & 7)) << 4));
      }
#pragma unroll
      for (int i=0;i<2;i++)
#pragma unroll
        for (int j2=0;j2<4;j2++)
          acc[i][j2] = __builtin_amdgcn_mfma_f32_16x16x32_bf16(af[i], bfr[j2], acc[i][j2], 0, 0, 0);
    }
    if (pf) asm volatile("s_waitcnt vmcnt(0)" ::: "memory");
    wgbar();
  }

#pragma unroll
  for (int i=0;i<2;i++){
#pragma unroll
    for (int j2=0;j2<4;j2++){
      const int n = n0 + wn + j2*16 + l16;
      const int m_base = m0 + wm + i*16 + quad*4;
#pragma unroll
      for (int r=0;r<4;r++){
        const int m = m_base + r;
        float v = acc[i][j2][r] + bias[n] + b2f(aux[(size_t)m*N + n]);
        C[(size_t)m*N + n] = f2b(v);
      }
    }
  }
}

// ---------------- MFMA flash attention (exp2-domain softmax + defer-max) ----------------
// scores arrive already scaled by 1/sqrt(64)*log2(e) (folded into q in the QKV epilogue),
// so softmax uses raw exp2.  Defer-max (THR=8): skip alpha/rescale when the tile max is
// within 8 (log2) of the running max; P is then bounded by 2^8=256 (safe in f16).
__global__ __launch_bounds__(256) void fattn_k(const bf16* __restrict__ qb,
    const bf16* __restrict__ kb, const _Float16* __restrict__ vt, bf16* __restrict__ ctx)
{
  __shared__ __align__(16) char smem[19456];
  bf16     (*Ks)[72] = (bf16(*)[72])smem;                  // [64 keys][72] bf16
  _Float16 (*Vs)[72] = (_Float16(*)[72])(smem + 9216);     // [64 d][72 keys(permuted)] f16
  float* maxb  = (float*)(smem + 18432);                   // [2 kh][64 q]
  float* libuf = (float*)(smem + 18944);                   // [2 kh][64 q]
  float* Obuf  = (float*)smem;                             // alias (end)

  const int bh = blockIdx.x;
  const int qt = 31 - blockIdx.y;       // heavy tiles first
  const int q0 = qt * 64;
  const int tid = threadIdx.x;
  const int wave = tid >> 6, lane = tid & 63;
  const int quad = lane >> 4, l16 = lane & 15;
  const int kh = wave >> 1, qh = wave & 1;
  const size_t kbase = (size_t)bh * S_ * DH_;

  bf16x8 qf[2][2];
#pragma unroll
  for (int nf=0; nf<2; nf++)
#pragma unroll
    for (int h=0; h<2; h++)
      qf[nf][h] = *(const bf16x8*)(qb + kbase + (size_t)(q0 + qh*32 + nf*16 + l16)*DH_ + h*32 + quad*8);

  f32x4 o[4][2];
#pragma unroll
  for (int df=0; df<4; df++){ o[df][0] = (f32x4)0.f; o[df][1] = (f32x4)0.f; }
  float mi[2] = {-1e30f, -1e30f}, li[2] = {0.f, 0.f};

  for (int kt = 0; kt <= qt; ++kt){
    const int k0 = kt * 64;
    __syncthreads();
    { // stage K (natural) and V^T (permuted keys)
      const int r = tid >> 2, seg = (tid & 3) * 16;
      const bf16* ksrc = kb + kbase + (size_t)(k0 + r)*DH_ + seg;
      bf16x8 ka = *(const bf16x8*)ksrc;
      bf16x8 kc2 = *(const bf16x8*)(ksrc + 8);
      *(bf16x8*)&Ks[r][seg]   = ka;
      *(bf16x8*)&Ks[r][seg+8] = kc2;
      const _Float16* vsrc = vt + ((size_t)bh*DH_ + r)*S_ + k0 + seg;
      half8 va = *(const half8*)vsrc;
      half8 vb2 = *(const half8*)(vsrc + 8);
      *(half8*)&Vs[r][seg]   = va;
      *(half8*)&Vs[r][seg+8] = vb2;
    }
    __syncthreads();

    bf16x8 af[2][2];
#pragma unroll
    for (int mf=0; mf<2; mf++)
#pragma unroll
      for (int h=0; h<2; h++)
        af[mf][h] = *(const bf16x8*)&Ks[kh*32 + mf*16 + l16][h*32 + quad*8];
    f32x4 sc[2][2];
#pragma unroll
    for (int mf=0; mf<2; mf++)
#pragma unroll
      for (int nf=0; nf<2; nf++){
        f32x4 t = __builtin_amdgcn_mfma_f32_16x16x32_bf16(af[mf][0], qf[nf][0], (f32x4)0.f, 0, 0, 0);
        sc[mf][nf] = __builtin_amdgcn_mfma_f32_16x16x32_bf16(af[mf][1], qf[nf][1], t, 0, 0, 0);
      }

    if (kt == qt){
#pragma unroll
      for (int mf=0; mf<2; mf++){
        const int keyl = kh*32 + mf*16 + quad*4;
#pragma unroll
        for (int nf=0; nf<2; nf++){
          const int ql = qh*32 + nf*16 + l16;
#pragma unroll
          for (int r=0; r<4; r++)
            if (keyl + r > ql) sc[mf][nf][r] = -1e30f;
        }
      }
    }

    float mw[2];
#pragma unroll
    for (int nf=0; nf<2; nf++){
      float mx = -1e30f;
#pragma unroll
      for (int mf=0; mf<2; mf++)
#pragma unroll
        for (int r=0; r<4; r++) mx = fmaxf(mx, sc[mf][nf][r]);
      mx = fmaxf(mx, __shfl_xor(mx, 16));
      mx = fmaxf(mx, __shfl_xor(mx, 32));
      mw[nf] = mx;
    }
    if (quad == 0){
      maxb[kh*64 + qh*32 + l16]      = mw[0];
      maxb[kh*64 + qh*32 + 16 + l16] = mw[1];
    }
    __syncthreads();

    // full-tile max (both kh halves) — identical value in the kh=0/1 wave pair
    const float tm0 = fmaxf(mw[0], maxb[(1-kh)*64 + qh*32 + l16]);
    const float tm1 = fmaxf(mw[1], maxb[(1-kh)*64 + qh*32 + 16 + l16]);
    // defer-max: wave-uniform skip of the rescale pass (decision identical across the
    // kh pair since tm/mi evolve identically)
    const bool need = !__all((tm0 - mi[0] <= 8.f) && (tm1 - mi[1] <= 8.f));
    if (need){
      const float mn0 = fmaxf(mi[0], tm0);
      const float mn1 = fmaxf(mi[1], tm1);
      const float a0 = __builtin_amdgcn_exp2f(mi[0] - mn0);
      const float a1 = __builtin_amdgcn_exp2f(mi[1] - mn1);
      mi[0] = mn0; mi[1] = mn1;
      li[0] *= a0; li[1] *= a1;
#pragma unroll
      for (int df=0; df<4; df++)
#pragma unroll
        for (int r=0; r<4; r++){ o[df][0][r] *= a0; o[df][1][r] *= a1; }
    }

    half4 pf[2][2];
#pragma unroll
    for (int nf=0; nf<2; nf++){
      float rs = 0.f;
#pragma unroll
      for (int mf=0; mf<2; mf++)
#pragma unroll
        for (int r=0; r<4; r++){
          float p = __builtin_amdgcn_exp2f(sc[mf][nf][r] - mi[nf]);
          pf[mf][nf][r] = (_Float16)p;
          rs += p;
        }
      rs += __shfl_xor(rs, 16);
      rs += __shfl_xor(rs, 32);
      li[nf] += rs;
    }

#pragma unroll
    for (int df=0; df<4; df++){
      half8 vv = *(const half8*)&Vs[df*16 + l16][quad*16 + kh*8];
      half4 vlo = __builtin_shufflevector(vv, vv, 0,1,2,3);
      half4 vhi = __builtin_shufflevector(vv, vv, 4,5,6,7);
#pragma unroll
      for (int nf=0; nf<2; nf++){
        o[df][nf] = __builtin_amdgcn_mfma_f32_16x16x16f16(vlo, pf[0][nf], o[df][nf], 0, 0, 0);
        o[df][nf] = __builtin_amdgcn_mfma_f32_16x16x16f16(vhi, pf[1][nf], o[df][nf], 0, 0, 0);
      }
    }
  }

  __syncthreads();
  if (quad == 0){
    libuf[kh*64 + qh*32 + l16]      = li[0];
    libuf[kh*64 + qh*32 + 16 + l16] = li[1];
  }
  // kh halves may hold different running max — write per-half max too for the merge
  if (quad == 1){
    maxb[kh*64 + qh*32 + l16]      = mi[0];
    maxb[kh*64 + qh*32 + 16 + l16] = mi[1];
  }
  if (kh == 1){
#pragma unroll
    for (int df=0; df<4; df++)
#pragma unroll
      for (int nf=0; nf<2; nf++)
#pragma unroll
        for (int r=0; r<4; r++)
          Obuf[(qh*64 + df*16 + quad*4 + r)*33 + nf*16 + l16] = o[df][nf][r];
  }
  __syncthreads();
  if (kh == 0){
    const int b = bh / H_, h = bh - (bh / H_)*H_;
#pragma unroll
    for (int nf=0; nf<2; nf++){
      const int q64 = qh*32 + nf*16 + l16;
      // merge halves: both halves saw the same mi sequence (identical decisions), so
      // scales match; mi[] here equals the stored other-half max.
      const float inv = 1.0f / (libuf[q64] + libuf[64 + q64]);
      const int qtok = q0 + q64;
#pragma unroll
      for (int df=0; df<4; df++){
        short4 pk;
        float v0 = (o[df][nf][0] + Obuf[(qh*64 + df*16 + quad*4 + 0)*33 + nf*16 + l16]) * inv;
        float v1 = (o[df][nf][1] + Obuf[(qh*64 + df*16 + quad*4 + 1)*33 + nf*16 + l16]) * inv;
        float v2 = (o[df][nf][2] + Obuf[(qh*64 + df*16 + quad*4 + 2)*33 + nf*16 + l16]) * inv;
        float v3 = (o[df][nf][3] + Obuf[(qh*64 + df*16 + quad*4 + 3)*33 + nf*16 + l16]) * inv;
        pk.x = f2bb(v0); pk.y = f2bb(v1); pk.z = f2bb(v2); pk.w = f2bb(v3);
        *(short4*)((short*)ctx + ((size_t)(b*S_ + qtok))*D_ + h*DH_ + df*16 + quad*4) = pk;
      }
    }
  }
}

// ---------------- layernorm over D=768 (192 thr, short4 loads, 16B stores) ----------------
template<typename T> __device__ __forceinline__ void st4(T* p, size_t idx, float a, float b, float c, float d);
template<> __device__ __forceinline__ void st4<float>(float* p, size_t idx, float a, float b, float c, float d){
  float4 v; v.x=a; v.y=b; v.z=c; v.w=d; *(float4*)(p+idx) = v;
}
template<> __device__ __forceinline__ void st4<bf16>(bf16* p, size_t idx, float a, float b, float c, float d){
  short4 v; v.x=f2bb(a); v.y=f2bb(b); v.z=f2bb(c); v.w=f2bb(d); *(short4*)((short*)p+idx) = v;
}

template<typename OutT>
__global__ __launch_bounds__(192) void layernorm_k(const bf16* __restrict__ X,
    const float* __restrict__ g, const float* __restrict__ bta, OutT* __restrict__ Y)
{
  const int row = blockIdx.x;
  const int tid = threadIdx.x;
  const short4 raw = *(const short4*)((const short*)X + (size_t)row*D_ + tid*4);
  const float v0 = bs2f(raw.x), v1 = bs2f(raw.y), v2 = bs2f(raw.z), v3 = bs2f(raw.w);
  float s  = v0+v1+v2+v3;
  float s2 = v0*v0+v1*v1+v2*v2+v3*v3;
#pragma unroll
  for (int o = 32; o > 0; o >>= 1){ s += __shfl_down(s, o); s2 += __shfl_down(s2, o); }
  __shared__ float rs[3], rq[3];
  const int lane = tid & 63, w = tid >> 6;
  if (lane == 0){ rs[w] = s; rq[w] = s2; }
  __syncthreads();
  s  = rs[0]+rs[1]+rs[2];
  s2 = rq[0]+rq[1]+rq[2];
  const float mean = s * (1.0f/D_);
  const float var  = s2 * (1.0f/D_) - mean*mean;
  const float inv  = rsqrtf(var + 1e-5f);
  const float4 g4 = *(const float4*)(g + tid*4);
  const float4 b4 = *(const float4*)(bta + tid*4);
  st4(Y, (size_t)row*D_ + tid*4,
      (v0-mean)*inv*g4.x + b4.x,
      (v1-mean)*inv*g4.y + b4.y,
      (v2-mean)*inv*g4.z + b4.z,
      (v3-mean)*inv*g4.w + b4.w);
}

extern "C" void kernel_launch(void* const* d_in, const int* in_sizes, int n_in,
                              void* d_out, int out_size, void* d_ws, size_t ws_size,
                              hipStream_t stream)
{
  const float* x   = (const float*)d_in[0];
  const float* Wq  = (const float*)d_in[1];
  const float* bq  = (const float*)d_in[2];
  const float* Wk  = (const float*)d_in[3];
  const float* bk  = (const float*)d_in[4];
  const float* Wv  = (const float*)d_in[5];
  const float* bv  = (const float*)d_in[6];
  const float* Wo  = (const float*)d_in[7];
  const float* bo  = (const float*)d_in[8];
  const float* W1  = (const float*)d_in[9];
  const float* b1  = (const float*)d_in[10];
  const float* W2  = (const float*)d_in[11];
  const float* b2  = (const float*)d_in[12];
  const float* g1  = (const float*)d_in[13];
  const float* be1 = (const float*)d_in[14];
  const float* g2  = (const float*)d_in[15];
  const float* be2 = (const float*)d_in[16];
  float* out = (float*)d_out;

  char* ws = (char*)d_ws;
  size_t off = 0;
  auto alloc = [&](size_t bytes)->char*{
    char* p = ws + off; off = (off + bytes + 255) & ~(size_t)255; return p;
  };
  bf16*  xb    = (bf16*) alloc((size_t)NTOK*D_*2);
  bf16*  WcatT = (bf16*) alloc((size_t)3*D_*D_*2);
  float* bcat  = (float*)alloc((size_t)3*D_*4);
  bf16*  WoT   = (bf16*) alloc((size_t)D_*D_*2);
  bf16*  W1T   = (bf16*) alloc((size_t)F_*D_*2);
  bf16*  W2T   = (bf16*) alloc((size_t)D_*F_*2);
  bf16*  r1    = (bf16*) alloc((size_t)NTOK*F_*2);     // q,k,vt then ff1
  bf16*  qb    = r1;
  bf16*  kb    = r1 + (size_t)NTOK*D_;
  _Float16* vt = (_Float16*)(r1 + (size_t)2*NTOK*D_);  // [bh*64+d][S], f16, key-permuted
  bf16*  ff1   = r1;
  bf16*  ctxb  = (bf16*) alloc((size_t)NTOK*D_*2);     // ctx then y2
  bf16*  y1    = (bf16*) alloc((size_t)NTOK*D_*2);
  bf16*  hb    = (bf16*) alloc((size_t)NTOK*D_*2);
  bf16*  y2    = ctxb;

  f32_to_bf16_k<<<(NTOK*D_/4+255)/256, 256, 0, stream>>>(
      (const float4*)x, (short4*)xb, NTOK*D_/4);
  transpose_f32_bf16_k<<<dim3(D_/32, D_/32), 256, 0, stream>>>(Wo, WoT, D_, D_);
  transpose_f32_bf16_k<<<dim3(F_/32, D_/32), 256, 0, stream>>>(W1, W1T, D_, F_);
  transpose_f32_bf16_k<<<dim3(D_/32, F_/32), 256, 0, stream>>>(W2, W2T, F_, D_);
  pack_qkv_t_k<<<(3*D_*D_+255)/256, 256, 0, stream>>>(Wq,bq,Wk,bk,Wv,bv,WcatT,bcat);

  // 1) fused QKV projection (q pre-scaled 1/8*log2e; v written transposed+permuted f16)
  mgemm256_k<0><<<dim3(3*D_/256, NTOK/256), 512, 0, stream>>>(
      xb, WcatT, bcat, nullptr, NTOK, 3*D_, D_, qb, kb, vt);

  // 2) MFMA flash attention -> ctx [8192,768]
  fattn_k<<<dim3(BH_, S_/64), 256, 0, stream>>>(qb, kb, vt, ctxb);

  // 3) out-proj + residual: y1 = ctx@Wo + bo + x   (64x128 tiles, BK=64, dbuf)
  mgemm64_k<<<dim3(D_/128, NTOK/64), 256, 0, stream>>>(
      ctxb, WoT, bo, xb, y1, NTOK, D_, D_);

  // 4) LN1 -> h
  layernorm_k<bf16><<<NTOK, 192, 0, stream>>>(y1, g1, be1, hb);

  // 5) FF1 + fast GELU (256x256 8-phase)
  mgemm256_k<2><<<dim3(F_/256, NTOK/256), 512, 0, stream>>>(
      hb, W1T, b1, ff1, NTOK, F_, D_, nullptr, nullptr, nullptr);

  // 6) FF2 + residual: y2 = ff1@W2 + b2 + h   (64x128 tiles, BK=64, dbuf)
  mgemm64_k<<<dim3(D_/128, NTOK/64), 256, 0, stream>>>(
      ff1, W2T, b2, hb, y2, NTOK, D_, F_);

  // 7) LN2 -> out (fp32)
  layernorm_k<float><<<NTOK, 192, 0, stream>>>(y2, g2, be2, out);
}

// Round 4
// 398.070 us; speedup vs baseline: 1.0367x; 1.0082x over previous
//
#include <hip/hip_runtime.h>
#include <hip/hip_bf16.h>
#include <math.h>

#define B_ 4
#define S_ 2048
#define D_ 768
#define H_ 12
#define DH_ 64
#define F_ 3072
#define NTOK (B_*S_)   // 8192
#define BH_ (B_*H_)    // 48

typedef __hip_bfloat16 bf16;
typedef __attribute__((ext_vector_type(8))) short bf16x8;   // 8 bf16 = 4 VGPRs (MFMA A/B frag)
typedef __attribute__((ext_vector_type(4))) float f32x4;    // MFMA C/D frag
typedef __attribute__((ext_vector_type(4))) _Float16 half4;
typedef __attribute__((ext_vector_type(8))) _Float16 half8;
typedef __attribute__((ext_vector_type(2))) __fp16 fp16x2;  // cvt_pkrtz result type

// async global->LDS: 16 B/lane, lane i lands at ldsbase + i*16 (wave-uniform base)
#define GLD16(g, l) __builtin_amdgcn_global_load_lds( \
    (__attribute__((address_space(1))) void*)(uintptr_t)(g), \
    (__attribute__((address_space(3))) void*)(uintptr_t)(l), 16, 0, 0)

__device__ __forceinline__ float bs2f(short s){
  union { unsigned int u; float f; } cv; cv.u = ((unsigned int)(unsigned short)s) << 16; return cv.f;
}
__device__ __forceinline__ float b2f(bf16 v){ return __bfloat162float(v); }
__device__ __forceinline__ bf16 f2b(float v){ return __float2bfloat16(v); }
__device__ __forceinline__ short f2bb(float v){ bf16 b = f2b(v); short s; __builtin_memcpy(&s, &b, 2); return s; }

// pack 4 floats -> half4 via v_cvt_pkrtz_f16_f32 pairs
__device__ __forceinline__ half4 pk4(float p0, float p1, float p2, float p3){
  union { fp16x2 v2[2]; half4 v4; } u;
  u.v2[0] = __builtin_amdgcn_cvt_pkrtz(p0, p1);
  u.v2[1] = __builtin_amdgcn_cvt_pkrtz(p2, p3);
  return u.v4;
}

// raw workgroup barrier (no vmcnt(0) drain like __syncthreads) + compiler mem fence
__device__ __forceinline__ void wgbar(){
  __builtin_amdgcn_s_barrier();
  asm volatile("" ::: "memory");
}
// barrier that guarantees this wave's ds_writes are visible (lgkmcnt only, no vmcnt drain)
__device__ __forceinline__ void wgbar_lds(){
  asm volatile("s_waitcnt lgkmcnt(0)" ::: "memory");
  __builtin_amdgcn_s_barrier();
  asm volatile("" ::: "memory");
}

// tanh-form GELU rewritten: 0.5x(1+tanh(u)) = x * rcp(1 + exp2(x*(c0 + c1*x^2)))
__device__ __forceinline__ float gelu_fast(float v){
  const float c0 = -2.302208157f;
  const float c1 = -0.102943238f;
  float w = v*v;
  float z = v * __builtin_fmaf(c1, w, c0);
  float t = __builtin_amdgcn_exp2f(z);
  return v * __builtin_amdgcn_rcpf(1.0f + t);
}

// ---------------- fp32 -> bf16 convert (vectorized: float4 -> short4) ----------------
__global__ void f32_to_bf16_k(const float4* __restrict__ in, short4* __restrict__ out, int n4){
  int i = blockIdx.x*256 + threadIdx.x;
  if (i < n4){
    float4 v = in[i];
    short4 o;
    o.x = f2bb(v.x); o.y = f2bb(v.y); o.z = f2bb(v.z); o.w = f2bb(v.w);
    out[i] = o;
  }
}

// ------- transpose+convert: in[K][N] f32 -> out[N][K] bf16 (LDS 32x32 tiles) -------
__global__ __launch_bounds__(256) void transpose_f32_bf16_k(const float* __restrict__ in,
    bf16* __restrict__ out, int K, int N){
  __shared__ float t[32][33];
  const int kb = blockIdx.y*32, nb = blockIdx.x*32;
  const int x = threadIdx.x & 31, y = threadIdx.x >> 5;
#pragma unroll
  for (int yy = y; yy < 32; yy += 8)
    t[yy][x] = in[(size_t)(kb+yy)*N + nb + x];
  __syncthreads();
#pragma unroll
  for (int yy = y; yy < 32; yy += 8)
    out[(size_t)(nb+yy)*K + kb + x] = f2b(t[x][yy]);
}

// ---- pack Wq/Wk/Wv [H,D,Dh] -> WcatT [3D][D] (n-major, k contiguous), biases -> bcat[3D] ----
__global__ void pack_qkv_t_k(const float* __restrict__ Wq, const float* __restrict__ bq,
                             const float* __restrict__ Wk, const float* __restrict__ bk,
                             const float* __restrict__ Wv, const float* __restrict__ bv,
                             bf16* __restrict__ Wt, float* __restrict__ bcat){
  int idx = blockIdx.x*256 + threadIdx.x;
  if (idx < 3*D_*D_){
    int n = idx / D_;
    int k = idx - n*D_;
    int which = n / D_;
    int cc = n - which*D_;
    int h = cc >> 6, e = cc & 63;
    const float* W = (which==0) ? Wq : ((which==1) ? Wk : Wv);
    Wt[idx] = f2b(W[((size_t)h*D_ + k)*DH_ + e]);
  }
  if (idx < 3*D_){
    int which = idx / D_;
    int cc = idx - which*D_;
    int h = cc >> 6, e = cc & 63;
    const float* bb = (which==0) ? bq : ((which==1) ? bk : bv);
    bcat[idx] = bb[h*DH_ + e];
  }
}

// ================= MFMA GEMM 256x256, BK=64, 8-phase counted-vmcnt schedule =================
// C[M,N] = A[M,K] @ Bt[N,K]^T.  8 waves (2M x 4N), per-wave 128x64 output.
// LDS: [2 dbuf][2 khalf][256 rows][32 cols] bf16 per operand = 64 KB each, 128 KB total.
#define STAGE_A(bufi_, kh_, kt_) do { \
    GLD16(gA  + (size_t)(kt_)*64 + (kh_)*32, asb + ((bufi_)<<15) + ((kh_)<<14)); \
    GLD16(gA2 + (size_t)(kt_)*64 + (kh_)*32, asb + ((bufi_)<<15) + ((kh_)<<14) + 8192); } while(0)
#define STAGE_B(bufi_, kh_, kt_) do { \
    GLD16(gB  + (size_t)(kt_)*64 + (kh_)*32, bsb + ((bufi_)<<15) + ((kh_)<<14)); \
    GLD16(gB2 + (size_t)(kt_)*64 + (kh_)*32, bsb + ((bufi_)<<15) + ((kh_)<<14) + 8192); } while(0)
#define AFRAG(bufi_, ks_, i_) (*(const bf16x8*)(AsB + ((bufi_)<<15) + ((ks_)<<14) + ((wm + (i_)*16 + l16)<<6) + fsw))
#define BFRAG(bufi_, ks_, j_) (*(const bf16x8*)(BsB + ((bufi_)<<15) + ((ks_)<<14) + ((wn + (j_)*16 + l16)<<6) + fsw))

template<int EPI>
__global__ __launch_bounds__(512, 2) void mgemm256_k(
    const bf16* __restrict__ A, const bf16* __restrict__ Bt,
    const float* __restrict__ bias, bf16* __restrict__ C,
    int M, int N, int K,
    bf16* __restrict__ qb, bf16* __restrict__ kbuf, _Float16* __restrict__ vt)
{
  __shared__ __align__(16) bf16 As[32768];  // [2 buf][2 kh][256 rows][32 cols]
  __shared__ __align__(16) bf16 Bs[32768];
  const int tid  = threadIdx.x;
  const int wave = tid >> 6, lane = tid & 63;
  const int quad = lane >> 4, l16 = lane & 15;
  const int wm = (wave >> 2) * 128;    // wave row block within 256-tile
  const int wn = (wave & 3) * 64;      // wave col block

  // XCD-aware remap (total blocks % 8 == 0 for all our launches)
  const int NX = gridDim.x;
  const int f  = blockIdx.y * NX + blockIdx.x;
  const int xcd = f & 7;
  const int j0  = f >> 3;
  const int bx  = j0 % NX;
  const int by  = (j0 / NX) * 8 + xcd;
  const int m0 = by * 256, n0 = bx * 256;

  // staging: thread t covers row t>>2 of a 128-row round, LDS slot t&3;
  // source chunk pre-swizzled: g = slot ^ ((row>>1)&3) = (t&3) ^ ((t>>3)&3)
  const int srow = tid >> 2;
  const int sg   = (tid & 3) ^ ((tid >> 3) & 3);
  const bf16* gA  = A  + (size_t)(m0 + srow)*K + sg*8;
  const bf16* gA2 = A  + (size_t)(m0 + 128 + srow)*K + sg*8;
  const bf16* gB  = Bt + (size_t)(n0 + srow)*K + sg*8;
  const bf16* gB2 = Bt + (size_t)(n0 + 128 + srow)*K + sg*8;
  const uintptr_t asb = (uintptr_t)(void*)As + (size_t)wave*1024;
  const uintptr_t bsb = (uintptr_t)(void*)Bs + (size_t)wave*1024;

  const char* AsB = (const char*)As;
  const char* BsB = (const char*)Bs;
  const int fsw = (quad ^ ((l16 >> 1) & 3)) * 16;  // swizzled 16B slot within 64B row

  f32x4 acc[8][4];
#pragma unroll
  for (int i=0;i<8;i++)
#pragma unroll
    for (int j2=0;j2<4;j2++) acc[i][j2] = (f32x4)0.f;

  const int KT = K >> 6;

  // prologue: stage tile 0 fully (issue order = consumption order), wait first 2 halves
  STAGE_A(0, 0, 0); STAGE_B(0, 0, 0); STAGE_A(0, 1, 0); STAGE_B(0, 1, 0);
  asm volatile("s_waitcnt vmcnt(4)" ::: "memory");
  wgbar();

  for (int kt = 0; kt < KT; ++kt){
    const int bufc = kt & 1, bufn = bufc ^ 1;
    const bool pf = (kt + 1) < KT;
    bf16x8 af[4], bfr[4];

    // -------- phase 0: khalf 0, rows i=0..3 --------
#pragma unroll
    for (int i=0;i<4;i++) af[i] = AFRAG(bufc, 0, i);
#pragma unroll
    for (int j2=0;j2<4;j2++) bfr[j2] = BFRAG(bufc, 0, j2);
    if (pf) STAGE_A(bufn, 0, kt+1);
    wgbar();
    __builtin_amdgcn_s_setprio(1);
#pragma unroll
    for (int i=0;i<4;i++)
#pragma unroll
      for (int j2=0;j2<4;j2++)
        acc[i][j2] = __builtin_amdgcn_mfma_f32_16x16x32_bf16(af[i], bfr[j2], acc[i][j2], 0, 0, 0);
    __builtin_amdgcn_s_setprio(0);
    wgbar();

    // -------- phase 1: khalf 0, rows i=4..7 --------
#pragma unroll
    for (int i=0;i<4;i++) af[i] = AFRAG(bufc, 0, 4+i);
    if (pf) STAGE_B(bufn, 0, kt+1);
    wgbar();
    __builtin_amdgcn_s_setprio(1);
#pragma unroll
    for (int i=0;i<4;i++)
#pragma unroll
      for (int j2=0;j2<4;j2++)
        acc[4+i][j2] = __builtin_amdgcn_mfma_f32_16x16x32_bf16(af[i], bfr[j2], acc[4+i][j2], 0, 0, 0);
    __builtin_amdgcn_s_setprio(0);
    if (pf) asm volatile("s_waitcnt vmcnt(4)" ::: "memory");
    else    asm volatile("s_waitcnt vmcnt(0)" ::: "memory");
    wgbar();

    // -------- phase 2: khalf 1, rows i=0..3 --------
#pragma unroll
    for (int i=0;i<4;i++) af[i] = AFRAG(bufc, 1, i);
#pragma unroll
    for (int j2=0;j2<4;j2++) bfr[j2] = BFRAG(bufc, 1, j2);
    if (pf) STAGE_A(bufn, 1, kt+1);
    wgbar();
    __builtin_amdgcn_s_setprio(1);
#pragma unroll
    for (int i=0;i<4;i++)
#pragma unroll
      for (int j2=0;j2<4;j2++)
        acc[i][j2] = __builtin_amdgcn_mfma_f32_16x16x32_bf16(af[i], bfr[j2], acc[i][j2], 0, 0, 0);
    __builtin_amdgcn_s_setprio(0);
    wgbar();

    // -------- phase 3: khalf 1, rows i=4..7 --------
#pragma unroll
    for (int i=0;i<4;i++) af[i] = AFRAG(bufc, 1, 4+i);
    if (pf) STAGE_B(bufn, 1, kt+1);
    wgbar();
    __builtin_amdgcn_s_setprio(1);
#pragma unroll
    for (int i=0;i<4;i++)
#pragma unroll
      for (int j2=0;j2<4;j2++)
        acc[4+i][j2] = __builtin_amdgcn_mfma_f32_16x16x32_bf16(af[i], bfr[j2], acc[4+i][j2], 0, 0, 0);
    __builtin_amdgcn_s_setprio(0);
    if (pf) asm volatile("s_waitcnt vmcnt(4)" ::: "memory");
    wgbar();
  }

  // -------- epilogue --------
#pragma unroll
  for (int i=0;i<8;i++){
#pragma unroll
    for (int j2=0;j2<4;j2++){
      const int n = n0 + wn + j2*16 + l16;
      const int m_base = m0 + wm + i*16 + quad*4;
      if (EPI == 0){
        const int which = n / D_;
        const int cc = n - which*D_;
        const int h = cc >> 6, e = cc & 63;
        if (which == 2){
          const int b = m_base >> 11, s = m_base & (S_-1);
          const int sl = s & 63;
          const int perm = ((sl>>2)&3)*16 + ((sl>>4)&3)*4;   // key-permuted V^T layout
          half4 hv;
#pragma unroll
          for (int r=0;r<4;r++) hv[r] = (_Float16)(acc[i][j2][r] + bias[n]);
          *(half4*)(vt + ((size_t)(b*H_+h)*DH_ + e)*S_ + (s & ~63) + perm) = hv;
        } else {
          bf16* dst = (which==0) ? qb : kbuf;
          // q: fold softmax 1/sqrt(64) AND log2(e) (exp2-domain softmax) into prescale
          const float sc2 = (which==0) ? 0.18033688f : 1.0f;
#pragma unroll
          for (int r=0;r<4;r++){
            const int m = m_base + r;
            const int b = m >> 11, s = m & (S_-1);
            dst[((size_t)(b*H_+h)*S_ + s)*DH_ + e] = f2b((acc[i][j2][r] + bias[n]) * sc2);
          }
        }
      } else {
#pragma unroll
        for (int r=0;r<4;r++){
          const int m = m_base + r;
          float v = acc[i][j2][r] + bias[n];
          C[(size_t)m*N + n] = f2b(gelu_fast(v));
        }
      }
    }
  }
}
#undef STAGE_A
#undef STAGE_B
#undef AFRAG
#undef BFRAG

// ---------------- MFMA GEMM 128x128, BK=64, double-buffered 2-phase counted-vmcnt ----------------
// (proj, FF2: N=768).  4 waves (2x2), per-wave 64x64 out, 32 MFMA per K-step per wave
// (2x the work per barrier of the old 64x128 tile at 64 F/B arithmetic intensity).
// Per K-step: issue next tile's 8 global_load_lds BEFORE computing the current buffer;
// single vmcnt(0) + s_barrier per step.  LDS 64 KB -> 2 blocks/CU; grid 384 co-resident.
// Swizzle: slot c of row r holds global chunk c ^ (r&7).  C = A@Bt^T + bias + aux (residual).
__global__ __launch_bounds__(256) void mgemm128_k(
    const bf16* __restrict__ A, const bf16* __restrict__ Bt,
    const float* __restrict__ bias, const bf16* __restrict__ aux,
    bf16* __restrict__ C, int M, int N, int K)
{
  __shared__ __align__(16) bf16 As[16384];   // [2][128][64] 32 KB
  __shared__ __align__(16) bf16 Bs[16384];   // [2][128][64] 32 KB
  const int tid  = threadIdx.x;
  const int wave = tid >> 6, lane = tid & 63;
  const int quad = lane >> 4, l16 = lane & 15;
  const int wm = (wave >> 1) * 64, wn = (wave & 1) * 64;

  const int NX = gridDim.x;
  const int f  = blockIdx.y * NX + blockIdx.x;
  const int xcd = f & 7;
  const int j   = f >> 3;
  const int bx  = j % NX;
  const int by  = (j / NX) * 8 + xcd;
  const int m0 = by * 128, n0 = bx * 128;

  const int srow8 = lane >> 3;                       // 0..7
  const int g     = (lane & 7) ^ srow8;              // global 16B-chunk within the row
  // wave w stages rows w*32 + t*8 + srow8 (t=0..3) for both A and B
  const bf16* gA = A  + (size_t)(m0 + wave*32 + srow8)*K + g*8;
  const bf16* gB = Bt + (size_t)(n0 + wave*32 + srow8)*K + g*8;
  const uintptr_t asb = (uintptr_t)(void*)As + (size_t)wave*32*128;
  const uintptr_t bsb = (uintptr_t)(void*)Bs + (size_t)wave*32*128;

  f32x4 acc[4][4];
#pragma unroll
  for (int i=0;i<4;i++)
#pragma unroll
    for (int j2=0;j2<4;j2++) acc[i][j2] = (f32x4)0.f;

  const char* AsB = (const char*)As;
  const char* BsB = (const char*)Bs;
  const int KT = K >> 6;

  // prologue: stage tile 0 into buf0
#pragma unroll
  for (int t=0;t<4;t++){
    GLD16(gA + (size_t)t*8*K, asb + t*1024);
    GLD16(gB + (size_t)t*8*K, bsb + t*1024);
  }
  gA += 64; gB += 64;
  asm volatile("s_waitcnt vmcnt(0)" ::: "memory");
  wgbar();

  for (int kt = 0; kt < KT; ++kt){
    const int cur = kt & 1, nxt = cur ^ 1;
    const bool pf = (kt + 1) < KT;
    if (pf){
      const uintptr_t ao = asb + (size_t)nxt*16384;
      const uintptr_t bo = bsb + (size_t)nxt*16384;
#pragma unroll
      for (int t=0;t<4;t++){
        GLD16(gA + (size_t)t*8*K, ao + t*1024);
        GLD16(gB + (size_t)t*8*K, bo + t*1024);
      }
      gA += 64; gB += 64;
    }
    const char* Ac = AsB + (size_t)cur*16384;
    const char* Bc = BsB + (size_t)cur*16384;
#pragma unroll
    for (int kq = 0; kq < 2; kq++){
      const int cbase = kq*4 + quad;
      bf16x8 af[4], bfr[4];
#pragma unroll
      for (int i=0;i<4;i++){
        const int m = wm + i*16 + l16;
        af[i] = *(const bf16x8*)(Ac + (m << 7) + ((cbase ^ (m & 7)) << 4));
      }
#pragma unroll
      for (int j2=0;j2<4;j2++){
        const int n = wn + j2*16 + l16;
        bfr[j2] = *(const bf16x8*)(Bc + (n << 7) + ((cbase ^ (n & 7)) << 4));
      }
#pragma unroll
      for (int i=0;i<4;i++)
#pragma unroll
        for (int j2=0;j2<4;j2++)
          acc[i][j2] = __builtin_amdgcn_mfma_f32_16x16x32_bf16(af[i], bfr[j2], acc[i][j2], 0, 0, 0);
    }
    if (pf) asm volatile("s_waitcnt vmcnt(0)" ::: "memory");
    wgbar();
  }

#pragma unroll
  for (int i=0;i<4;i++){
#pragma unroll
    for (int j2=0;j2<4;j2++){
      const int n = n0 + wn + j2*16 + l16;
      const int m_base = m0 + wm + i*16 + quad*4;
#pragma unroll
      for (int r=0;r<4;r++){
        const int m = m_base + r;
        float v = acc[i][j2][r] + bias[n] + b2f(aux[(size_t)m*N + n]);
        C[(size_t)m*N + n] = f2b(v);
      }
    }
  }
}

// ---------------- MFMA flash attention: 1 barrier/tile, K dbuf + V tribuf + T14 ----------------
// exp2-domain softmax (1/sqrt(64)*log2e folded into q) + defer-max (THR=8).
// Pipeline per tile kt: [QK^T from K(kt) | local max | write maxb(kt&1) | ds_write next tile
// from regs | issue loads for kt+2] -> barrier -> [read other-half max | P | PV from V(kt)].
// Buffer safety: K read(kt) pre-bar, K write(kt+1) next interval -> 2 bufs OK.
// V read(kt) POST-bar overlaps V write(kt+2) interval -> 3 bufs required. maxb: 2 bufs.
__global__ __launch_bounds__(256) void fattn_k(const bf16* __restrict__ qb,
    const bf16* __restrict__ kb, const _Float16* __restrict__ vt, bf16* __restrict__ ctx)
{
  __shared__ __align__(16) char smem[47616];
  typedef bf16     KsRow[72];
  typedef _Float16 VsRow[72];
  KsRow* kp0 = (KsRow*)(smem);            // K buf A [64][72] bf16 (9216 B)
  KsRow* kp1 = (KsRow*)(smem + 9216);     // K buf B
  VsRow* vp0 = (VsRow*)(smem + 18432);    // V bufs [64 d][72 keys(permuted)] f16
  VsRow* vp1 = (VsRow*)(smem + 27648);
  VsRow* vp2 = (VsRow*)(smem + 36864);
  float* maxb  = (float*)(smem + 46080);  // [2 bufs][2 kh][64 q]
  float* libuf = (float*)(smem + 47104);  // [2 kh][64 q]
  float* Obuf  = (float*)smem;            // epilogue alias (16896 B < 18432)

  const int bh = blockIdx.x;
  const int qt = 31 - blockIdx.y;       // heavy tiles first
  const int q0 = qt * 64;
  const int tid = threadIdx.x;
  const int wave = tid >> 6, lane = tid & 63;
  const int quad = lane >> 4, l16 = lane & 15;
  const int kh = wave >> 1, qh = wave & 1;
  const size_t kbase = (size_t)bh * S_ * DH_;
  const int nt = qt + 1;

  const int sr  = tid >> 2;            // staging row 0..63
  const int seg = (tid & 3) * 16;      // staging col 0,16,32,48

  bf16x8 qf[2][2];
#pragma unroll
  for (int nf=0; nf<2; nf++)
#pragma unroll
    for (int h=0; h<2; h++)
      qf[nf][h] = *(const bf16x8*)(qb + kbase + (size_t)(q0 + qh*32 + nf*16 + l16)*DH_ + h*32 + quad*8);

  f32x4 o[4][2];
#pragma unroll
  for (int df=0; df<4; df++){ o[df][0] = (f32x4)0.f; o[df][1] = (f32x4)0.f; }
  float mi[2] = {-1e30f, -1e30f}, li[2] = {0.f, 0.f};

  // ---- prologue: tile 0 -> LDS (kp0/vp0); tile 1 -> regs ----
  bf16x8 ka0, ka1; half8 va0, va1;
  {
    const bf16* ks = kb + kbase + (size_t)sr*DH_ + seg;
    ka0 = *(const bf16x8*)ks; ka1 = *(const bf16x8*)(ks + 8);
    const _Float16* vs = vt + ((size_t)bh*DH_ + sr)*S_ + seg;
    va0 = *(const half8*)vs; va1 = *(const half8*)(vs + 8);
  }
  *(bf16x8*)&kp0[sr][seg]   = ka0;
  *(bf16x8*)&kp0[sr][seg+8] = ka1;
  *(half8*)&vp0[sr][seg]    = va0;
  *(half8*)&vp0[sr][seg+8]  = va1;
  if (nt > 1){
    const bf16* ks = kb + kbase + (size_t)(64 + sr)*DH_ + seg;
    ka0 = *(const bf16x8*)ks; ka1 = *(const bf16x8*)(ks + 8);
    const _Float16* vs = vt + ((size_t)bh*DH_ + sr)*S_ + 64 + seg;
    va0 = *(const half8*)vs; va1 = *(const half8*)(vs + 8);
  }
  wgbar_lds();

  for (int kt = 0; kt < nt; ++kt){
    // -------- pre-barrier: QK^T(kt) from kp0, local max, stage kt+1, load kt+2 --------
    bf16x8 af[2][2];
#pragma unroll
    for (int mf=0; mf<2; mf++)
#pragma unroll
      for (int h=0; h<2; h++)
        af[mf][h] = *(const bf16x8*)&kp0[kh*32 + mf*16 + l16][h*32 + quad*8];
    f32x4 sc[2][2];
#pragma unroll
    for (int mf=0; mf<2; mf++)
#pragma unroll
      for (int nf=0; nf<2; nf++){
        f32x4 t = __builtin_amdgcn_mfma_f32_16x16x32_bf16(af[mf][0], qf[nf][0], (f32x4)0.f, 0, 0, 0);
        sc[mf][nf] = __builtin_amdgcn_mfma_f32_16x16x32_bf16(af[mf][1], qf[nf][1], t, 0, 0, 0);
      }

    if (kt == qt){
#pragma unroll
      for (int mf=0; mf<2; mf++){
        const int keyl = kh*32 + mf*16 + quad*4;
#pragma unroll
        for (int nf=0; nf<2; nf++){
          const int ql = qh*32 + nf*16 + l16;
#pragma unroll
          for (int r=0; r<4; r++)
            if (keyl + r > ql) sc[mf][nf][r] = -1e30f;
        }
      }
    }

    float mw[2];
#pragma unroll
    for (int nf=0; nf<2; nf++){
      float mx = -1e30f;
#pragma unroll
      for (int mf=0; mf<2; mf++)
#pragma unroll
        for (int r=0; r<4; r++) mx = fmaxf(mx, sc[mf][nf][r]);
      mx = fmaxf(mx, __shfl_xor(mx, 16));
      mx = fmaxf(mx, __shfl_xor(mx, 32));
      mw[nf] = mx;
    }
    float* mb = maxb + (kt & 1)*128;
    if (quad == 0){
      mb[kh*64 + qh*32 + l16]      = mw[0];
      mb[kh*64 + qh*32 + 16 + l16] = mw[1];
    }

    if (kt + 1 < nt){
      // write staged regs (tile kt+1) -> kp1 / vp1
      *(bf16x8*)&kp1[sr][seg]   = ka0;
      *(bf16x8*)&kp1[sr][seg+8] = ka1;
      *(half8*)&vp1[sr][seg]    = va0;
      *(half8*)&vp1[sr][seg+8]  = va1;
      if (kt + 2 < nt){
        const int k0n = (kt + 2) * 64;
        const bf16* ks = kb + kbase + (size_t)(k0n + sr)*DH_ + seg;
        ka0 = *(const bf16x8*)ks; ka1 = *(const bf16x8*)(ks + 8);
        const _Float16* vs = vt + ((size_t)bh*DH_ + sr)*S_ + k0n + seg;
        va0 = *(const half8*)vs; va1 = *(const half8*)(vs + 8);
      }
    }
    wgbar_lds();

    // -------- post-barrier: cross-half max, defer-max, P, PV from vp0 --------
    const float tm0 = fmaxf(mw[0], mb[(1-kh)*64 + qh*32 + l16]);
    const float tm1 = fmaxf(mw[1], mb[(1-kh)*64 + qh*32 + 16 + l16]);
    const bool need = !__all((tm0 - mi[0] <= 8.f) && (tm1 - mi[1] <= 8.f));
    if (need){
      const float mn0 = fmaxf(mi[0], tm0);
      const float mn1 = fmaxf(mi[1], tm1);
      const float a0 = __builtin_amdgcn_exp2f(mi[0] - mn0);
      const float a1 = __builtin_amdgcn_exp2f(mi[1] - mn1);
      mi[0] = mn0; mi[1] = mn1;
      li[0] *= a0; li[1] *= a1;
#pragma unroll
      for (int df=0; df<4; df++)
#pragma unroll
        for (int r=0; r<4; r++){ o[df][0][r] *= a0; o[df][1][r] *= a1; }
    }

    half4 pfr[2][2];
#pragma unroll
    for (int nf=0; nf<2; nf++){
      float rs = 0.f;
#pragma unroll
      for (int mf=0; mf<2; mf++){
        const float p0 = __builtin_amdgcn_exp2f(sc[mf][nf][0] - mi[nf]);
        const float p1 = __builtin_amdgcn_exp2f(sc[mf][nf][1] - mi[nf]);
        const float p2 = __builtin_amdgcn_exp2f(sc[mf][nf][2] - mi[nf]);
        const float p3 = __builtin_amdgcn_exp2f(sc[mf][nf][3] - mi[nf]);
        rs += (p0 + p1) + (p2 + p3);
        pfr[mf][nf] = pk4(p0, p1, p2, p3);
      }
      rs += __shfl_xor(rs, 16);
      rs += __shfl_xor(rs, 32);
      li[nf] += rs;
    }

#pragma unroll
    for (int df=0; df<4; df++){
      half8 vv = *(const half8*)&vp0[df*16 + l16][quad*16 + kh*8];
      half4 vlo = __builtin_shufflevector(vv, vv, 0,1,2,3);
      half4 vhi = __builtin_shufflevector(vv, vv, 4,5,6,7);
#pragma unroll
      for (int nf=0; nf<2; nf++){
        o[df][nf] = __builtin_amdgcn_mfma_f32_16x16x16f16(vlo, pfr[0][nf], o[df][nf], 0, 0, 0);
        o[df][nf] = __builtin_amdgcn_mfma_f32_16x16x16f16(vhi, pfr[1][nf], o[df][nf], 0, 0, 0);
      }
    }

    // rotate buffers: K 2-cycle, V 3-cycle
    { KsRow* t_ = kp0; kp0 = kp1; kp1 = t_; }
    { VsRow* t_ = vp0; vp0 = vp1; vp1 = vp2; vp2 = t_; }
  }

  __syncthreads();
  if (quad == 0){
    libuf[kh*64 + qh*32 + l16]      = li[0];
    libuf[kh*64 + qh*32 + 16 + l16] = li[1];
  }
  if (kh == 1){
#pragma unroll
    for (int df=0; df<4; df++)
#pragma unroll
      for (int nf=0; nf<2; nf++)
#pragma unroll
        for (int r=0; r<4; r++)
          Obuf[(qh*64 + df*16 + quad*4 + r)*33 + nf*16 + l16] = o[df][nf][r];
  }
  __syncthreads();
  if (kh == 0){
    const int b = bh / H_, h = bh - (bh / H_)*H_;
#pragma unroll
    for (int nf=0; nf<2; nf++){
      const int q64 = qh*32 + nf*16 + l16;
      // both kh halves applied identical defer-max decisions -> same mi -> li directly addable
      const float inv = 1.0f / (libuf[q64] + libuf[64 + q64]);
      const int qtok = q0 + q64;
#pragma unroll
      for (int df=0; df<4; df++){
        short4 pk;
        float v0 = (o[df][nf][0] + Obuf[(qh*64 + df*16 + quad*4 + 0)*33 + nf*16 + l16]) * inv;
        float v1 = (o[df][nf][1] + Obuf[(qh*64 + df*16 + quad*4 + 1)*33 + nf*16 + l16]) * inv;
        float v2 = (o[df][nf][2] + Obuf[(qh*64 + df*16 + quad*4 + 2)*33 + nf*16 + l16]) * inv;
        float v3 = (o[df][nf][3] + Obuf[(qh*64 + df*16 + quad*4 + 3)*33 + nf*16 + l16]) * inv;
        pk.x = f2bb(v0); pk.y = f2bb(v1); pk.z = f2bb(v2); pk.w = f2bb(v3);
        *(short4*)((short*)ctx + ((size_t)(b*S_ + qtok))*D_ + h*DH_ + df*16 + quad*4) = pk;
      }
    }
  }
}

// ---------------- layernorm over D=768 (192 thr, short4 loads, 16B stores) ----------------
template<typename T> __device__ __forceinline__ void st4(T* p, size_t idx, float a, float b, float c, float d);
template<> __device__ __forceinline__ void st4<float>(float* p, size_t idx, float a, float b, float c, float d){
  float4 v; v.x=a; v.y=b; v.z=c; v.w=d; *(float4*)(p+idx) = v;
}
template<> __device__ __forceinline__ void st4<bf16>(bf16* p, size_t idx, float a, float b, float c, float d){
  short4 v; v.x=f2bb(a); v.y=f2bb(b); v.z=f2bb(c); v.w=f2bb(d); *(short4*)((short*)p+idx) = v;
}

template<typename OutT>
__global__ __launch_bounds__(192) void layernorm_k(const bf16* __restrict__ X,
    const float* __restrict__ g, const float* __restrict__ bta, OutT* __restrict__ Y)
{
  const int row = blockIdx.x;
  const int tid = threadIdx.x;
  const short4 raw = *(const short4*)((const short*)X + (size_t)row*D_ + tid*4);
  const float v0 = bs2f(raw.x), v1 = bs2f(raw.y), v2 = bs2f(raw.z), v3 = bs2f(raw.w);
  float s  = v0+v1+v2+v3;
  float s2 = v0*v0+v1*v1+v2*v2+v3*v3;
#pragma unroll
  for (int o = 32; o > 0; o >>= 1){ s += __shfl_down(s, o); s2 += __shfl_down(s2, o); }
  __shared__ float rs[3], rq[3];
  const int lane = tid & 63, w = tid >> 6;
  if (lane == 0){ rs[w] = s; rq[w] = s2; }
  __syncthreads();
  s  = rs[0]+rs[1]+rs[2];
  s2 = rq[0]+rq[1]+rq[2];
  const float mean = s * (1.0f/D_);
  const float var  = s2 * (1.0f/D_) - mean*mean;
  const float inv  = rsqrtf(var + 1e-5f);
  const float4 g4 = *(const float4*)(g + tid*4);
  const float4 b4 = *(const float4*)(bta + tid*4);
  st4(Y, (size_t)row*D_ + tid*4,
      (v0-mean)*inv*g4.x + b4.x,
      (v1-mean)*inv*g4.y + b4.y,
      (v2-mean)*inv*g4.z + b4.z,
      (v3-mean)*inv*g4.w + b4.w);
}

extern "C" void kernel_launch(void* const* d_in, const int* in_sizes, int n_in,
                              void* d_out, int out_size, void* d_ws, size_t ws_size,
                              hipStream_t stream)
{
  const float* x   = (const float*)d_in[0];
  const float* Wq  = (const float*)d_in[1];
  const float* bq  = (const float*)d_in[2];
  const float* Wk  = (const float*)d_in[3];
  const float* bk  = (const float*)d_in[4];
  const float* Wv  = (const float*)d_in[5];
  const float* bv  = (const float*)d_in[6];
  const float* Wo  = (const float*)d_in[7];
  const float* bo  = (const float*)d_in[8];
  const float* W1  = (const float*)d_in[9];
  const float* b1  = (const float*)d_in[10];
  const float* W2  = (const float*)d_in[11];
  const float* b2  = (const float*)d_in[12];
  const float* g1  = (const float*)d_in[13];
  const float* be1 = (const float*)d_in[14];
  const float* g2  = (const float*)d_in[15];
  const float* be2 = (const float*)d_in[16];
  float* out = (float*)d_out;

  char* ws = (char*)d_ws;
  size_t off = 0;
  auto alloc = [&](size_t bytes)->char*{
    char* p = ws + off; off = (off + bytes + 255) & ~(size_t)255; return p;
  };
  bf16*  xb    = (bf16*) alloc((size_t)NTOK*D_*2);
  bf16*  WcatT = (bf16*) alloc((size_t)3*D_*D_*2);
  float* bcat  = (float*)alloc((size_t)3*D_*4);
  bf16*  WoT   = (bf16*) alloc((size_t)D_*D_*2);
  bf16*  W1T   = (bf16*) alloc((size_t)F_*D_*2);
  bf16*  W2T   = (bf16*) alloc((size_t)D_*F_*2);
  bf16*  r1    = (bf16*) alloc((size_t)NTOK*F_*2);     // q,k,vt then ff1
  bf16*  qb    = r1;
  bf16*  kb    = r1 + (size_t)NTOK*D_;
  _Float16* vt = (_Float16*)(r1 + (size_t)2*NTOK*D_);  // [bh*64+d][S], f16, key-permuted
  bf16*  ff1   = r1;
  bf16*  ctxb  = (bf16*) alloc((size_t)NTOK*D_*2);     // ctx then y2
  bf16*  y1    = (bf16*) alloc((size_t)NTOK*D_*2);
  bf16*  hb    = (bf16*) alloc((size_t)NTOK*D_*2);
  bf16*  y2    = ctxb;

  f32_to_bf16_k<<<(NTOK*D_/4+255)/256, 256, 0, stream>>>(
      (const float4*)x, (short4*)xb, NTOK*D_/4);
  transpose_f32_bf16_k<<<dim3(D_/32, D_/32), 256, 0, stream>>>(Wo, WoT, D_, D_);
  transpose_f32_bf16_k<<<dim3(F_/32, D_/32), 256, 0, stream>>>(W1, W1T, D_, F_);
  transpose_f32_bf16_k<<<dim3(D_/32, F_/32), 256, 0, stream>>>(W2, W2T, F_, D_);
  pack_qkv_t_k<<<(3*D_*D_+255)/256, 256, 0, stream>>>(Wq,bq,Wk,bk,Wv,bv,WcatT,bcat);

  // 1) fused QKV projection (q pre-scaled 1/8*log2e; v written transposed+permuted f16)
  mgemm256_k<0><<<dim3(3*D_/256, NTOK/256), 512, 0, stream>>>(
      xb, WcatT, bcat, nullptr, NTOK, 3*D_, D_, qb, kb, vt);

  // 2) MFMA flash attention -> ctx [8192,768]
  fattn_k<<<dim3(BH_, S_/64), 256, 0, stream>>>(qb, kb, vt, ctxb);

  // 3) out-proj + residual: y1 = ctx@Wo + bo + x   (128x128 tiles, BK=64, dbuf)
  mgemm128_k<<<dim3(D_/128, NTOK/128), 256, 0, stream>>>(
      ctxb, WoT, bo, xb, y1, NTOK, D_, D_);

  // 4) LN1 -> h
  layernorm_k<bf16><<<NTOK, 192, 0, stream>>>(y1, g1, be1, hb);

  // 5) FF1 + fast GELU (256x256 8-phase)
  mgemm256_k<2><<<dim3(F_/256, NTOK/256), 512, 0, stream>>>(
      hb, W1T, b1, ff1, NTOK, F_, D_, nullptr, nullptr, nullptr);

  // 6) FF2 + residual: y2 = ff1@W2 + b2 + h   (128x128 tiles, BK=64, dbuf)
  mgemm128_k<<<dim3(D_/128, NTOK/128), 256, 0, stream>>>(
      ff1, W2T, b2, hb, y2, NTOK, D_, F_);

  // 7) LN2 -> out (fp32)
  layernorm_k<float><<<NTOK, 192, 0, stream>>>(y2, g2, be2, out);
}

// Round 5
// 393.046 us; speedup vs baseline: 1.0500x; 1.0128x over previous
//
#include <hip/hip_runtime.h>
#include <hip/hip_bf16.h>
#include <math.h>

#define B_ 4
#define S_ 2048
#define D_ 768
#define H_ 12
#define DH_ 64
#define F_ 3072
#define NTOK (B_*S_)   // 8192
#define BH_ (B_*H_)    // 48

typedef __hip_bfloat16 bf16;
typedef __attribute__((ext_vector_type(8))) short bf16x8;   // 8 bf16 = 4 VGPRs (MFMA A/B frag)
typedef __attribute__((ext_vector_type(4))) float f32x4;    // MFMA C/D frag
typedef __attribute__((ext_vector_type(4))) _Float16 half4;
typedef __attribute__((ext_vector_type(8))) _Float16 half8;
typedef __attribute__((ext_vector_type(2))) __fp16 fp16x2;  // cvt_pkrtz result type

// async global->LDS: 16 B/lane, lane i lands at ldsbase + i*16 (wave-uniform base)
#define GLD16(g, l) __builtin_amdgcn_global_load_lds( \
    (__attribute__((address_space(1))) void*)(uintptr_t)(g), \
    (__attribute__((address_space(3))) void*)(uintptr_t)(l), 16, 0, 0)

__device__ __forceinline__ float bs2f(short s){
  union { unsigned int u; float f; } cv; cv.u = ((unsigned int)(unsigned short)s) << 16; return cv.f;
}
__device__ __forceinline__ float b2f(bf16 v){ return __bfloat162float(v); }
__device__ __forceinline__ bf16 f2b(float v){ return __float2bfloat16(v); }
__device__ __forceinline__ short f2bb(float v){ bf16 b = f2b(v); short s; __builtin_memcpy(&s, &b, 2); return s; }

// pack 4 floats -> half4 via v_cvt_pkrtz_f16_f32 pairs
__device__ __forceinline__ half4 pk4(float p0, float p1, float p2, float p3){
  union { fp16x2 v2[2]; half4 v4; } u;
  u.v2[0] = __builtin_amdgcn_cvt_pkrtz(p0, p1);
  u.v2[1] = __builtin_amdgcn_cvt_pkrtz(p2, p3);
  return u.v4;
}

// raw workgroup barrier (no vmcnt(0) drain like __syncthreads) + compiler mem fence
__device__ __forceinline__ void wgbar(){
  __builtin_amdgcn_s_barrier();
  asm volatile("" ::: "memory");
}
// barrier that guarantees this wave's ds_writes are visible (lgkmcnt only, no vmcnt drain)
__device__ __forceinline__ void wgbar_lds(){
  asm volatile("s_waitcnt lgkmcnt(0)" ::: "memory");
  __builtin_amdgcn_s_barrier();
  asm volatile("" ::: "memory");
}

// tanh-form GELU rewritten: 0.5x(1+tanh(u)) = x * rcp(1 + exp2(x*(c0 + c1*x^2)))
__device__ __forceinline__ float gelu_fast(float v){
  const float c0 = -2.302208157f;
  const float c1 = -0.102943238f;
  float w = v*v;
  float z = v * __builtin_fmaf(c1, w, c0);
  float t = __builtin_amdgcn_exp2f(z);
  return v * __builtin_amdgcn_rcpf(1.0f + t);
}

// ---------------- fp32 -> bf16 convert (vectorized: float4 -> short4) ----------------
__global__ void f32_to_bf16_k(const float4* __restrict__ in, short4* __restrict__ out, int n4){
  int i = blockIdx.x*256 + threadIdx.x;
  if (i < n4){
    float4 v = in[i];
    short4 o;
    o.x = f2bb(v.x); o.y = f2bb(v.y); o.z = f2bb(v.z); o.w = f2bb(v.w);
    out[i] = o;
  }
}

// ------- transpose+convert: in[K][N] f32 -> out[N][K] bf16 (LDS 32x32 tiles) -------
__global__ __launch_bounds__(256) void transpose_f32_bf16_k(const float* __restrict__ in,
    bf16* __restrict__ out, int K, int N){
  __shared__ float t[32][33];
  const int kb = blockIdx.y*32, nb = blockIdx.x*32;
  const int x = threadIdx.x & 31, y = threadIdx.x >> 5;
#pragma unroll
  for (int yy = y; yy < 32; yy += 8)
    t[yy][x] = in[(size_t)(kb+yy)*N + nb + x];
  __syncthreads();
#pragma unroll
  for (int yy = y; yy < 32; yy += 8)
    out[(size_t)(nb+yy)*K + kb + x] = f2b(t[x][yy]);
}

// ---- pack Wq/Wk/Wv [H,D,Dh] -> WcatT [3D][D] (n-major, k contiguous), biases -> bcat[3D] ----
__global__ void pack_qkv_t_k(const float* __restrict__ Wq, const float* __restrict__ bq,
                             const float* __restrict__ Wk, const float* __restrict__ bk,
                             const float* __restrict__ Wv, const float* __restrict__ bv,
                             bf16* __restrict__ Wt, float* __restrict__ bcat){
  int idx = blockIdx.x*256 + threadIdx.x;
  if (idx < 3*D_*D_){
    int n = idx / D_;
    int k = idx - n*D_;
    int which = n / D_;
    int cc = n - which*D_;
    int h = cc >> 6, e = cc & 63;
    const float* W = (which==0) ? Wq : ((which==1) ? Wk : Wv);
    Wt[idx] = f2b(W[((size_t)h*D_ + k)*DH_ + e]);
  }
  if (idx < 3*D_){
    int which = idx / D_;
    int cc = idx - which*D_;
    int h = cc >> 6, e = cc & 63;
    const float* bb = (which==0) ? bq : ((which==1) ? bk : bv);
    bcat[idx] = bb[h*DH_ + e];
  }
}

// ================= MFMA GEMM 256x256, BK=64, 8-phase counted-vmcnt schedule =================
// C[M,N] = A[M,K] @ Bt[N,K]^T.  8 waves (2M x 4N), per-wave 128x64 output.
// LDS: [2 dbuf][2 khalf][256 rows][32 cols] bf16 per operand = 64 KB each, 128 KB total.
#define STAGE_A(bufi_, kh_, kt_) do { \
    GLD16(gA  + (size_t)(kt_)*64 + (kh_)*32, asb + ((bufi_)<<15) + ((kh_)<<14)); \
    GLD16(gA2 + (size_t)(kt_)*64 + (kh_)*32, asb + ((bufi_)<<15) + ((kh_)<<14) + 8192); } while(0)
#define STAGE_B(bufi_, kh_, kt_) do { \
    GLD16(gB  + (size_t)(kt_)*64 + (kh_)*32, bsb + ((bufi_)<<15) + ((kh_)<<14)); \
    GLD16(gB2 + (size_t)(kt_)*64 + (kh_)*32, bsb + ((bufi_)<<15) + ((kh_)<<14) + 8192); } while(0)
#define AFRAG(bufi_, ks_, i_) (*(const bf16x8*)(AsB + ((bufi_)<<15) + ((ks_)<<14) + ((wm + (i_)*16 + l16)<<6) + fsw))
#define BFRAG(bufi_, ks_, j_) (*(const bf16x8*)(BsB + ((bufi_)<<15) + ((ks_)<<14) + ((wn + (j_)*16 + l16)<<6) + fsw))

template<int EPI>
__global__ __launch_bounds__(512, 2) void mgemm256_k(
    const bf16* __restrict__ A, const bf16* __restrict__ Bt,
    const float* __restrict__ bias, bf16* __restrict__ C,
    int M, int N, int K,
    bf16* __restrict__ qb, bf16* __restrict__ kbuf, _Float16* __restrict__ vt)
{
  __shared__ __align__(16) bf16 As[32768];  // [2 buf][2 kh][256 rows][32 cols]
  __shared__ __align__(16) bf16 Bs[32768];
  const int tid  = threadIdx.x;
  const int wave = tid >> 6, lane = tid & 63;
  const int quad = lane >> 4, l16 = lane & 15;
  const int wm = (wave >> 2) * 128;    // wave row block within 256-tile
  const int wn = (wave & 3) * 64;      // wave col block

  // XCD-aware remap (total blocks % 8 == 0 for all our launches)
  const int NX = gridDim.x;
  const int f  = blockIdx.y * NX + blockIdx.x;
  const int xcd = f & 7;
  const int j0  = f >> 3;
  const int bx  = j0 % NX;
  const int by  = (j0 / NX) * 8 + xcd;
  const int m0 = by * 256, n0 = bx * 256;

  // staging: thread t covers row t>>2 of a 128-row round, LDS slot t&3;
  // source chunk pre-swizzled: g = slot ^ ((row>>1)&3) = (t&3) ^ ((t>>3)&3)
  const int srow = tid >> 2;
  const int sg   = (tid & 3) ^ ((tid >> 3) & 3);
  const bf16* gA  = A  + (size_t)(m0 + srow)*K + sg*8;
  const bf16* gA2 = A  + (size_t)(m0 + 128 + srow)*K + sg*8;
  const bf16* gB  = Bt + (size_t)(n0 + srow)*K + sg*8;
  const bf16* gB2 = Bt + (size_t)(n0 + 128 + srow)*K + sg*8;
  const uintptr_t asb = (uintptr_t)(void*)As + (size_t)wave*1024;
  const uintptr_t bsb = (uintptr_t)(void*)Bs + (size_t)wave*1024;

  const char* AsB = (const char*)As;
  const char* BsB = (const char*)Bs;
  const int fsw = (quad ^ ((l16 >> 1) & 3)) * 16;  // swizzled 16B slot within 64B row

  f32x4 acc[8][4];
#pragma unroll
  for (int i=0;i<8;i++)
#pragma unroll
    for (int j2=0;j2<4;j2++) acc[i][j2] = (f32x4)0.f;

  const int KT = K >> 6;

  // prologue: stage tile 0 fully (issue order = consumption order), wait first 2 halves
  STAGE_A(0, 0, 0); STAGE_B(0, 0, 0); STAGE_A(0, 1, 0); STAGE_B(0, 1, 0);
  asm volatile("s_waitcnt vmcnt(4)" ::: "memory");
  wgbar();

  for (int kt = 0; kt < KT; ++kt){
    const int bufc = kt & 1, bufn = bufc ^ 1;
    const bool pf = (kt + 1) < KT;
    bf16x8 af[4], bfr[4];

    // -------- phase 0: khalf 0, rows i=0..3 --------
#pragma unroll
    for (int i=0;i<4;i++) af[i] = AFRAG(bufc, 0, i);
#pragma unroll
    for (int j2=0;j2<4;j2++) bfr[j2] = BFRAG(bufc, 0, j2);
    if (pf) STAGE_A(bufn, 0, kt+1);
    wgbar();
    __builtin_amdgcn_s_setprio(1);
#pragma unroll
    for (int i=0;i<4;i++)
#pragma unroll
      for (int j2=0;j2<4;j2++)
        acc[i][j2] = __builtin_amdgcn_mfma_f32_16x16x32_bf16(af[i], bfr[j2], acc[i][j2], 0, 0, 0);
    __builtin_amdgcn_s_setprio(0);
    wgbar();

    // -------- phase 1: khalf 0, rows i=4..7 --------
#pragma unroll
    for (int i=0;i<4;i++) af[i] = AFRAG(bufc, 0, 4+i);
    if (pf) STAGE_B(bufn, 0, kt+1);
    wgbar();
    __builtin_amdgcn_s_setprio(1);
#pragma unroll
    for (int i=0;i<4;i++)
#pragma unroll
      for (int j2=0;j2<4;j2++)
        acc[4+i][j2] = __builtin_amdgcn_mfma_f32_16x16x32_bf16(af[i], bfr[j2], acc[4+i][j2], 0, 0, 0);
    __builtin_amdgcn_s_setprio(0);
    if (pf) asm volatile("s_waitcnt vmcnt(4)" ::: "memory");
    else    asm volatile("s_waitcnt vmcnt(0)" ::: "memory");
    wgbar();

    // -------- phase 2: khalf 1, rows i=0..3 --------
#pragma unroll
    for (int i=0;i<4;i++) af[i] = AFRAG(bufc, 1, i);
#pragma unroll
    for (int j2=0;j2<4;j2++) bfr[j2] = BFRAG(bufc, 1, j2);
    if (pf) STAGE_A(bufn, 1, kt+1);
    wgbar();
    __builtin_amdgcn_s_setprio(1);
#pragma unroll
    for (int i=0;i<4;i++)
#pragma unroll
      for (int j2=0;j2<4;j2++)
        acc[i][j2] = __builtin_amdgcn_mfma_f32_16x16x32_bf16(af[i], bfr[j2], acc[i][j2], 0, 0, 0);
    __builtin_amdgcn_s_setprio(0);
    wgbar();

    // -------- phase 3: khalf 1, rows i=4..7 --------
#pragma unroll
    for (int i=0;i<4;i++) af[i] = AFRAG(bufc, 1, 4+i);
    if (pf) STAGE_B(bufn, 1, kt+1);
    wgbar();
    __builtin_amdgcn_s_setprio(1);
#pragma unroll
    for (int i=0;i<4;i++)
#pragma unroll
      for (int j2=0;j2<4;j2++)
        acc[4+i][j2] = __builtin_amdgcn_mfma_f32_16x16x32_bf16(af[i], bfr[j2], acc[4+i][j2], 0, 0, 0);
    __builtin_amdgcn_s_setprio(0);
    if (pf) asm volatile("s_waitcnt vmcnt(4)" ::: "memory");
    wgbar();
  }

  // -------- epilogue --------
#pragma unroll
  for (int i=0;i<8;i++){
#pragma unroll
    for (int j2=0;j2<4;j2++){
      const int n = n0 + wn + j2*16 + l16;
      const int m_base = m0 + wm + i*16 + quad*4;
      if (EPI == 0){
        const int which = n / D_;
        const int cc = n - which*D_;
        const int h = cc >> 6, e = cc & 63;
        if (which == 2){
          const int b = m_base >> 11, s = m_base & (S_-1);
          const int sl = s & 63;
          const int perm = ((sl>>2)&3)*16 + ((sl>>4)&3)*4;   // key-permuted V^T layout
          half4 hv;
#pragma unroll
          for (int r=0;r<4;r++) hv[r] = (_Float16)(acc[i][j2][r] + bias[n]);
          *(half4*)(vt + ((size_t)(b*H_+h)*DH_ + e)*S_ + (s & ~63) + perm) = hv;
        } else {
          bf16* dst = (which==0) ? qb : kbuf;
          // q: fold softmax 1/sqrt(64) AND log2(e) (exp2-domain softmax) into prescale
          const float sc2 = (which==0) ? 0.18033688f : 1.0f;
#pragma unroll
          for (int r=0;r<4;r++){
            const int m = m_base + r;
            const int b = m >> 11, s = m & (S_-1);
            dst[((size_t)(b*H_+h)*S_ + s)*DH_ + e] = f2b((acc[i][j2][r] + bias[n]) * sc2);
          }
        }
      } else {
#pragma unroll
        for (int r=0;r<4;r++){
          const int m = m_base + r;
          float v = acc[i][j2][r] + bias[n];
          C[(size_t)m*N + n] = f2b(gelu_fast(v));
        }
      }
    }
  }
}
#undef STAGE_A
#undef STAGE_B
#undef AFRAG
#undef BFRAG

// ---------------- MFMA GEMM 128x128, BK=64, double-buffered 2-phase counted-vmcnt ----------------
// (proj, FF2: N=768).  4 waves (2x2), per-wave 64x64 out, 32 MFMA per K-step per wave.
// Per K-step: issue next tile's 8 global_load_lds BEFORE computing the current buffer;
// single vmcnt(0) + s_barrier per step.  LDS 64 KB -> 2 blocks/CU; grid 384 co-resident.
// Swizzle: slot c of row r holds global chunk c ^ (r&7).  C = A@Bt^T + bias + aux (residual).
__global__ __launch_bounds__(256) void mgemm128_k(
    const bf16* __restrict__ A, const bf16* __restrict__ Bt,
    const float* __restrict__ bias, const bf16* __restrict__ aux,
    bf16* __restrict__ C, int M, int N, int K)
{
  __shared__ __align__(16) bf16 As[16384];   // [2][128][64] 32 KB
  __shared__ __align__(16) bf16 Bs[16384];   // [2][128][64] 32 KB
  const int tid  = threadIdx.x;
  const int wave = tid >> 6, lane = tid & 63;
  const int quad = lane >> 4, l16 = lane & 15;
  const int wm = (wave >> 1) * 64, wn = (wave & 1) * 64;

  const int NX = gridDim.x;
  const int f  = blockIdx.y * NX + blockIdx.x;
  const int xcd = f & 7;
  const int j   = f >> 3;
  const int bx  = j % NX;
  const int by  = (j / NX) * 8 + xcd;
  const int m0 = by * 128, n0 = bx * 128;

  const int srow8 = lane >> 3;                       // 0..7
  const int g     = (lane & 7) ^ srow8;              // global 16B-chunk within the row
  // wave w stages rows w*32 + t*8 + srow8 (t=0..3) for both A and B
  const bf16* gA = A  + (size_t)(m0 + wave*32 + srow8)*K + g*8;
  const bf16* gB = Bt + (size_t)(n0 + wave*32 + srow8)*K + g*8;
  const uintptr_t asb = (uintptr_t)(void*)As + (size_t)wave*32*128;
  const uintptr_t bsb = (uintptr_t)(void*)Bs + (size_t)wave*32*128;

  f32x4 acc[4][4];
#pragma unroll
  for (int i=0;i<4;i++)
#pragma unroll
    for (int j2=0;j2<4;j2++) acc[i][j2] = (f32x4)0.f;

  const char* AsB = (const char*)As;
  const char* BsB = (const char*)Bs;
  const int KT = K >> 6;

  // prologue: stage tile 0 into buf0
#pragma unroll
  for (int t=0;t<4;t++){
    GLD16(gA + (size_t)t*8*K, asb + t*1024);
    GLD16(gB + (size_t)t*8*K, bsb + t*1024);
  }
  gA += 64; gB += 64;
  asm volatile("s_waitcnt vmcnt(0)" ::: "memory");
  wgbar();

  for (int kt = 0; kt < KT; ++kt){
    const int cur = kt & 1, nxt = cur ^ 1;
    const bool pf = (kt + 1) < KT;
    if (pf){
      const uintptr_t ao = asb + (size_t)nxt*16384;
      const uintptr_t bo = bsb + (size_t)nxt*16384;
#pragma unroll
      for (int t=0;t<4;t++){
        GLD16(gA + (size_t)t*8*K, ao + t*1024);
        GLD16(gB + (size_t)t*8*K, bo + t*1024);
      }
      gA += 64; gB += 64;
    }
    const char* Ac = AsB + (size_t)cur*16384;
    const char* Bc = BsB + (size_t)cur*16384;
#pragma unroll
    for (int kq = 0; kq < 2; kq++){
      const int cbase = kq*4 + quad;
      bf16x8 af[4], bfr[4];
#pragma unroll
      for (int i=0;i<4;i++){
        const int m = wm + i*16 + l16;
        af[i] = *(const bf16x8*)(Ac + (m << 7) + ((cbase ^ (m & 7)) << 4));
      }
#pragma unroll
      for (int j2=0;j2<4;j2++){
        const int n = wn + j2*16 + l16;
        bfr[j2] = *(const bf16x8*)(Bc + (n << 7) + ((cbase ^ (n & 7)) << 4));
      }
#pragma unroll
      for (int i=0;i<4;i++)
#pragma unroll
        for (int j2=0;j2<4;j2++)
          acc[i][j2] = __builtin_amdgcn_mfma_f32_16x16x32_bf16(af[i], bfr[j2], acc[i][j2], 0, 0, 0);
    }
    if (pf) asm volatile("s_waitcnt vmcnt(0)" ::: "memory");
    wgbar();
  }

#pragma unroll
  for (int i=0;i<4;i++){
#pragma unroll
    for (int j2=0;j2<4;j2++){
      const int n = n0 + wn + j2*16 + l16;
      const int m_base = m0 + wm + i*16 + quad*4;
#pragma unroll
      for (int r=0;r<4;r++){
        const int m = m_base + r;
        float v = acc[i][j2][r] + bias[n] + b2f(aux[(size_t)m*N + n]);
        C[(size_t)m*N + n] = f2b(v);
      }
    }
  }
}

// ---------------- MFMA flash attention: 1 barrier/tile, K+V dbuf, V->regs pre-barrier ----------------
// exp2-domain softmax (1/sqrt(64)*log2e folded into q) + defer-max (THR=8).
// Pipeline per tile kt: [QK^T from K(kt) | local max -> maxb(kt&1) | V(kt) LDS->regs |
// ds_write tile kt+1 from regs | global-load kt+2 -> regs] -> barrier ->
// [cross-half max | defer-max | P | PV from V-regs].
// Buffer safety (all LDS reads of buffer X complete pre-bar; writes to X happen post-bar
// of the SAME interval or later): K dbuf OK; V dbuf OK *because* V-read moved pre-bar.
// LDS 38.4 KB -> 4 blocks/CU (VGPR ~100 <= 128 cap from __launch_bounds__(256,4)).
__global__ __launch_bounds__(256, 4) void fattn_k(const bf16* __restrict__ qb,
    const bf16* __restrict__ kb, const _Float16* __restrict__ vt, bf16* __restrict__ ctx)
{
  __shared__ __align__(16) char smem[38400];
  typedef bf16     KsRow[72];
  typedef _Float16 VsRow[72];
  KsRow* kp0 = (KsRow*)(smem);            // K buf A [64][72] bf16 (9216 B)
  KsRow* kp1 = (KsRow*)(smem + 9216);     // K buf B
  VsRow* vp0 = (VsRow*)(smem + 18432);    // V bufs [64 d][72 keys(permuted)] f16
  VsRow* vp1 = (VsRow*)(smem + 27648);
  float* maxb  = (float*)(smem + 36864);  // [2 bufs][2 kh][64 q]  (1024 B)
  float* libuf = (float*)(smem + 37888);  // [2 kh][64 q]          (512 B)
  float* Obuf  = (float*)smem;            // epilogue alias (16896 B < 18432)

  const int bh = blockIdx.x;
  const int qt = 31 - blockIdx.y;       // heavy tiles first
  const int q0 = qt * 64;
  const int tid = threadIdx.x;
  const int wave = tid >> 6, lane = tid & 63;
  const int quad = lane >> 4, l16 = lane & 15;
  const int kh = wave >> 1, qh = wave & 1;
  const size_t kbase = (size_t)bh * S_ * DH_;
  const int nt = qt + 1;

  const int sr  = tid >> 2;            // staging row 0..63
  const int seg = (tid & 3) * 16;      // staging col 0,16,32,48

  bf16x8 qf[2][2];
#pragma unroll
  for (int nf=0; nf<2; nf++)
#pragma unroll
    for (int h=0; h<2; h++)
      qf[nf][h] = *(const bf16x8*)(qb + kbase + (size_t)(q0 + qh*32 + nf*16 + l16)*DH_ + h*32 + quad*8);

  f32x4 o[4][2];
#pragma unroll
  for (int df=0; df<4; df++){ o[df][0] = (f32x4)0.f; o[df][1] = (f32x4)0.f; }
  float mi[2] = {-1e30f, -1e30f}, li[2] = {0.f, 0.f};

  // ---- prologue: tile 0 -> LDS (kp0/vp0); tile 1 -> regs ----
  bf16x8 ka0, ka1; half8 va0, va1;
  {
    const bf16* ks = kb + kbase + (size_t)sr*DH_ + seg;
    ka0 = *(const bf16x8*)ks; ka1 = *(const bf16x8*)(ks + 8);
    const _Float16* vs = vt + ((size_t)bh*DH_ + sr)*S_ + seg;
    va0 = *(const half8*)vs; va1 = *(const half8*)(vs + 8);
  }
  *(bf16x8*)&kp0[sr][seg]   = ka0;
  *(bf16x8*)&kp0[sr][seg+8] = ka1;
  *(half8*)&vp0[sr][seg]    = va0;
  *(half8*)&vp0[sr][seg+8]  = va1;
  if (nt > 1){
    const bf16* ks = kb + kbase + (size_t)(64 + sr)*DH_ + seg;
    ka0 = *(const bf16x8*)ks; ka1 = *(const bf16x8*)(ks + 8);
    const _Float16* vs = vt + ((size_t)bh*DH_ + sr)*S_ + 64 + seg;
    va0 = *(const half8*)vs; va1 = *(const half8*)(vs + 8);
  }
  wgbar_lds();

  for (int kt = 0; kt < nt; ++kt){
    // -------- pre-barrier: QK^T(kt), local max, V(kt)->regs, stage kt+1, load kt+2 --------
    bf16x8 af[2][2];
#pragma unroll
    for (int mf=0; mf<2; mf++)
#pragma unroll
      for (int h=0; h<2; h++)
        af[mf][h] = *(const bf16x8*)&kp0[kh*32 + mf*16 + l16][h*32 + quad*8];
    f32x4 sc[2][2];
#pragma unroll
    for (int mf=0; mf<2; mf++)
#pragma unroll
      for (int nf=0; nf<2; nf++){
        f32x4 t = __builtin_amdgcn_mfma_f32_16x16x32_bf16(af[mf][0], qf[nf][0], (f32x4)0.f, 0, 0, 0);
        sc[mf][nf] = __builtin_amdgcn_mfma_f32_16x16x32_bf16(af[mf][1], qf[nf][1], t, 0, 0, 0);
      }

    if (kt == qt){
#pragma unroll
      for (int mf=0; mf<2; mf++){
        const int keyl = kh*32 + mf*16 + quad*4;
#pragma unroll
        for (int nf=0; nf<2; nf++){
          const int ql = qh*32 + nf*16 + l16;
#pragma unroll
          for (int r=0; r<4; r++)
            if (keyl + r > ql) sc[mf][nf][r] = -1e30f;
        }
      }
    }

    float mw[2];
#pragma unroll
    for (int nf=0; nf<2; nf++){
      float mx = -1e30f;
#pragma unroll
      for (int mf=0; mf<2; mf++)
#pragma unroll
        for (int r=0; r<4; r++) mx = fmaxf(mx, sc[mf][nf][r]);
      mx = fmaxf(mx, __shfl_xor(mx, 16));
      mx = fmaxf(mx, __shfl_xor(mx, 32));
      mw[nf] = mx;
    }
    float* mb = maxb + (kt & 1)*128;
    if (quad == 0){
      mb[kh*64 + qh*32 + l16]      = mw[0];
      mb[kh*64 + qh*32 + 16 + l16] = mw[1];
    }

    // V(kt): LDS -> regs (pre-barrier, so vp0 can be overwritten next interval)
    half8 vv[4];
#pragma unroll
    for (int df=0; df<4; df++)
      vv[df] = *(const half8*)&vp0[df*16 + l16][quad*16 + kh*8];

    if (kt + 1 < nt){
      // write staged regs (tile kt+1) -> kp1 / vp1
      *(bf16x8*)&kp1[sr][seg]   = ka0;
      *(bf16x8*)&kp1[sr][seg+8] = ka1;
      *(half8*)&vp1[sr][seg]    = va0;
      *(half8*)&vp1[sr][seg+8]  = va1;
      if (kt + 2 < nt){
        const int k0n = (kt + 2) * 64;
        const bf16* ks = kb + kbase + (size_t)(k0n + sr)*DH_ + seg;
        ka0 = *(const bf16x8*)ks; ka1 = *(const bf16x8*)(ks + 8);
        const _Float16* vs = vt + ((size_t)bh*DH_ + sr)*S_ + k0n + seg;
        va0 = *(const half8*)vs; va1 = *(const half8*)(vs + 8);
      }
    }
    wgbar_lds();

    // -------- post-barrier: cross-half max, defer-max, P, PV from V-regs --------
    const float tm0 = fmaxf(mw[0], mb[(1-kh)*64 + qh*32 + l16]);
    const float tm1 = fmaxf(mw[1], mb[(1-kh)*64 + qh*32 + 16 + l16]);
    const bool need = !__all((tm0 - mi[0] <= 8.f) && (tm1 - mi[1] <= 8.f));
    if (need){
      const float mn0 = fmaxf(mi[0], tm0);
      const float mn1 = fmaxf(mi[1], tm1);
      const float a0 = __builtin_amdgcn_exp2f(mi[0] - mn0);
      const float a1 = __builtin_amdgcn_exp2f(mi[1] - mn1);
      mi[0] = mn0; mi[1] = mn1;
      li[0] *= a0; li[1] *= a1;
#pragma unroll
      for (int df=0; df<4; df++)
#pragma unroll
        for (int r=0; r<4; r++){ o[df][0][r] *= a0; o[df][1][r] *= a1; }
    }

    half4 pfr[2][2];
#pragma unroll
    for (int nf=0; nf<2; nf++){
      float rs = 0.f;
#pragma unroll
      for (int mf=0; mf<2; mf++){
        const float p0 = __builtin_amdgcn_exp2f(sc[mf][nf][0] - mi[nf]);
        const float p1 = __builtin_amdgcn_exp2f(sc[mf][nf][1] - mi[nf]);
        const float p2 = __builtin_amdgcn_exp2f(sc[mf][nf][2] - mi[nf]);
        const float p3 = __builtin_amdgcn_exp2f(sc[mf][nf][3] - mi[nf]);
        rs += (p0 + p1) + (p2 + p3);
        pfr[mf][nf] = pk4(p0, p1, p2, p3);
      }
      rs += __shfl_xor(rs, 16);
      rs += __shfl_xor(rs, 32);
      li[nf] += rs;
    }

#pragma unroll
    for (int df=0; df<4; df++){
      half4 vlo = __builtin_shufflevector(vv[df], vv[df], 0,1,2,3);
      half4 vhi = __builtin_shufflevector(vv[df], vv[df], 4,5,6,7);
#pragma unroll
      for (int nf=0; nf<2; nf++){
        o[df][nf] = __builtin_amdgcn_mfma_f32_16x16x16f16(vlo, pfr[0][nf], o[df][nf], 0, 0, 0);
        o[df][nf] = __builtin_amdgcn_mfma_f32_16x16x16f16(vhi, pfr[1][nf], o[df][nf], 0, 0, 0);
      }
    }

    // rotate buffers: K and V both 2-cycle
    { KsRow* t_ = kp0; kp0 = kp1; kp1 = t_; }
    { VsRow* t_ = vp0; vp0 = vp1; vp1 = t_; }
  }

  __syncthreads();
  if (quad == 0){
    libuf[kh*64 + qh*32 + l16]      = li[0];
    libuf[kh*64 + qh*32 + 16 + l16] = li[1];
  }
  if (kh == 1){
#pragma unroll
    for (int df=0; df<4; df++)
#pragma unroll
      for (int nf=0; nf<2; nf++)
#pragma unroll
        for (int r=0; r<4; r++)
          Obuf[(qh*64 + df*16 + quad*4 + r)*33 + nf*16 + l16] = o[df][nf][r];
  }
  __syncthreads();
  if (kh == 0){
    const int b = bh / H_, h = bh - (bh / H_)*H_;
#pragma unroll
    for (int nf=0; nf<2; nf++){
      const int q64 = qh*32 + nf*16 + l16;
      // both kh halves applied identical defer-max decisions -> same mi -> li directly addable
      const float inv = 1.0f / (libuf[q64] + libuf[64 + q64]);
      const int qtok = q0 + q64;
#pragma unroll
      for (int df=0; df<4; df++){
        short4 pk;
        float v0 = (o[df][nf][0] + Obuf[(qh*64 + df*16 + quad*4 + 0)*33 + nf*16 + l16]) * inv;
        float v1 = (o[df][nf][1] + Obuf[(qh*64 + df*16 + quad*4 + 1)*33 + nf*16 + l16]) * inv;
        float v2 = (o[df][nf][2] + Obuf[(qh*64 + df*16 + quad*4 + 2)*33 + nf*16 + l16]) * inv;
        float v3 = (o[df][nf][3] + Obuf[(qh*64 + df*16 + quad*4 + 3)*33 + nf*16 + l16]) * inv;
        pk.x = f2bb(v0); pk.y = f2bb(v1); pk.z = f2bb(v2); pk.w = f2bb(v3);
        *(short4*)((short*)ctx + ((size_t)(b*S_ + qtok))*D_ + h*DH_ + df*16 + quad*4) = pk;
      }
    }
  }
}

// ---------------- layernorm over D=768 (192 thr, short4 loads, 16B stores) ----------------
template<typename T> __device__ __forceinline__ void st4(T* p, size_t idx, float a, float b, float c, float d);
template<> __device__ __forceinline__ void st4<float>(float* p, size_t idx, float a, float b, float c, float d){
  float4 v; v.x=a; v.y=b; v.z=c; v.w=d; *(float4*)(p+idx) = v;
}
template<> __device__ __forceinline__ void st4<bf16>(bf16* p, size_t idx, float a, float b, float c, float d){
  short4 v; v.x=f2bb(a); v.y=f2bb(b); v.z=f2bb(c); v.w=f2bb(d); *(short4*)((short*)p+idx) = v;
}

template<typename OutT>
__global__ __launch_bounds__(192) void layernorm_k(const bf16* __restrict__ X,
    const float* __restrict__ g, const float* __restrict__ bta, OutT* __restrict__ Y)
{
  const int row = blockIdx.x;
  const int tid = threadIdx.x;
  const short4 raw = *(const short4*)((const short*)X + (size_t)row*D_ + tid*4);
  const float v0 = bs2f(raw.x), v1 = bs2f(raw.y), v2 = bs2f(raw.z), v3 = bs2f(raw.w);
  float s  = v0+v1+v2+v3;
  float s2 = v0*v0+v1*v1+v2*v2+v3*v3;
#pragma unroll
  for (int o = 32; o > 0; o >>= 1){ s += __shfl_down(s, o); s2 += __shfl_down(s2, o); }
  __shared__ float rs[3], rq[3];
  const int lane = tid & 63, w = tid >> 6;
  if (lane == 0){ rs[w] = s; rq[w] = s2; }
  __syncthreads();
  s  = rs[0]+rs[1]+rs[2];
  s2 = rq[0]+rq[1]+rq[2];
  const float mean = s * (1.0f/D_);
  const float var  = s2 * (1.0f/D_) - mean*mean;
  const float inv  = rsqrtf(var + 1e-5f);
  const float4 g4 = *(const float4*)(g + tid*4);
  const float4 b4 = *(const float4*)(bta + tid*4);
  st4(Y, (size_t)row*D_ + tid*4,
      (v0-mean)*inv*g4.x + b4.x,
      (v1-mean)*inv*g4.y + b4.y,
      (v2-mean)*inv*g4.z + b4.z,
      (v3-mean)*inv*g4.w + b4.w);
}

extern "C" void kernel_launch(void* const* d_in, const int* in_sizes, int n_in,
                              void* d_out, int out_size, void* d_ws, size_t ws_size,
                              hipStream_t stream)
{
  const float* x   = (const float*)d_in[0];
  const float* Wq  = (const float*)d_in[1];
  const float* bq  = (const float*)d_in[2];
  const float* Wk  = (const float*)d_in[3];
  const float* bk  = (const float*)d_in[4];
  const float* Wv  = (const float*)d_in[5];
  const float* bv  = (const float*)d_in[6];
  const float* Wo  = (const float*)d_in[7];
  const float* bo  = (const float*)d_in[8];
  const float* W1  = (const float*)d_in[9];
  const float* b1  = (const float*)d_in[10];
  const float* W2  = (const float*)d_in[11];
  const float* b2  = (const float*)d_in[12];
  const float* g1  = (const float*)d_in[13];
  const float* be1 = (const float*)d_in[14];
  const float* g2  = (const float*)d_in[15];
  const float* be2 = (const float*)d_in[16];
  float* out = (float*)d_out;

  char* ws = (char*)d_ws;
  size_t off = 0;
  auto alloc = [&](size_t bytes)->char*{
    char* p = ws + off; off = (off + bytes + 255) & ~(size_t)255; return p;
  };
  bf16*  xb    = (bf16*) alloc((size_t)NTOK*D_*2);
  bf16*  WcatT = (bf16*) alloc((size_t)3*D_*D_*2);
  float* bcat  = (float*)alloc((size_t)3*D_*4);
  bf16*  WoT   = (bf16*) alloc((size_t)D_*D_*2);
  bf16*  W1T   = (bf16*) alloc((size_t)F_*D_*2);
  bf16*  W2T   = (bf16*) alloc((size_t)D_*F_*2);
  bf16*  r1    = (bf16*) alloc((size_t)NTOK*F_*2);     // q,k,vt then ff1
  bf16*  qb    = r1;
  bf16*  kb    = r1 + (size_t)NTOK*D_;
  _Float16* vt = (_Float16*)(r1 + (size_t)2*NTOK*D_);  // [bh*64+d][S], f16, key-permuted
  bf16*  ff1   = r1;
  bf16*  ctxb  = (bf16*) alloc((size_t)NTOK*D_*2);     // ctx then y2
  bf16*  y1    = (bf16*) alloc((size_t)NTOK*D_*2);
  bf16*  hb    = (bf16*) alloc((size_t)NTOK*D_*2);
  bf16*  y2    = ctxb;

  f32_to_bf16_k<<<(NTOK*D_/4+255)/256, 256, 0, stream>>>(
      (const float4*)x, (short4*)xb, NTOK*D_/4);
  transpose_f32_bf16_k<<<dim3(D_/32, D_/32), 256, 0, stream>>>(Wo, WoT, D_, D_);
  transpose_f32_bf16_k<<<dim3(F_/32, D_/32), 256, 0, stream>>>(W1, W1T, D_, F_);
  transpose_f32_bf16_k<<<dim3(D_/32, F_/32), 256, 0, stream>>>(W2, W2T, F_, D_);
  pack_qkv_t_k<<<(3*D_*D_+255)/256, 256, 0, stream>>>(Wq,bq,Wk,bk,Wv,bv,WcatT,bcat);

  // 1) fused QKV projection (q pre-scaled 1/8*log2e; v written transposed+permuted f16)
  mgemm256_k<0><<<dim3(3*D_/256, NTOK/256), 512, 0, stream>>>(
      xb, WcatT, bcat, nullptr, NTOK, 3*D_, D_, qb, kb, vt);

  // 2) MFMA flash attention -> ctx [8192,768]
  fattn_k<<<dim3(BH_, S_/64), 256, 0, stream>>>(qb, kb, vt, ctxb);

  // 3) out-proj + residual: y1 = ctx@Wo + bo + x   (128x128 tiles, BK=64, dbuf)
  mgemm128_k<<<dim3(D_/128, NTOK/128), 256, 0, stream>>>(
      ctxb, WoT, bo, xb, y1, NTOK, D_, D_);

  // 4) LN1 -> h
  layernorm_k<bf16><<<NTOK, 192, 0, stream>>>(y1, g1, be1, hb);

  // 5) FF1 + fast GELU (256x256 8-phase)
  mgemm256_k<2><<<dim3(F_/256, NTOK/256), 512, 0, stream>>>(
      hb, W1T, b1, ff1, NTOK, F_, D_, nullptr, nullptr, nullptr);

  // 6) FF2 + residual: y2 = ff1@W2 + b2 + h   (128x128 tiles, BK=64, dbuf)
  mgemm128_k<<<dim3(D_/128, NTOK/128), 256, 0, stream>>>(
      ff1, W2T, b2, hb, y2, NTOK, D_, F_);

  // 7) LN2 -> out (fp32)
  layernorm_k<float><<<NTOK, 192, 0, stream>>>(y2, g2, be2, out);
}

// Round 6
// 375.775 us; speedup vs baseline: 1.0982x; 1.0460x over previous
//
#include <hip/hip_runtime.h>
#include <hip/hip_bf16.h>
#include <math.h>

#define B_ 4
#define S_ 2048
#define D_ 768
#define H_ 12
#define DH_ 64
#define F_ 3072
#define NTOK (B_*S_)   // 8192
#define BH_ (B_*H_)    // 48

typedef __hip_bfloat16 bf16;
typedef __attribute__((ext_vector_type(8))) short bf16x8;   // 8 bf16 = 4 VGPRs (MFMA A/B frag)
typedef __attribute__((ext_vector_type(4))) float f32x4;    // MFMA C/D frag
typedef __attribute__((ext_vector_type(4))) _Float16 half4;
typedef __attribute__((ext_vector_type(8))) _Float16 half8;
typedef __attribute__((ext_vector_type(2))) __fp16 fp16x2;  // cvt_pkrtz result type

// async global->LDS: 16 B/lane, lane i lands at ldsbase + i*16 (wave-uniform base)
#define GLD16(g, l) __builtin_amdgcn_global_load_lds( \
    (__attribute__((address_space(1))) void*)(uintptr_t)(g), \
    (__attribute__((address_space(3))) void*)(uintptr_t)(l), 16, 0, 0)

__device__ __forceinline__ float bs2f(short s){
  union { unsigned int u; float f; } cv; cv.u = ((unsigned int)(unsigned short)s) << 16; return cv.f;
}
__device__ __forceinline__ float b2f(bf16 v){ return __bfloat162float(v); }
__device__ __forceinline__ bf16 f2b(float v){ return __float2bfloat16(v); }
__device__ __forceinline__ short f2bb(float v){ bf16 b = f2b(v); short s; __builtin_memcpy(&s, &b, 2); return s; }

// pack 4 floats -> half4 via v_cvt_pkrtz_f16_f32 pairs
__device__ __forceinline__ half4 pk4(float p0, float p1, float p2, float p3){
  union { fp16x2 v2[2]; half4 v4; } u;
  u.v2[0] = __builtin_amdgcn_cvt_pkrtz(p0, p1);
  u.v2[1] = __builtin_amdgcn_cvt_pkrtz(p2, p3);
  return u.v4;
}

// raw workgroup barrier (no vmcnt(0) drain like __syncthreads) + compiler mem fence
__device__ __forceinline__ void wgbar(){
  __builtin_amdgcn_s_barrier();
  asm volatile("" ::: "memory");
}
// barrier that guarantees this wave's ds_writes are visible (lgkmcnt only, no vmcnt drain)
__device__ __forceinline__ void wgbar_lds(){
  asm volatile("s_waitcnt lgkmcnt(0)" ::: "memory");
  __builtin_amdgcn_s_barrier();
  asm volatile("" ::: "memory");
}

// tanh-form GELU rewritten: 0.5x(1+tanh(u)) = x * rcp(1 + exp2(x*(c0 + c1*x^2)))
__device__ __forceinline__ float gelu_fast(float v){
  const float c0 = -2.302208157f;
  const float c1 = -0.102943238f;
  float w = v*v;
  float z = v * __builtin_fmaf(c1, w, c0);
  float t = __builtin_amdgcn_exp2f(z);
  return v * __builtin_amdgcn_rcpf(1.0f + t);
}

// ---------------- fp32 -> bf16 convert (vectorized: float4 -> short4) ----------------
__global__ void f32_to_bf16_k(const float4* __restrict__ in, short4* __restrict__ out, int n4){
  int i = blockIdx.x*256 + threadIdx.x;
  if (i < n4){
    float4 v = in[i];
    short4 o;
    o.x = f2bb(v.x); o.y = f2bb(v.y); o.z = f2bb(v.z); o.w = f2bb(v.w);
    out[i] = o;
  }
}

// ------- transpose+convert: in[K][N] f32 -> out[N][K] bf16 (LDS 32x32 tiles) -------
__global__ __launch_bounds__(256) void transpose_f32_bf16_k(const float* __restrict__ in,
    bf16* __restrict__ out, int K, int N){
  __shared__ float t[32][33];
  const int kb = blockIdx.y*32, nb = blockIdx.x*32;
  const int x = threadIdx.x & 31, y = threadIdx.x >> 5;
#pragma unroll
  for (int yy = y; yy < 32; yy += 8)
    t[yy][x] = in[(size_t)(kb+yy)*N + nb + x];
  __syncthreads();
#pragma unroll
  for (int yy = y; yy < 32; yy += 8)
    out[(size_t)(nb+yy)*K + kb + x] = f2b(t[x][yy]);
}

// ---- pack Wq/Wk/Wv [H,D,Dh] -> WcatT [3D][D] (n-major, k contiguous), biases -> bcat[3D] ----
__global__ void pack_qkv_t_k(const float* __restrict__ Wq, const float* __restrict__ bq,
                             const float* __restrict__ Wk, const float* __restrict__ bk,
                             const float* __restrict__ Wv, const float* __restrict__ bv,
                             bf16* __restrict__ Wt, float* __restrict__ bcat){
  int idx = blockIdx.x*256 + threadIdx.x;
  if (idx < 3*D_*D_){
    int n = idx / D_;
    int k = idx - n*D_;
    int which = n / D_;
    int cc = n - which*D_;
    int h = cc >> 6, e = cc & 63;
    const float* W = (which==0) ? Wq : ((which==1) ? Wk : Wv);
    Wt[idx] = f2b(W[((size_t)h*D_ + k)*DH_ + e]);
  }
  if (idx < 3*D_){
    int which = idx / D_;
    int cc = idx - which*D_;
    int h = cc >> 6, e = cc & 63;
    const float* bb = (which==0) ? bq : ((which==1) ? bk : bv);
    bcat[idx] = bb[h*DH_ + e];
  }
}

// ============ MFMA GEMM 128x128, BK=64, double-buffered 2-phase counted-vmcnt ============
// All four block GEMMs run on this tile: 64 KB LDS -> 2 blocks/CU -> 512 co-resident
// block slots, which packs the short-K grids far better than 256^2 tiles:
//   QKV  (N=2304): 18x64 = 1152 blocks = 2.25 fills (vs 288 @ 1/CU = 2 rounds, 56% util)
//   FF1  (N=3072): 24x64 = 1536 blocks = exactly 3.0 fills (perfect)
//   proj/FF2 (N=768): 6x64 = 384 blocks, fully resident
// 4 waves (2x2), per-wave 64x64 out, 32 MFMA per K-step per wave.  Per K-step: issue next
// tile's 8 global_load_lds BEFORE computing current buffer; single vmcnt(0)+s_barrier.
// Swizzle: slot c of row r holds global chunk c ^ (r&7).
// EPI 0: qkv scatter (q pre-scaled 1/8*log2e, V -> transposed+key-permuted f16)
// EPI 1: C = A@Bt^T + bias + aux (residual), bf16
// EPI 2: C = gelu(A@Bt^T + bias), bf16
template<int EPI>
__global__ __launch_bounds__(256) void mgemm128_k(
    const bf16* __restrict__ A, const bf16* __restrict__ Bt,
    const float* __restrict__ bias, const bf16* __restrict__ aux,
    bf16* __restrict__ C, int M, int N, int K,
    bf16* __restrict__ qb, bf16* __restrict__ kbuf, _Float16* __restrict__ vt)
{
  __shared__ __align__(16) bf16 As[16384];   // [2][128][64] 32 KB
  __shared__ __align__(16) bf16 Bs[16384];   // [2][128][64] 32 KB
  const int tid  = threadIdx.x;
  const int wave = tid >> 6, lane = tid & 63;
  const int quad = lane >> 4, l16 = lane & 15;
  const int wm = (wave >> 1) * 64, wn = (wave & 1) * 64;

  const int NX = gridDim.x;
  const int f  = blockIdx.y * NX + blockIdx.x;
  const int xcd = f & 7;
  const int j   = f >> 3;
  const int bx  = j % NX;
  const int by  = (j / NX) * 8 + xcd;
  const int m0 = by * 128, n0 = bx * 128;

  const int srow8 = lane >> 3;                       // 0..7
  const int g     = (lane & 7) ^ srow8;              // global 16B-chunk within the row
  // wave w stages rows w*32 + t*8 + srow8 (t=0..3) for both A and B
  const bf16* gA = A  + (size_t)(m0 + wave*32 + srow8)*K + g*8;
  const bf16* gB = Bt + (size_t)(n0 + wave*32 + srow8)*K + g*8;
  const uintptr_t asb = (uintptr_t)(void*)As + (size_t)wave*32*128;
  const uintptr_t bsb = (uintptr_t)(void*)Bs + (size_t)wave*32*128;

  f32x4 acc[4][4];
#pragma unroll
  for (int i=0;i<4;i++)
#pragma unroll
    for (int j2=0;j2<4;j2++) acc[i][j2] = (f32x4)0.f;

  const char* AsB = (const char*)As;
  const char* BsB = (const char*)Bs;
  const int KT = K >> 6;

  // prologue: stage tile 0 into buf0
#pragma unroll
  for (int t=0;t<4;t++){
    GLD16(gA + (size_t)t*8*K, asb + t*1024);
    GLD16(gB + (size_t)t*8*K, bsb + t*1024);
  }
  gA += 64; gB += 64;
  asm volatile("s_waitcnt vmcnt(0)" ::: "memory");
  wgbar();

  for (int kt = 0; kt < KT; ++kt){
    const int cur = kt & 1, nxt = cur ^ 1;
    const bool pf = (kt + 1) < KT;
    if (pf){
      const uintptr_t ao = asb + (size_t)nxt*16384;
      const uintptr_t bo = bsb + (size_t)nxt*16384;
#pragma unroll
      for (int t=0;t<4;t++){
        GLD16(gA + (size_t)t*8*K, ao + t*1024);
        GLD16(gB + (size_t)t*8*K, bo + t*1024);
      }
      gA += 64; gB += 64;
    }
    const char* Ac = AsB + (size_t)cur*16384;
    const char* Bc = BsB + (size_t)cur*16384;
#pragma unroll
    for (int kq = 0; kq < 2; kq++){
      const int cbase = kq*4 + quad;
      bf16x8 af[4], bfr[4];
#pragma unroll
      for (int i=0;i<4;i++){
        const int m = wm + i*16 + l16;
        af[i] = *(const bf16x8*)(Ac + (m << 7) + ((cbase ^ (m & 7)) << 4));
      }
#pragma unroll
      for (int j2=0;j2<4;j2++){
        const int n = wn + j2*16 + l16;
        bfr[j2] = *(const bf16x8*)(Bc + (n << 7) + ((cbase ^ (n & 7)) << 4));
      }
#pragma unroll
      for (int i=0;i<4;i++)
#pragma unroll
        for (int j2=0;j2<4;j2++)
          acc[i][j2] = __builtin_amdgcn_mfma_f32_16x16x32_bf16(af[i], bfr[j2], acc[i][j2], 0, 0, 0);
    }
    if (pf) asm volatile("s_waitcnt vmcnt(0)" ::: "memory");
    wgbar();
  }

  // -------- epilogue --------
#pragma unroll
  for (int i=0;i<4;i++){
#pragma unroll
    for (int j2=0;j2<4;j2++){
      const int n = n0 + wn + j2*16 + l16;
      const int m_base = m0 + wm + i*16 + quad*4;
      if (EPI == 0){
        const int which = n / D_;
        const int cc = n - which*D_;
        const int h = cc >> 6, e = cc & 63;
        if (which == 2){
          const int b = m_base >> 11, s = m_base & (S_-1);
          const int sl = s & 63;
          const int perm = ((sl>>2)&3)*16 + ((sl>>4)&3)*4;   // key-permuted V^T layout
          half4 hv;
#pragma unroll
          for (int r=0;r<4;r++) hv[r] = (_Float16)(acc[i][j2][r] + bias[n]);
          *(half4*)(vt + ((size_t)(b*H_+h)*DH_ + e)*S_ + (s & ~63) + perm) = hv;
        } else {
          bf16* dst = (which==0) ? qb : kbuf;
          // q: fold softmax 1/sqrt(64) AND log2(e) (exp2-domain softmax) into prescale
          const float sc2 = (which==0) ? 0.18033688f : 1.0f;
#pragma unroll
          for (int r=0;r<4;r++){
            const int m = m_base + r;
            const int b = m >> 11, s = m & (S_-1);
            dst[((size_t)(b*H_+h)*S_ + s)*DH_ + e] = f2b((acc[i][j2][r] + bias[n]) * sc2);
          }
        }
      } else if (EPI == 1){
#pragma unroll
        for (int r=0;r<4;r++){
          const int m = m_base + r;
          float v = acc[i][j2][r] + bias[n] + b2f(aux[(size_t)m*N + n]);
          C[(size_t)m*N + n] = f2b(v);
        }
      } else {
#pragma unroll
        for (int r=0;r<4;r++){
          const int m = m_base + r;
          float v = acc[i][j2][r] + bias[n];
          C[(size_t)m*N + n] = f2b(gelu_fast(v));
        }
      }
    }
  }
}

// ---------------- MFMA flash attention: 1 barrier/tile, K+V dbuf, V->regs pre-barrier ----------------
// exp2-domain softmax (1/sqrt(64)*log2e folded into q) + defer-max (THR=8).
// Pipeline per tile kt: [QK^T from K(kt) | local max -> maxb(kt&1) | V(kt) LDS->regs |
// ds_write tile kt+1 from regs | global-load kt+2 -> regs] -> barrier ->
// [cross-half max | defer-max | P | PV from V-regs].
// LDS 38.4 KB -> 4 blocks/CU (VGPR ~100 <= 128 cap from __launch_bounds__(256,4)).
__global__ __launch_bounds__(256, 4) void fattn_k(const bf16* __restrict__ qb,
    const bf16* __restrict__ kb, const _Float16* __restrict__ vt, bf16* __restrict__ ctx)
{
  __shared__ __align__(16) char smem[38400];
  typedef bf16     KsRow[72];
  typedef _Float16 VsRow[72];
  KsRow* kp0 = (KsRow*)(smem);            // K buf A [64][72] bf16 (9216 B)
  KsRow* kp1 = (KsRow*)(smem + 9216);     // K buf B
  VsRow* vp0 = (VsRow*)(smem + 18432);    // V bufs [64 d][72 keys(permuted)] f16
  VsRow* vp1 = (VsRow*)(smem + 27648);
  float* maxb  = (float*)(smem + 36864);  // [2 bufs][2 kh][64 q]  (1024 B)
  float* libuf = (float*)(smem + 37888);  // [2 kh][64 q]          (512 B)
  float* Obuf  = (float*)smem;            // epilogue alias (16896 B < 18432)

  const int bh = blockIdx.x;
  const int qt = 31 - blockIdx.y;       // heavy tiles first
  const int q0 = qt * 64;
  const int tid = threadIdx.x;
  const int wave = tid >> 6, lane = tid & 63;
  const int quad = lane >> 4, l16 = lane & 15;
  const int kh = wave >> 1, qh = wave & 1;
  const size_t kbase = (size_t)bh * S_ * DH_;
  const int nt = qt + 1;

  const int sr  = tid >> 2;            // staging row 0..63
  const int seg = (tid & 3) * 16;      // staging col 0,16,32,48

  bf16x8 qf[2][2];
#pragma unroll
  for (int nf=0; nf<2; nf++)
#pragma unroll
    for (int h=0; h<2; h++)
      qf[nf][h] = *(const bf16x8*)(qb + kbase + (size_t)(q0 + qh*32 + nf*16 + l16)*DH_ + h*32 + quad*8);

  f32x4 o[4][2];
#pragma unroll
  for (int df=0; df<4; df++){ o[df][0] = (f32x4)0.f; o[df][1] = (f32x4)0.f; }
  float mi[2] = {-1e30f, -1e30f}, li[2] = {0.f, 0.f};

  // ---- prologue: tile 0 -> LDS (kp0/vp0); tile 1 -> regs ----
  bf16x8 ka0, ka1; half8 va0, va1;
  {
    const bf16* ks = kb + kbase + (size_t)sr*DH_ + seg;
    ka0 = *(const bf16x8*)ks; ka1 = *(const bf16x8*)(ks + 8);
    const _Float16* vs = vt + ((size_t)bh*DH_ + sr)*S_ + seg;
    va0 = *(const half8*)vs; va1 = *(const half8*)(vs + 8);
  }
  *(bf16x8*)&kp0[sr][seg]   = ka0;
  *(bf16x8*)&kp0[sr][seg+8] = ka1;
  *(half8*)&vp0[sr][seg]    = va0;
  *(half8*)&vp0[sr][seg+8]  = va1;
  if (nt > 1){
    const bf16* ks = kb + kbase + (size_t)(64 + sr)*DH_ + seg;
    ka0 = *(const bf16x8*)ks; ka1 = *(const bf16x8*)(ks + 8);
    const _Float16* vs = vt + ((size_t)bh*DH_ + sr)*S_ + 64 + seg;
    va0 = *(const half8*)vs; va1 = *(const half8*)(vs + 8);
  }
  wgbar_lds();

  for (int kt = 0; kt < nt; ++kt){
    // -------- pre-barrier: QK^T(kt), local max, V(kt)->regs, stage kt+1, load kt+2 --------
    bf16x8 af[2][2];
#pragma unroll
    for (int mf=0; mf<2; mf++)
#pragma unroll
      for (int h=0; h<2; h++)
        af[mf][h] = *(const bf16x8*)&kp0[kh*32 + mf*16 + l16][h*32 + quad*8];
    f32x4 sc[2][2];
#pragma unroll
    for (int mf=0; mf<2; mf++)
#pragma unroll
      for (int nf=0; nf<2; nf++){
        f32x4 t = __builtin_amdgcn_mfma_f32_16x16x32_bf16(af[mf][0], qf[nf][0], (f32x4)0.f, 0, 0, 0);
        sc[mf][nf] = __builtin_amdgcn_mfma_f32_16x16x32_bf16(af[mf][1], qf[nf][1], t, 0, 0, 0);
      }

    if (kt == qt){
#pragma unroll
      for (int mf=0; mf<2; mf++){
        const int keyl = kh*32 + mf*16 + quad*4;
#pragma unroll
        for (int nf=0; nf<2; nf++){
          const int ql = qh*32 + nf*16 + l16;
#pragma unroll
          for (int r=0; r<4; r++)
            if (keyl + r > ql) sc[mf][nf][r] = -1e30f;
        }
      }
    }

    float mw[2];
#pragma unroll
    for (int nf=0; nf<2; nf++){
      float mx = -1e30f;
#pragma unroll
      for (int mf=0; mf<2; mf++)
#pragma unroll
        for (int r=0; r<4; r++) mx = fmaxf(mx, sc[mf][nf][r]);
      mx = fmaxf(mx, __shfl_xor(mx, 16));
      mx = fmaxf(mx, __shfl_xor(mx, 32));
      mw[nf] = mx;
    }
    float* mb = maxb + (kt & 1)*128;
    if (quad == 0){
      mb[kh*64 + qh*32 + l16]      = mw[0];
      mb[kh*64 + qh*32 + 16 + l16] = mw[1];
    }

    // V(kt): LDS -> regs (pre-barrier, so vp0 can be overwritten next interval)
    half8 vv[4];
#pragma unroll
    for (int df=0; df<4; df++)
      vv[df] = *(const half8*)&vp0[df*16 + l16][quad*16 + kh*8];

    if (kt + 1 < nt){
      // write staged regs (tile kt+1) -> kp1 / vp1
      *(bf16x8*)&kp1[sr][seg]   = ka0;
      *(bf16x8*)&kp1[sr][seg+8] = ka1;
      *(half8*)&vp1[sr][seg]    = va0;
      *(half8*)&vp1[sr][seg+8]  = va1;
      if (kt + 2 < nt){
        const int k0n = (kt + 2) * 64;
        const bf16* ks = kb + kbase + (size_t)(k0n + sr)*DH_ + seg;
        ka0 = *(const bf16x8*)ks; ka1 = *(const bf16x8*)(ks + 8);
        const _Float16* vs = vt + ((size_t)bh*DH_ + sr)*S_ + k0n + seg;
        va0 = *(const half8*)vs; va1 = *(const half8*)(vs + 8);
      }
    }
    wgbar_lds();

    // -------- post-barrier: cross-half max, defer-max, P, PV from V-regs --------
    const float tm0 = fmaxf(mw[0], mb[(1-kh)*64 + qh*32 + l16]);
    const float tm1 = fmaxf(mw[1], mb[(1-kh)*64 + qh*32 + 16 + l16]);
    const bool need = !__all((tm0 - mi[0] <= 8.f) && (tm1 - mi[1] <= 8.f));
    if (need){
      const float mn0 = fmaxf(mi[0], tm0);
      const float mn1 = fmaxf(mi[1], tm1);
      const float a0 = __builtin_amdgcn_exp2f(mi[0] - mn0);
      const float a1 = __builtin_amdgcn_exp2f(mi[1] - mn1);
      mi[0] = mn0; mi[1] = mn1;
      li[0] *= a0; li[1] *= a1;
#pragma unroll
      for (int df=0; df<4; df++)
#pragma unroll
        for (int r=0; r<4; r++){ o[df][0][r] *= a0; o[df][1][r] *= a1; }
    }

    half4 pfr[2][2];
#pragma unroll
    for (int nf=0; nf<2; nf++){
      float rs = 0.f;
#pragma unroll
      for (int mf=0; mf<2; mf++){
        const float p0 = __builtin_amdgcn_exp2f(sc[mf][nf][0] - mi[nf]);
        const float p1 = __builtin_amdgcn_exp2f(sc[mf][nf][1] - mi[nf]);
        const float p2 = __builtin_amdgcn_exp2f(sc[mf][nf][2] - mi[nf]);
        const float p3 = __builtin_amdgcn_exp2f(sc[mf][nf][3] - mi[nf]);
        rs += (p0 + p1) + (p2 + p3);
        pfr[mf][nf] = pk4(p0, p1, p2, p3);
      }
      rs += __shfl_xor(rs, 16);
      rs += __shfl_xor(rs, 32);
      li[nf] += rs;
    }

#pragma unroll
    for (int df=0; df<4; df++){
      half4 vlo = __builtin_shufflevector(vv[df], vv[df], 0,1,2,3);
      half4 vhi = __builtin_shufflevector(vv[df], vv[df], 4,5,6,7);
#pragma unroll
      for (int nf=0; nf<2; nf++){
        o[df][nf] = __builtin_amdgcn_mfma_f32_16x16x16f16(vlo, pfr[0][nf], o[df][nf], 0, 0, 0);
        o[df][nf] = __builtin_amdgcn_mfma_f32_16x16x16f16(vhi, pfr[1][nf], o[df][nf], 0, 0, 0);
      }
    }

    // rotate buffers: K and V both 2-cycle
    { KsRow* t_ = kp0; kp0 = kp1; kp1 = t_; }
    { VsRow* t_ = vp0; vp0 = vp1; vp1 = t_; }
  }

  __syncthreads();
  if (quad == 0){
    libuf[kh*64 + qh*32 + l16]      = li[0];
    libuf[kh*64 + qh*32 + 16 + l16] = li[1];
  }
  if (kh == 1){
#pragma unroll
    for (int df=0; df<4; df++)
#pragma unroll
      for (int nf=0; nf<2; nf++)
#pragma unroll
        for (int r=0; r<4; r++)
          Obuf[(qh*64 + df*16 + quad*4 + r)*33 + nf*16 + l16] = o[df][nf][r];
  }
  __syncthreads();
  if (kh == 0){
    const int b = bh / H_, h = bh - (bh / H_)*H_;
#pragma unroll
    for (int nf=0; nf<2; nf++){
      const int q64 = qh*32 + nf*16 + l16;
      // both kh halves applied identical defer-max decisions -> same mi -> li directly addable
      const float inv = 1.0f / (libuf[q64] + libuf[64 + q64]);
      const int qtok = q0 + q64;
#pragma unroll
      for (int df=0; df<4; df++){
        short4 pk;
        float v0 = (o[df][nf][0] + Obuf[(qh*64 + df*16 + quad*4 + 0)*33 + nf*16 + l16]) * inv;
        float v1 = (o[df][nf][1] + Obuf[(qh*64 + df*16 + quad*4 + 1)*33 + nf*16 + l16]) * inv;
        float v2 = (o[df][nf][2] + Obuf[(qh*64 + df*16 + quad*4 + 2)*33 + nf*16 + l16]) * inv;
        float v3 = (o[df][nf][3] + Obuf[(qh*64 + df*16 + quad*4 + 3)*33 + nf*16 + l16]) * inv;
        pk.x = f2bb(v0); pk.y = f2bb(v1); pk.z = f2bb(v2); pk.w = f2bb(v3);
        *(short4*)((short*)ctx + ((size_t)(b*S_ + qtok))*D_ + h*DH_ + df*16 + quad*4) = pk;
      }
    }
  }
}

// ---------------- layernorm over D=768 (192 thr, short4 loads, 16B stores) ----------------
template<typename T> __device__ __forceinline__ void st4(T* p, size_t idx, float a, float b, float c, float d);
template<> __device__ __forceinline__ void st4<float>(float* p, size_t idx, float a, float b, float c, float d){
  float4 v; v.x=a; v.y=b; v.z=c; v.w=d; *(float4*)(p+idx) = v;
}
template<> __device__ __forceinline__ void st4<bf16>(bf16* p, size_t idx, float a, float b, float c, float d){
  short4 v; v.x=f2bb(a); v.y=f2bb(b); v.z=f2bb(c); v.w=f2bb(d); *(short4*)((short*)p+idx) = v;
}

template<typename OutT>
__global__ __launch_bounds__(192) void layernorm_k(const bf16* __restrict__ X,
    const float* __restrict__ g, const float* __restrict__ bta, OutT* __restrict__ Y)
{
  const int row = blockIdx.x;
  const int tid = threadIdx.x;
  const short4 raw = *(const short4*)((const short*)X + (size_t)row*D_ + tid*4);
  const float v0 = bs2f(raw.x), v1 = bs2f(raw.y), v2 = bs2f(raw.z), v3 = bs2f(raw.w);
  float s  = v0+v1+v2+v3;
  float s2 = v0*v0+v1*v1+v2*v2+v3*v3;
#pragma unroll
  for (int o = 32; o > 0; o >>= 1){ s += __shfl_down(s, o); s2 += __shfl_down(s2, o); }
  __shared__ float rs[3], rq[3];
  const int lane = tid & 63, w = tid >> 6;
  if (lane == 0){ rs[w] = s; rq[w] = s2; }
  __syncthreads();
  s  = rs[0]+rs[1]+rs[2];
  s2 = rq[0]+rq[1]+rq[2];
  const float mean = s * (1.0f/D_);
  const float var  = s2 * (1.0f/D_) - mean*mean;
  const float inv  = rsqrtf(var + 1e-5f);
  const float4 g4 = *(const float4*)(g + tid*4);
  const float4 b4 = *(const float4*)(bta + tid*4);
  st4(Y, (size_t)row*D_ + tid*4,
      (v0-mean)*inv*g4.x + b4.x,
      (v1-mean)*inv*g4.y + b4.y,
      (v2-mean)*inv*g4.z + b4.z,
      (v3-mean)*inv*g4.w + b4.w);
}

extern "C" void kernel_launch(void* const* d_in, const int* in_sizes, int n_in,
                              void* d_out, int out_size, void* d_ws, size_t ws_size,
                              hipStream_t stream)
{
  const float* x   = (const float*)d_in[0];
  const float* Wq  = (const float*)d_in[1];
  const float* bq  = (const float*)d_in[2];
  const float* Wk  = (const float*)d_in[3];
  const float* bk  = (const float*)d_in[4];
  const float* Wv  = (const float*)d_in[5];
  const float* bv  = (const float*)d_in[6];
  const float* Wo  = (const float*)d_in[7];
  const float* bo  = (const float*)d_in[8];
  const float* W1  = (const float*)d_in[9];
  const float* b1  = (const float*)d_in[10];
  const float* W2  = (const float*)d_in[11];
  const float* b2  = (const float*)d_in[12];
  const float* g1  = (const float*)d_in[13];
  const float* be1 = (const float*)d_in[14];
  const float* g2  = (const float*)d_in[15];
  const float* be2 = (const float*)d_in[16];
  float* out = (float*)d_out;

  char* ws = (char*)d_ws;
  size_t off = 0;
  auto alloc = [&](size_t bytes)->char*{
    char* p = ws + off; off = (off + bytes + 255) & ~(size_t)255; return p;
  };
  bf16*  xb    = (bf16*) alloc((size_t)NTOK*D_*2);
  bf16*  WcatT = (bf16*) alloc((size_t)3*D_*D_*2);
  float* bcat  = (float*)alloc((size_t)3*D_*4);
  bf16*  WoT   = (bf16*) alloc((size_t)D_*D_*2);
  bf16*  W1T   = (bf16*) alloc((size_t)F_*D_*2);
  bf16*  W2T   = (bf16*) alloc((size_t)D_*F_*2);
  bf16*  r1    = (bf16*) alloc((size_t)NTOK*F_*2);     // q,k,vt then ff1
  bf16*  qb    = r1;
  bf16*  kb    = r1 + (size_t)NTOK*D_;
  _Float16* vt = (_Float16*)(r1 + (size_t)2*NTOK*D_);  // [bh*64+d][S], f16, key-permuted
  bf16*  ff1   = r1;
  bf16*  ctxb  = (bf16*) alloc((size_t)NTOK*D_*2);     // ctx then y2
  bf16*  y1    = (bf16*) alloc((size_t)NTOK*D_*2);
  bf16*  hb    = (bf16*) alloc((size_t)NTOK*D_*2);
  bf16*  y2    = ctxb;

  f32_to_bf16_k<<<(NTOK*D_/4+255)/256, 256, 0, stream>>>(
      (const float4*)x, (short4*)xb, NTOK*D_/4);
  transpose_f32_bf16_k<<<dim3(D_/32, D_/32), 256, 0, stream>>>(Wo, WoT, D_, D_);
  transpose_f32_bf16_k<<<dim3(F_/32, D_/32), 256, 0, stream>>>(W1, W1T, D_, F_);
  transpose_f32_bf16_k<<<dim3(D_/32, F_/32), 256, 0, stream>>>(W2, W2T, F_, D_);
  pack_qkv_t_k<<<(3*D_*D_+255)/256, 256, 0, stream>>>(Wq,bq,Wk,bk,Wv,bv,WcatT,bcat);

  // 1) fused QKV projection: 128x128 tiles, grid 18x64 = 1152 blocks (2 blocks/CU)
  mgemm128_k<0><<<dim3(3*D_/128, NTOK/128), 256, 0, stream>>>(
      xb, WcatT, bcat, nullptr, nullptr, NTOK, 3*D_, D_, qb, kb, vt);

  // 2) MFMA flash attention -> ctx [8192,768]
  fattn_k<<<dim3(BH_, S_/64), 256, 0, stream>>>(qb, kb, vt, ctxb);

  // 3) out-proj + residual: y1 = ctx@Wo + bo + x   (grid 6x64 = 384, fully resident)
  mgemm128_k<1><<<dim3(D_/128, NTOK/128), 256, 0, stream>>>(
      ctxb, WoT, bo, xb, y1, NTOK, D_, D_, nullptr, nullptr, nullptr);

  // 4) LN1 -> h
  layernorm_k<bf16><<<NTOK, 192, 0, stream>>>(y1, g1, be1, hb);

  // 5) FF1 + fast GELU (grid 24x64 = 1536 = exactly 3 fills of 512 slots)
  mgemm128_k<2><<<dim3(F_/128, NTOK/128), 256, 0, stream>>>(
      hb, W1T, b1, nullptr, ff1, NTOK, F_, D_, nullptr, nullptr, nullptr);

  // 6) FF2 + residual: y2 = ff1@W2 + b2 + h   (grid 6x64 = 384, fully resident)
  mgemm128_k<1><<<dim3(D_/128, NTOK/128), 256, 0, stream>>>(
      ff1, W2T, b2, hb, y2, NTOK, D_, F_, nullptr, nullptr, nullptr);

  // 7) LN2 -> out (fp32)
  layernorm_k<float><<<NTOK, 192, 0, stream>>>(y2, g2, be2, out);
}

// Round 7
// 341.747 us; speedup vs baseline: 1.2076x; 1.0996x over previous
//
#include <hip/hip_runtime.h>
#include <hip/hip_bf16.h>
#include <math.h>

#define B_ 4
#define S_ 2048
#define D_ 768
#define H_ 12
#define DH_ 64
#define F_ 3072
#define NTOK (B_*S_)   // 8192
#define BH_ (B_*H_)    // 48

typedef __hip_bfloat16 bf16;
typedef __attribute__((ext_vector_type(8))) short bf16x8;   // 8 bf16 = 4 VGPRs (MFMA A/B frag)
typedef __attribute__((ext_vector_type(4))) float f32x4;    // MFMA C/D frag
typedef __attribute__((ext_vector_type(4))) _Float16 half4;
typedef __attribute__((ext_vector_type(8))) _Float16 half8;
typedef __attribute__((ext_vector_type(2))) __fp16 fp16x2;  // cvt_pkrtz result type

// async global->LDS: 16 B/lane, lane i lands at ldsbase + i*16 (wave-uniform base)
#define GLD16(g, l) __builtin_amdgcn_global_load_lds( \
    (__attribute__((address_space(1))) void*)(uintptr_t)(g), \
    (__attribute__((address_space(3))) void*)(uintptr_t)(l), 16, 0, 0)

__device__ __forceinline__ float bs2f(short s){
  union { unsigned int u; float f; } cv; cv.u = ((unsigned int)(unsigned short)s) << 16; return cv.f;
}
__device__ __forceinline__ float b2f(bf16 v){ return __bfloat162float(v); }
__device__ __forceinline__ bf16 f2b(float v){ return __float2bfloat16(v); }
__device__ __forceinline__ short f2bb(float v){ bf16 b = f2b(v); short s; __builtin_memcpy(&s, &b, 2); return s; }

// pack 4 floats -> half4 via v_cvt_pkrtz_f16_f32 pairs
__device__ __forceinline__ half4 pk4(float p0, float p1, float p2, float p3){
  union { fp16x2 v2[2]; half4 v4; } u;
  u.v2[0] = __builtin_amdgcn_cvt_pkrtz(p0, p1);
  u.v2[1] = __builtin_amdgcn_cvt_pkrtz(p2, p3);
  return u.v4;
}

// raw workgroup barrier (no vmcnt(0) drain like __syncthreads) + compiler mem fence
__device__ __forceinline__ void wgbar(){
  __builtin_amdgcn_s_barrier();
  asm volatile("" ::: "memory");
}
// barrier that guarantees this wave's ds ops are visible (lgkmcnt only, no vmcnt drain)
__device__ __forceinline__ void wgbar_lds(){
  asm volatile("s_waitcnt lgkmcnt(0)" ::: "memory");
  __builtin_amdgcn_s_barrier();
  asm volatile("" ::: "memory");
}

// tanh-form GELU rewritten: 0.5x(1+tanh(u)) = x * rcp(1 + exp2(x*(c0 + c1*x^2)))
__device__ __forceinline__ float gelu_fast(float v){
  const float c0 = -2.302208157f;
  const float c1 = -0.102943238f;
  float w = v*v;
  float z = v * __builtin_fmaf(c1, w, c0);
  float t = __builtin_amdgcn_exp2f(z);
  return v * __builtin_amdgcn_rcpf(1.0f + t);
}

// ============ fused prep: fp32->bf16 cvt | 3 weight transposes | qkv pack ============
// One dispatch, region-sliced by blockIdx.x; all jobs independent + memory-bound, so
// fusing lets them overlap instead of serializing across 5 launches.
//   [0, 6144)        : x f32 -> xb bf16 (float4->short4)
//   [6144, 6720)     : Wo  [768][768]  -> WoT  (32x32 LDS tiles, 24x24)
//   [6720, 9024)     : W1  [768][3072] -> W1T  (96 x-tiles, 24 y-tiles)
//   [9024, 11328)    : W2  [3072][768] -> W2T  (24 x-tiles, 96 y-tiles)
//   [11328, 18240)   : Wq/Wk/Wv -> WcatT [3D][D] + bcat
__global__ __launch_bounds__(256) void prep_k(
    const float4* __restrict__ x4, short4* __restrict__ xb4,
    const float* __restrict__ Wo, bf16* __restrict__ WoT,
    const float* __restrict__ W1, bf16* __restrict__ W1T,
    const float* __restrict__ W2, bf16* __restrict__ W2T,
    const float* __restrict__ Wq, const float* __restrict__ bq,
    const float* __restrict__ Wk, const float* __restrict__ bk,
    const float* __restrict__ Wv, const float* __restrict__ bv,
    bf16* __restrict__ Wt, float* __restrict__ bcat)
{
  __shared__ float t[32][33];
  int bid = blockIdx.x;
  const int tidx = threadIdx.x;

  if (bid < 6144){                       // ---- cvt ----
    const int i = bid*256 + tidx;
    float4 v = x4[i];
    short4 o;
    o.x = f2bb(v.x); o.y = f2bb(v.y); o.z = f2bb(v.z); o.w = f2bb(v.w);
    xb4[i] = o;
    return;
  }
  bid -= 6144;
  if (bid >= 576 + 2304 + 2304){         // ---- qkv pack ----
    bid -= 576 + 2304 + 2304;
    const int idx = bid*256 + tidx;
    {
      int n = idx / D_;
      int k = idx - n*D_;
      int which = n / D_;
      int cc = n - which*D_;
      int h = cc >> 6, e = cc & 63;
      const float* W = (which==0) ? Wq : ((which==1) ? Wk : Wv);
      Wt[idx] = f2b(W[((size_t)h*D_ + k)*DH_ + e]);
    }
    if (idx < 3*D_){
      int which = idx / D_;
      int cc = idx - which*D_;
      int h = cc >> 6, e = cc & 63;
      const float* bb = (which==0) ? bq : ((which==1) ? bk : bv);
      bcat[idx] = bb[h*DH_ + e];
    }
    return;
  }
  // ---- transposes: in[K][N] f32 -> out[N][K] bf16 ----
  const float* tin; bf16* tout; int K, N, tiles_x;
  if (bid < 576){ tin = Wo; tout = WoT; K = D_; N = D_; tiles_x = 24; }
  else if (bid < 576 + 2304){ bid -= 576; tin = W1; tout = W1T; K = D_; N = F_; tiles_x = 96; }
  else { bid -= 576 + 2304; tin = W2; tout = W2T; K = F_; N = D_; tiles_x = 24; }
  const int kb = (bid / tiles_x)*32, nb = (bid % tiles_x)*32;
  const int xx = tidx & 31, y = tidx >> 5;
#pragma unroll
  for (int yy = y; yy < 32; yy += 8)
    t[yy][xx] = tin[(size_t)(kb+yy)*N + nb + xx];
  __syncthreads();
#pragma unroll
  for (int yy = y; yy < 32; yy += 8)
    tout[(size_t)(nb+yy)*K + kb + xx] = f2b(t[xx][yy]);
}

// ============ MFMA GEMM 128x128, BK=64, double-buffered 2-phase counted-vmcnt ============
// 64 KB LDS -> 2 blocks/CU -> 512 co-resident block slots.
// EPI 0: qkv scatter (q pre-scaled 1/8*log2e, V -> transposed+key-permuted f16)
// EPI 1: C = A@Bt^T + bias + aux (residual), bf16;  EPI 2: C = gelu(A@Bt^T + bias)
template<int EPI>
__global__ __launch_bounds__(256) void mgemm128_k(
    const bf16* __restrict__ A, const bf16* __restrict__ Bt,
    const float* __restrict__ bias, const bf16* __restrict__ aux,
    bf16* __restrict__ C, int M, int N, int K,
    bf16* __restrict__ qb, bf16* __restrict__ kbuf, _Float16* __restrict__ vt)
{
  __shared__ __align__(16) bf16 As[16384];   // [2][128][64] 32 KB
  __shared__ __align__(16) bf16 Bs[16384];   // [2][128][64] 32 KB
  const int tid  = threadIdx.x;
  const int wave = tid >> 6, lane = tid & 63;
  const int quad = lane >> 4, l16 = lane & 15;
  const int wm = (wave >> 1) * 64, wn = (wave & 1) * 64;

  const int NX = gridDim.x;
  const int f  = blockIdx.y * NX + blockIdx.x;
  const int xcd = f & 7;
  const int j   = f >> 3;
  const int bx  = j % NX;
  const int by  = (j / NX) * 8 + xcd;
  const int m0 = by * 128, n0 = bx * 128;

  const int srow8 = lane >> 3;                       // 0..7
  const int g     = (lane & 7) ^ srow8;              // global 16B-chunk within the row
  const bf16* gA = A  + (size_t)(m0 + wave*32 + srow8)*K + g*8;
  const bf16* gB = Bt + (size_t)(n0 + wave*32 + srow8)*K + g*8;
  const uintptr_t asb = (uintptr_t)(void*)As + (size_t)wave*32*128;
  const uintptr_t bsb = (uintptr_t)(void*)Bs + (size_t)wave*32*128;

  f32x4 acc[4][4];
#pragma unroll
  for (int i=0;i<4;i++)
#pragma unroll
    for (int j2=0;j2<4;j2++) acc[i][j2] = (f32x4)0.f;

  const char* AsB = (const char*)As;
  const char* BsB = (const char*)Bs;
  const int KT = K >> 6;

  // prologue: stage tile 0 into buf0
#pragma unroll
  for (int t=0;t<4;t++){
    GLD16(gA + (size_t)t*8*K, asb + t*1024);
    GLD16(gB + (size_t)t*8*K, bsb + t*1024);
  }
  gA += 64; gB += 64;
  asm volatile("s_waitcnt vmcnt(0)" ::: "memory");
  wgbar();

  for (int kt = 0; kt < KT; ++kt){
    const int cur = kt & 1, nxt = cur ^ 1;
    const bool pf = (kt + 1) < KT;
    if (pf){
      const uintptr_t ao = asb + (size_t)nxt*16384;
      const uintptr_t bo = bsb + (size_t)nxt*16384;
#pragma unroll
      for (int t=0;t<4;t++){
        GLD16(gA + (size_t)t*8*K, ao + t*1024);
        GLD16(gB + (size_t)t*8*K, bo + t*1024);
      }
      gA += 64; gB += 64;
    }
    const char* Ac = AsB + (size_t)cur*16384;
    const char* Bc = BsB + (size_t)cur*16384;
#pragma unroll
    for (int kq = 0; kq < 2; kq++){
      const int cbase = kq*4 + quad;
      bf16x8 af[4], bfr[4];
#pragma unroll
      for (int i=0;i<4;i++){
        const int m = wm + i*16 + l16;
        af[i] = *(const bf16x8*)(Ac + (m << 7) + ((cbase ^ (m & 7)) << 4));
      }
#pragma unroll
      for (int j2=0;j2<4;j2++){
        const int n = wn + j2*16 + l16;
        bfr[j2] = *(const bf16x8*)(Bc + (n << 7) + ((cbase ^ (n & 7)) << 4));
      }
#pragma unroll
      for (int i=0;i<4;i++)
#pragma unroll
        for (int j2=0;j2<4;j2++)
          acc[i][j2] = __builtin_amdgcn_mfma_f32_16x16x32_bf16(af[i], bfr[j2], acc[i][j2], 0, 0, 0);
    }
    if (pf) asm volatile("s_waitcnt vmcnt(0)" ::: "memory");
    wgbar();
  }

  // -------- epilogue --------
#pragma unroll
  for (int i=0;i<4;i++){
#pragma unroll
    for (int j2=0;j2<4;j2++){
      const int n = n0 + wn + j2*16 + l16;
      const int m_base = m0 + wm + i*16 + quad*4;
      if (EPI == 0){
        const int which = n / D_;
        const int cc = n - which*D_;
        const int h = cc >> 6, e = cc & 63;
        if (which == 2){
          const int b = m_base >> 11, s = m_base & (S_-1);
          const int sl = s & 63;
          const int perm = ((sl>>2)&3)*16 + ((sl>>4)&3)*4;   // key-permuted V^T layout
          half4 hv;
#pragma unroll
          for (int r=0;r<4;r++) hv[r] = (_Float16)(acc[i][j2][r] + bias[n]);
          *(half4*)(vt + ((size_t)(b*H_+h)*DH_ + e)*S_ + (s & ~63) + perm) = hv;
        } else {
          bf16* dst = (which==0) ? qb : kbuf;
          // q: fold softmax 1/sqrt(64) AND log2(e) (exp2-domain softmax) into prescale
          const float sc2 = (which==0) ? 0.18033688f : 1.0f;
#pragma unroll
          for (int r=0;r<4;r++){
            const int m = m_base + r;
            const int b = m >> 11, s = m & (S_-1);
            dst[((size_t)(b*H_+h)*S_ + s)*DH_ + e] = f2b((acc[i][j2][r] + bias[n]) * sc2);
          }
        }
      } else if (EPI == 1){
#pragma unroll
        for (int r=0;r<4;r++){
          const int m = m_base + r;
          float v = acc[i][j2][r] + bias[n] + b2f(aux[(size_t)m*N + n]);
          C[(size_t)m*N + n] = f2b(v);
        }
      } else {
#pragma unroll
        for (int r=0;r<4;r++){
          const int m = m_base + r;
          float v = acc[i][j2][r] + bias[n];
          C[(size_t)m*N + n] = f2b(gelu_fast(v));
        }
      }
    }
  }
}

// ======== MFMA flash attention: wave-owns-16q org, zero cross-wave softmax state ========
// Each of the 4 waves owns 16 q-rows x ALL 64 keys per tile: row max and row sum finish
// with two shfl_xor (no maxb LDS exchange, no paired defer-max, no Obuf/libuf epilogue
// merge).  exp2-domain softmax (1/sqrt(64)*log2e folded into q) + wave-local defer-max
// (THR=8).  K+V double-buffered; V read to regs PRE-barrier so dbuf suffices; staged
// global->reg prefetch of tile kt+2.  One barrier per tile.  LDS 36.9 KB -> 4 blocks/CU.
// Key-permuted V^T position decode: key s=[b5b4|b3b2|b1b0] stored at p=[b3b2|b5b4|b1b0],
// so kslot ks (keys ks*16+quad*4+r) = half4 at vp[dh][quad*16 + ks*4].
__global__ __launch_bounds__(256, 4) void fattn_k(const bf16* __restrict__ qb,
    const bf16* __restrict__ kb, const _Float16* __restrict__ vt, bf16* __restrict__ ctx)
{
  __shared__ __align__(16) char smem[36864];
  typedef bf16     KsRow[72];
  typedef _Float16 VsRow[72];
  KsRow* kp0 = (KsRow*)(smem);            // K buf A [64][72] bf16 (9216 B)
  KsRow* kp1 = (KsRow*)(smem + 9216);     // K buf B
  VsRow* vp0 = (VsRow*)(smem + 18432);    // V bufs [64 dh][72 key-positions] f16
  VsRow* vp1 = (VsRow*)(smem + 27648);

  const int bh = blockIdx.x;
  const int qt = 31 - blockIdx.y;       // heavy tiles first
  const int q0 = qt * 64;
  const int tid = threadIdx.x;
  const int wave = tid >> 6, lane = tid & 63;
  const int quad = lane >> 4, l16 = lane & 15;
  const size_t kbase = (size_t)bh * S_ * DH_;
  const int nt = qt + 1;

  const int sr  = tid >> 2;            // staging row 0..63
  const int seg = (tid & 3) * 16;      // staging col 0,16,32,48

  // wave owns q rows q0 + wave*16 + l16 (quads share the row, split over k)
  const int qloc = wave*16 + l16;
  bf16x8 qf[2];
#pragma unroll
  for (int h=0; h<2; h++)
    qf[h] = *(const bf16x8*)(qb + kbase + (size_t)(q0 + qloc)*DH_ + h*32 + quad*8);

  f32x4 o[4];                          // o[df][r] = O[q=own row][dh=df*16+quad*4+r]
#pragma unroll
  for (int df=0; df<4; df++) o[df] = (f32x4)0.f;
  float mi = -1e30f, li = 0.f;

  // ---- prologue: tile 0 -> LDS (kp0/vp0); tile 1 -> regs ----
  bf16x8 ka0, ka1; half8 va0, va1;
  {
    const bf16* ks = kb + kbase + (size_t)sr*DH_ + seg;
    ka0 = *(const bf16x8*)ks; ka1 = *(const bf16x8*)(ks + 8);
    const _Float16* vs = vt + ((size_t)bh*DH_ + sr)*S_ + seg;
    va0 = *(const half8*)vs; va1 = *(const half8*)(vs + 8);
  }
  *(bf16x8*)&kp0[sr][seg]   = ka0;
  *(bf16x8*)&kp0[sr][seg+8] = ka1;
  *(half8*)&vp0[sr][seg]    = va0;
  *(half8*)&vp0[sr][seg+8]  = va1;
  if (nt > 1){
    const bf16* ks = kb + kbase + (size_t)(64 + sr)*DH_ + seg;
    ka0 = *(const bf16x8*)ks; ka1 = *(const bf16x8*)(ks + 8);
    const _Float16* vs = vt + ((size_t)bh*DH_ + sr)*S_ + 64 + seg;
    va0 = *(const half8*)vs; va1 = *(const half8*)(vs + 8);
  }
  wgbar_lds();

  for (int kt = 0; kt < nt; ++kt){
    // -------- pre-barrier: QK^T(kt) all 64 keys, row max, V(kt)->regs, stage kt+1 --------
    f32x4 sc[4];
#pragma unroll
    for (int mf=0; mf<4; mf++){
      bf16x8 a0 = *(const bf16x8*)&kp0[mf*16 + l16][quad*8];
      bf16x8 a1 = *(const bf16x8*)&kp0[mf*16 + l16][32 + quad*8];
      f32x4 t = __builtin_amdgcn_mfma_f32_16x16x32_bf16(a0, qf[0], (f32x4)0.f, 0, 0, 0);
      sc[mf]  = __builtin_amdgcn_mfma_f32_16x16x32_bf16(a1, qf[1], t, 0, 0, 0);
    }

    if (kt == qt){
#pragma unroll
      for (int mf=0; mf<4; mf++){
        const int keyl = mf*16 + quad*4;
#pragma unroll
        for (int r=0; r<4; r++)
          if (keyl + r > qloc) sc[mf][r] = -1e30f;
      }
    }

    float mx = -1e30f;
#pragma unroll
    for (int mf=0; mf<4; mf++)
#pragma unroll
      for (int r=0; r<4; r++) mx = fmaxf(mx, sc[mf][r]);
    mx = fmaxf(mx, __shfl_xor(mx, 16));
    mx = fmaxf(mx, __shfl_xor(mx, 32));

    // V(kt): LDS -> regs (pre-barrier, so vp0 can be overwritten next interval)
    half8 vva[4], vvb[4];
#pragma unroll
    for (int df=0; df<4; df++){
      vva[df] = *(const half8*)&vp0[df*16 + l16][quad*16];
      vvb[df] = *(const half8*)&vp0[df*16 + l16][quad*16 + 8];
    }

    if (kt + 1 < nt){
      // write staged regs (tile kt+1) -> kp1 / vp1
      *(bf16x8*)&kp1[sr][seg]   = ka0;
      *(bf16x8*)&kp1[sr][seg+8] = ka1;
      *(half8*)&vp1[sr][seg]    = va0;
      *(half8*)&vp1[sr][seg+8]  = va1;
      if (kt + 2 < nt){
        const int k0n = (kt + 2) * 64;
        const bf16* ks = kb + kbase + (size_t)(k0n + sr)*DH_ + seg;
        ka0 = *(const bf16x8*)ks; ka1 = *(const bf16x8*)(ks + 8);
        const _Float16* vs = vt + ((size_t)bh*DH_ + sr)*S_ + k0n + seg;
        va0 = *(const half8*)vs; va1 = *(const half8*)(vs + 8);
      }
    }
    wgbar_lds();

    // -------- post-barrier (registers only): defer-max, P, PV --------
    const bool need = !__all(mx - mi <= 8.f);
    if (need){
      const float mn = fmaxf(mi, mx);
      const float a = __builtin_amdgcn_exp2f(mi - mn);
      mi = mn; li *= a;
#pragma unroll
      for (int df=0; df<4; df++)
#pragma unroll
        for (int r=0; r<4; r++) o[df][r] *= a;
    }

    half4 pfr[4];
    float rs = 0.f;
#pragma unroll
    for (int mf=0; mf<4; mf++){
      const float p0 = __builtin_amdgcn_exp2f(sc[mf][0] - mi);
      const float p1 = __builtin_amdgcn_exp2f(sc[mf][1] - mi);
      const float p2 = __builtin_amdgcn_exp2f(sc[mf][2] - mi);
      const float p3 = __builtin_amdgcn_exp2f(sc[mf][3] - mi);
      rs += (p0 + p1) + (p2 + p3);
      pfr[mf] = pk4(p0, p1, p2, p3);
    }
    rs += __shfl_xor(rs, 16);
    rs += __shfl_xor(rs, 32);
    li += rs;

#pragma unroll
    for (int df=0; df<4; df++){
      half4 k0f = __builtin_shufflevector(vva[df], vva[df], 0,1,2,3);
      half4 k1f = __builtin_shufflevector(vva[df], vva[df], 4,5,6,7);
      half4 k2f = __builtin_shufflevector(vvb[df], vvb[df], 0,1,2,3);
      half4 k3f = __builtin_shufflevector(vvb[df], vvb[df], 4,5,6,7);
      o[df] = __builtin_amdgcn_mfma_f32_16x16x16f16(k0f, pfr[0], o[df], 0, 0, 0);
      o[df] = __builtin_amdgcn_mfma_f32_16x16x16f16(k1f, pfr[1], o[df], 0, 0, 0);
      o[df] = __builtin_amdgcn_mfma_f32_16x16x16f16(k2f, pfr[2], o[df], 0, 0, 0);
      o[df] = __builtin_amdgcn_mfma_f32_16x16x16f16(k3f, pfr[3], o[df], 0, 0, 0);
    }

    // rotate buffers (both 2-cycle)
    { KsRow* t_ = kp0; kp0 = kp1; kp1 = t_; }
    { VsRow* t_ = vp0; vp0 = vp1; vp1 = t_; }
  }

  // -------- epilogue: direct write, no LDS, no barriers --------
  const int b = bh / H_, h = bh - (bh / H_)*H_;
  const float inv = 1.0f / li;
  const int token = q0 + qloc;
  short* cdst = (short*)ctx + ((size_t)(b*S_ + token))*D_ + h*DH_;
#pragma unroll
  for (int df=0; df<4; df++){
    short4 pk;
    pk.x = f2bb(o[df][0] * inv);
    pk.y = f2bb(o[df][1] * inv);
    pk.z = f2bb(o[df][2] * inv);
    pk.w = f2bb(o[df][3] * inv);
    *(short4*)(cdst + df*16 + quad*4) = pk;
  }
}

// ---------------- layernorm over D=768 (192 thr, short4 loads, 16B stores) ----------------
template<typename T> __device__ __forceinline__ void st4(T* p, size_t idx, float a, float b, float c, float d);
template<> __device__ __forceinline__ void st4<float>(float* p, size_t idx, float a, float b, float c, float d){
  float4 v; v.x=a; v.y=b; v.z=c; v.w=d; *(float4*)(p+idx) = v;
}
template<> __device__ __forceinline__ void st4<bf16>(bf16* p, size_t idx, float a, float b, float c, float d){
  short4 v; v.x=f2bb(a); v.y=f2bb(b); v.z=f2bb(c); v.w=f2bb(d); *(short4*)((short*)p+idx) = v;
}

template<typename OutT>
__global__ __launch_bounds__(192) void layernorm_k(const bf16* __restrict__ X,
    const float* __restrict__ g, const float* __restrict__ bta, OutT* __restrict__ Y)
{
  const int row = blockIdx.x;
  const int tid = threadIdx.x;
  const short4 raw = *(const short4*)((const short*)X + (size_t)row*D_ + tid*4);
  const float v0 = bs2f(raw.x), v1 = bs2f(raw.y), v2 = bs2f(raw.z), v3 = bs2f(raw.w);
  float s  = v0+v1+v2+v3;
  float s2 = v0*v0+v1*v1+v2*v2+v3*v3;
#pragma unroll
  for (int o = 32; o > 0; o >>= 1){ s += __shfl_down(s, o); s2 += __shfl_down(s2, o); }
  __shared__ float rs[3], rq[3];
  const int lane = tid & 63, w = tid >> 6;
  if (lane == 0){ rs[w] = s; rq[w] = s2; }
  __syncthreads();
  s  = rs[0]+rs[1]+rs[2];
  s2 = rq[0]+rq[1]+rq[2];
  const float mean = s * (1.0f/D_);
  const float var  = s2 * (1.0f/D_) - mean*mean;
  const float inv  = rsqrtf(var + 1e-5f);
  const float4 g4 = *(const float4*)(g + tid*4);
  const float4 b4 = *(const float4*)(bta + tid*4);
  st4(Y, (size_t)row*D_ + tid*4,
      (v0-mean)*inv*g4.x + b4.x,
      (v1-mean)*inv*g4.y + b4.y,
      (v2-mean)*inv*g4.z + b4.z,
      (v3-mean)*inv*g4.w + b4.w);
}

extern "C" void kernel_launch(void* const* d_in, const int* in_sizes, int n_in,
                              void* d_out, int out_size, void* d_ws, size_t ws_size,
                              hipStream_t stream)
{
  const float* x   = (const float*)d_in[0];
  const float* Wq  = (const float*)d_in[1];
  const float* bq  = (const float*)d_in[2];
  const float* Wk  = (const float*)d_in[3];
  const float* bk  = (const float*)d_in[4];
  const float* Wv  = (const float*)d_in[5];
  const float* bv  = (const float*)d_in[6];
  const float* Wo  = (const float*)d_in[7];
  const float* bo  = (const float*)d_in[8];
  const float* W1  = (const float*)d_in[9];
  const float* b1  = (const float*)d_in[10];
  const float* W2  = (const float*)d_in[11];
  const float* b2  = (const float*)d_in[12];
  const float* g1  = (const float*)d_in[13];
  const float* be1 = (const float*)d_in[14];
  const float* g2  = (const float*)d_in[15];
  const float* be2 = (const float*)d_in[16];
  float* out = (float*)d_out;

  char* ws = (char*)d_ws;
  size_t off = 0;
  auto alloc = [&](size_t bytes)->char*{
    char* p = ws + off; off = (off + bytes + 255) & ~(size_t)255; return p;
  };
  bf16*  xb    = (bf16*) alloc((size_t)NTOK*D_*2);
  bf16*  WcatT = (bf16*) alloc((size_t)3*D_*D_*2);
  float* bcat  = (float*)alloc((size_t)3*D_*4);
  bf16*  WoT   = (bf16*) alloc((size_t)D_*D_*2);
  bf16*  W1T   = (bf16*) alloc((size_t)F_*D_*2);
  bf16*  W2T   = (bf16*) alloc((size_t)D_*F_*2);
  bf16*  r1    = (bf16*) alloc((size_t)NTOK*F_*2);     // q,k,vt then ff1
  bf16*  qb    = r1;
  bf16*  kb    = r1 + (size_t)NTOK*D_;
  _Float16* vt = (_Float16*)(r1 + (size_t)2*NTOK*D_);  // [bh*64+d][S], f16, key-permuted
  bf16*  ff1   = r1;
  bf16*  ctxb  = (bf16*) alloc((size_t)NTOK*D_*2);     // ctx then y2
  bf16*  y1    = (bf16*) alloc((size_t)NTOK*D_*2);
  bf16*  hb    = (bf16*) alloc((size_t)NTOK*D_*2);
  bf16*  y2    = ctxb;

  // 0) fused prep: cvt + 3 transposes + qkv pack in one dispatch
  prep_k<<<18240, 256, 0, stream>>>(
      (const float4*)x, (short4*)xb, Wo, WoT, W1, W1T, W2, W2T,
      Wq, bq, Wk, bk, Wv, bv, WcatT, bcat);

  // 1) fused QKV projection: 128x128 tiles, grid 18x64 = 1152 blocks (2 blocks/CU)
  mgemm128_k<0><<<dim3(3*D_/128, NTOK/128), 256, 0, stream>>>(
      xb, WcatT, bcat, nullptr, nullptr, NTOK, 3*D_, D_, qb, kb, vt);

  // 2) MFMA flash attention -> ctx [8192,768]
  fattn_k<<<dim3(BH_, S_/64), 256, 0, stream>>>(qb, kb, vt, ctxb);

  // 3) out-proj + residual: y1 = ctx@Wo + bo + x   (grid 6x64 = 384, fully resident)
  mgemm128_k<1><<<dim3(D_/128, NTOK/128), 256, 0, stream>>>(
      ctxb, WoT, bo, xb, y1, NTOK, D_, D_, nullptr, nullptr, nullptr);

  // 4) LN1 -> h
  layernorm_k<bf16><<<NTOK, 192, 0, stream>>>(y1, g1, be1, hb);

  // 5) FF1 + fast GELU (grid 24x64 = 1536 = exactly 3 fills of 512 slots)
  mgemm128_k<2><<<dim3(F_/128, NTOK/128), 256, 0, stream>>>(
      hb, W1T, b1, nullptr, ff1, NTOK, F_, D_, nullptr, nullptr, nullptr);

  // 6) FF2 + residual: y2 = ff1@W2 + b2 + h   (grid 6x64 = 384, fully resident)
  mgemm128_k<1><<<dim3(D_/128, NTOK/128), 256, 0, stream>>>(
      ff1, W2T, b2, hb, y2, NTOK, D_, F_, nullptr, nullptr, nullptr);

  // 7) LN2 -> out (fp32)
  layernorm_k<float><<<NTOK, 192, 0, stream>>>(y2, g2, be2, out);
}